// Round 1
// 832.475 us; speedup vs baseline: 1.0831x; 1.0831x over previous
//
#include <hip/hip_runtime.h>
#include <hip/hip_bf16.h>

// Mamba2 mixer forward, MI355X. B=2, L=2048, D_MODEL=2048, H=64, P=64, N=128,
// G=1, K=4, CHUNK=256. T = 4096 tokens, 16 chunks.
// fp16 MFMA for: in_proj (8-phase 256^2 template), CBT, states, ydiag+yoff
// (fused), out_proj. fp32 kept for: conv math, dt/cumsum (exact), inter-chunk
// recurrence, epilogues.

typedef __attribute__((ext_vector_type(8))) _Float16 f16x8;
typedef __attribute__((ext_vector_type(4))) float f32x4;

#define GLD16(gp, lp) __builtin_amdgcn_global_load_lds( \
    (__attribute__((address_space(1))) void*)(gp),      \
    (__attribute__((address_space(3))) void*)(lp), 16, 0, 0)

__device__ __forceinline__ unsigned short f2h(float v) {
  _Float16 h = (_Float16)v;
  return *reinterpret_cast<unsigned short*>(&h);
}
__device__ __forceinline__ float h2f(unsigned short u) {
  _Float16 h = *reinterpret_cast<_Float16*>(&u);
  return (float)h;
}
__device__ __forceinline__ float siluf(float x) { return x / (1.f + expf(-x)); }

// ---------------------------------------------------------------- cast X->fp16
__global__ __launch_bounds__(256) void cast_f16(const float* __restrict__ s,
                                                _Float16* __restrict__ d) {
  long i = ((long)blockIdx.x * 256 + threadIdx.x) * 4;
  float4 v = *reinterpret_cast<const float4*>(s + i);
  ushort4 u;
  u.x = f2h(v.x); u.y = f2h(v.y); u.z = f2h(v.z); u.w = f2h(v.w);
  *reinterpret_cast<ushort4*>(d + i) = u;
}

// --------------------------- transpose Win cols [0,8448) -> fp16 [n][k]
__global__ __launch_bounds__(256) void transpose_win(const float* __restrict__ src,
                                                     _Float16* __restrict__ dst) {
  __shared__ float tile[32][33];
  int c0 = blockIdx.x * 32, r0 = blockIdx.y * 32;
  int tx = threadIdx.x, ty = threadIdx.y;  // 32 x 8
#pragma unroll
  for (int i = 0; i < 4; i++)
    tile[ty + i * 8][tx] = src[(long)(r0 + ty + i * 8) * 8512 + c0 + tx];
  __syncthreads();
#pragma unroll
  for (int i = 0; i < 4; i++) {
    int c = c0 + ty + i * 8, r = r0 + tx;
    dst[(long)c * 2048 + r] = (_Float16)tile[tx][ty + i * 8];
  }
}

// ------------------ transpose+cast fp32 RxC -> fp16 [C][R] (for out_proj W)
__global__ __launch_bounds__(256) void transpose_wout(const float* __restrict__ src,
                                                      _Float16* __restrict__ dst,
                                                      int R, int C) {
  __shared__ float tile[32][33];
  int c0 = blockIdx.x * 32, r0 = blockIdx.y * 32;
  int tx = threadIdx.x, ty = threadIdx.y;
#pragma unroll
  for (int i = 0; i < 4; i++)
    tile[ty + i * 8][tx] = src[(long)(r0 + ty + i * 8) * C + c0 + tx];
  __syncthreads();
#pragma unroll
  for (int i = 0; i < 4; i++) {
    int c = c0 + ty + i * 8, r = r0 + tx;
    dst[(long)c * R + r] = (_Float16)tile[tx][ty + i * 8];
  }
}

// ===================== in_proj GEMM: 256^2 tile, BK=64, 8-wave 8-phase =======
// A[4096,2048] f16 row-major, Bt[8448,2048] f16 row-major (Win^T).
// C cols [0,4096) -> gate (fp16, ld 4096); cols [4096,8448) -> hbcf (fp32, ld 4352).
// LDS 128 KiB: 8 regions x 16 KiB: buf(b) regions {4b+0: A half0, 4b+1: A half1,
// 4b+2: B half0, 4b+3: B half1}. st_16x32 swizzle: physical col16 ^= (row&4)>>1,
// applied on the READ path and pre-applied to the GLOBAL source (gload_lds writes
// linearly: dest = wave-uniform base + lane*16).
__global__ __launch_bounds__(512, 2) void gemm_in8(const _Float16* __restrict__ A,
                                                   const _Float16* __restrict__ Bt,
                                                   _Float16* __restrict__ gate,
                                                   float* __restrict__ hbcf) {
  __shared__ char ldsB[131072];
  const int tid = threadIdx.x;
  const int lane = tid & 63;
  const int wv = tid >> 6;
  const int wr = wv >> 2, wc = wv & 3;  // 2 (M) x 4 (N) waves; wave C = 128x64
  // bijective XCD swizzle (grid 528 = 8*66)
  const int wg = blockIdx.x;
  const int swz = (wg & 7) * 66 + (wg >> 3);
  const int bx = swz % 33, by = swz / 33;  // bx: N-tile [0,33), by: M-tile [0,16)

  // -------- staging geometry: half-tile = 128 rows x 64 halfs (16 KiB),
  // 2 x GLD16/thread; round r covers rows r*64 + tid/8; col16 = tid&7.
  const int srow = tid >> 3;
  const int scolg = (tid & 7) ^ ((srow & 4) >> 1);  // inverse-swizzled source col
  const _Float16* Ab = A + (long)by * 256 * 2048 + (long)srow * 2048 + scolg * 8;
  const _Float16* Bb = Bt + (long)bx * 256 * 2048 + (long)srow * 2048 + scolg * 8;
  const int ldst = tid << 4;

#define STAGE_A(tau, h) do {                                              \
    const _Float16* g_ = Ab + (long)(h) * 262144 + (tau) * 64;            \
    char* l_ = ldsB + ((((tau) & 1) << 2) + (h)) * 16384 + ldst;          \
    GLD16(g_, l_); GLD16(g_ + 131072, l_ + 8192); } while (0)
#define STAGE_B(tau, h) do {                                              \
    const _Float16* g_ = Bb + (long)(h) * 262144 + (tau) * 64;            \
    char* l_ = ldsB + ((((tau) & 1) << 2) + 2 + (h)) * 16384 + ldst;      \
    GLD16(g_, l_); GLD16(g_ + 131072, l_ + 8192); } while (0)

  // -------- fragment-read bases (swizzled)
  const int fr = lane & 15;
  const int fkA = (lane >> 4) ^ ((fr & 4) ? 2 : 0);
  const char* aRd = ldsB + wr * 16384 + fr * 128 + fkA * 16;
  const char* bRd = ldsB + (2 + (wc >> 1)) * 16384 + ((wc & 1) * 64 + fr) * 128 + fkA * 16;
#define RD_A(b, mi, k32) (*(const f16x8*)(aRd + (b) * 65536 + (mi) * 2048 + (k32) * 64))
#define RD_B(b, ni, k32) (*(const f16x8*)(bRd + (b) * 65536 + (ni) * 2048 + (k32) * 64))

#define BAR() __builtin_amdgcn_s_barrier()
#define WLG0() asm volatile("s_waitcnt lgkmcnt(0)" ::: "memory")
#define WLG8() asm volatile("s_waitcnt lgkmcnt(8)" ::: "memory")
#define WVM4() asm volatile("s_waitcnt vmcnt(4)" ::: "memory")

  f32x4 acc[8][4];
#pragma unroll
  for (int mi = 0; mi < 8; ++mi)
#pragma unroll
    for (int ni = 0; ni < 4; ++ni) acc[mi][ni] = f32x4{0.f, 0.f, 0.f, 0.f};

  // prologue: tile0 {A0,A1,B0,B1} + tile1 {B0,B1}; keep last 2 half-tiles in flight
  STAGE_A(0, 0); STAGE_A(0, 1); STAGE_B(0, 0); STAGE_B(0, 1);
  STAGE_B(1, 0); STAGE_B(1, 1);
  WVM4(); BAR();

#define MFMA_Q(MI0, MI1, x0, x1, x2, x3, PB)                                        \
  __builtin_amdgcn_s_setprio(1);                                                    \
  _Pragma("unroll") for (int ni = 0; ni < 4; ++ni) {                                \
    acc[MI0][ni] = __builtin_amdgcn_mfma_f32_16x16x32_f16(x0, PB[ni][0], acc[MI0][ni], 0, 0, 0); \
    acc[MI0][ni] = __builtin_amdgcn_mfma_f32_16x16x32_f16(x1, PB[ni][1], acc[MI0][ni], 0, 0, 0); \
    acc[MI1][ni] = __builtin_amdgcn_mfma_f32_16x16x32_f16(x2, PB[ni][0], acc[MI1][ni], 0, 0, 0); \
    acc[MI1][ni] = __builtin_amdgcn_mfma_f32_16x16x32_f16(x3, PB[ni][1], acc[MI1][ni], 0, 0, 0); \
  }                                                                                 \
  __builtin_amdgcn_s_setprio(0);

  // 32 K-tiles of 64; 2 tiles per iteration, 8 phases. Stage schedule
  // (region dead-window verified): p0:A0(t+1) p1:A1(t+1) p2:B0(t+2) p3:B1(t+2)
  // p4:A0(t+2) p5:A1(t+2) p6:B0(t+3) p7:B1(t+3); vmcnt(4) at end of p3/p7.
  for (int u = 0; u < 16; ++u) {
    const int t1 = 2 * u + 1;
    const int t2 = (2 * u + 2) & 31;  // wrap on last iter: harmless reload
    const int t3 = (2 * u + 3) & 31;
    // ---- p0 (tile 2u, buf0, quadrant 0) + B-frags for buf0
    f16x8 PB0[4][2];
#pragma unroll
    for (int ni = 0; ni < 4; ++ni) { PB0[ni][0] = RD_B(0, ni, 0); PB0[ni][1] = RD_B(0, ni, 1); }
    {
      f16x8 x0 = RD_A(0, 0, 0), x1 = RD_A(0, 0, 1), x2 = RD_A(0, 1, 0), x3 = RD_A(0, 1, 1);
      STAGE_A(t1, 0); WLG8(); BAR(); WLG0();
      MFMA_Q(0, 1, x0, x1, x2, x3, PB0) BAR();
    }
    // ---- p1
    {
      f16x8 x0 = RD_A(0, 2, 0), x1 = RD_A(0, 2, 1), x2 = RD_A(0, 3, 0), x3 = RD_A(0, 3, 1);
      STAGE_A(t1, 1); BAR(); WLG0();
      MFMA_Q(2, 3, x0, x1, x2, x3, PB0) BAR();
    }
    // ---- p2
    {
      f16x8 x0 = RD_A(0, 4, 0), x1 = RD_A(0, 4, 1), x2 = RD_A(0, 5, 0), x3 = RD_A(0, 5, 1);
      STAGE_B(t2, 0); BAR(); WLG0();
      MFMA_Q(4, 5, x0, x1, x2, x3, PB0) BAR();
    }
    // ---- p3
    {
      f16x8 x0 = RD_A(0, 6, 0), x1 = RD_A(0, 6, 1), x2 = RD_A(0, 7, 0), x3 = RD_A(0, 7, 1);
      STAGE_B(t2, 1); BAR(); WLG0();
      MFMA_Q(6, 7, x0, x1, x2, x3, PB0) WVM4(); BAR();
    }
    // ---- p4 (tile 2u+1, buf1, quadrant 0) + B-frags for buf1
    f16x8 PB1[4][2];
#pragma unroll
    for (int ni = 0; ni < 4; ++ni) { PB1[ni][0] = RD_B(1, ni, 0); PB1[ni][1] = RD_B(1, ni, 1); }
    {
      f16x8 x0 = RD_A(1, 0, 0), x1 = RD_A(1, 0, 1), x2 = RD_A(1, 1, 0), x3 = RD_A(1, 1, 1);
      STAGE_A(t2, 0); WLG8(); BAR(); WLG0();
      MFMA_Q(0, 1, x0, x1, x2, x3, PB1) BAR();
    }
    // ---- p5
    {
      f16x8 x0 = RD_A(1, 2, 0), x1 = RD_A(1, 2, 1), x2 = RD_A(1, 3, 0), x3 = RD_A(1, 3, 1);
      STAGE_A(t2, 1); BAR(); WLG0();
      MFMA_Q(2, 3, x0, x1, x2, x3, PB1) BAR();
    }
    // ---- p6
    {
      f16x8 x0 = RD_A(1, 4, 0), x1 = RD_A(1, 4, 1), x2 = RD_A(1, 5, 0), x3 = RD_A(1, 5, 1);
      STAGE_B(t3, 0); BAR(); WLG0();
      MFMA_Q(4, 5, x0, x1, x2, x3, PB1) BAR();
    }
    // ---- p7
    {
      f16x8 x0 = RD_A(1, 6, 0), x1 = RD_A(1, 6, 1), x2 = RD_A(1, 7, 0), x3 = RD_A(1, 7, 1);
      STAGE_B(t3, 1); BAR(); WLG0();
      MFMA_Q(6, 7, x0, x1, x2, x3, PB1) WVM4(); BAR();
    }
  }
  // -------- epilogue: block-uniform gate/hbcf split at bx == 16
  const int m0 = by * 256 + wr * 128;
  const int n0 = bx * 256 + wc * 64;
  const int cl = lane & 15, rq = (lane >> 4) * 4;
  if (bx < 16) {
#pragma unroll
    for (int mi = 0; mi < 8; ++mi)
#pragma unroll
      for (int r = 0; r < 4; ++r) {
        long rowoff = (long)(m0 + mi * 16 + rq + r) * 4096 + n0 + cl;
#pragma unroll
        for (int ni = 0; ni < 4; ++ni) gate[rowoff + ni * 16] = (_Float16)acc[mi][ni][r];
      }
  } else {
#pragma unroll
    for (int mi = 0; mi < 8; ++mi)
#pragma unroll
      for (int r = 0; r < 4; ++r) {
        long rowoff = (long)(m0 + mi * 16 + rq + r) * 4352 + (n0 - 4096) + cl;
#pragma unroll
        for (int ni = 0; ni < 4; ++ni) hbcf[rowoff + ni * 16] = acc[mi][ni][r];
      }
  }
#undef STAGE_A
#undef STAGE_B
#undef RD_A
#undef RD_B
#undef BAR
#undef WLG0
#undef WLG8
#undef WVM4
#undef MFMA_Q
}

// --------------------------- fp16 GEMM (B^T), z-batched, fp32 out
// used for CBT (z=16, K=128) and out_proj (z=1, K=4096).
__global__ __launch_bounds__(256) void gemm_bt(const _Float16* __restrict__ A,
                                               const _Float16* __restrict__ Bt,
                                               float* __restrict__ Cf,
                                               int K, int ldc,
                                               long zsA, long zsB, long zsC) {
  __shared__ uint4 As4[512];
  __shared__ uint4 Bs4[512];
  _Float16* As = (_Float16*)As4;
  _Float16* Bs = (_Float16*)Bs4;
  const int tid = threadIdx.x;
  const int wv = tid >> 6;
  const int lane = tid & 63;
  const _Float16* Ab = A + (long)blockIdx.z * zsA + (long)blockIdx.y * 128 * K;
  const _Float16* Bb = Bt + (long)blockIdx.z * zsB + (long)blockIdx.x * 128 * K;
  const int c0 = wv * 128 + lane;
  const int c1 = c0 + 64;
  const long ra0 = (long)(c0 >> 2) * K + (c0 & 3) * 8;
  const long ra1 = (long)(c1 >> 2) * K + (c1 & 3) * 8;
  f32x4 acc[4][4];
#pragma unroll
  for (int mi = 0; mi < 4; mi++)
#pragma unroll
    for (int ni = 0; ni < 4; ni++) acc[mi][ni] = f32x4{0.f, 0.f, 0.f, 0.f};
  const int mrow = (wv & 1) * 64 + (lane & 15);
  const int nrow = (wv >> 1) * 64 + (lane & 15);
  const int koff = (lane >> 4) * 8;
  for (int k0 = 0; k0 < K; k0 += 32) {
    GLD16(Ab + ra0 + k0, (char*)As + c0 * 16);
    GLD16(Ab + ra1 + k0, (char*)As + c1 * 16);
    GLD16(Bb + ra0 + k0, (char*)Bs + c0 * 16);
    GLD16(Bb + ra1 + k0, (char*)Bs + c1 * 16);
    __syncthreads();
    f16x8 af[4], bfr[4];
#pragma unroll
    for (int mi = 0; mi < 4; mi++)
      af[mi] = *(const f16x8*)(As + (mrow + mi * 16) * 32 + koff);
#pragma unroll
    for (int ni = 0; ni < 4; ni++)
      bfr[ni] = *(const f16x8*)(Bs + (nrow + ni * 16) * 32 + koff);
#pragma unroll
    for (int mi = 0; mi < 4; mi++)
#pragma unroll
      for (int ni = 0; ni < 4; ni++)
        acc[mi][ni] = __builtin_amdgcn_mfma_f32_16x16x32_f16(af[mi], bfr[ni],
                                                             acc[mi][ni], 0, 0, 0);
    __syncthreads();
  }
  const int m0 = blockIdx.y * 128 + (wv & 1) * 64;
  const int n0 = blockIdx.x * 128 + (wv >> 1) * 64;
  const int cl = lane & 15, rq = (lane >> 4) * 4;
  const long zc = (long)blockIdx.z * zsC;
#pragma unroll
  for (int mi = 0; mi < 4; mi++)
#pragma unroll
    for (int r = 0; r < 4; r++) {
      long rowoff = zc + (long)(m0 + mi * 16 + rq + r) * ldc + n0 + cl;
#pragma unroll
      for (int ni = 0; ni < 4; ni++) Cf[rowoff + ni * 16] = acc[mi][ni][r];
    }
}

// ---------------------------------------- fp32 dt pre-activation (exact slice)
__global__ __launch_bounds__(256) void dtz_kernel(const float* __restrict__ hs,
                                                  const float* __restrict__ Win,
                                                  float* __restrict__ zf) {
  __shared__ float Xs[4][2048];
  int t0 = blockIdx.x * 4;
  int tid = threadIdx.x;
#pragma unroll
  for (int i = 0; i < 8; i++) {
    int e = tid * 4 + i * 1024;
    int tok = e >> 11, k = e & 2047;
    *reinterpret_cast<float4*>(&Xs[tok][k]) =
        *reinterpret_cast<const float4*>(&hs[(long)(t0 + tok) * 2048 + k]);
  }
  __syncthreads();
  int h = tid & 63, tg = tid >> 6;
  float a0 = 0.f, a1 = 0.f, a2 = 0.f, a3 = 0.f;
  const float* wcol = Win + 8448 + h;
  for (int k = 0; k < 2048; k += 4) {
    a0 = fmaf(Xs[tg][k + 0], wcol[(long)(k + 0) * 8512], a0);
    a1 = fmaf(Xs[tg][k + 1], wcol[(long)(k + 1) * 8512], a1);
    a2 = fmaf(Xs[tg][k + 2], wcol[(long)(k + 2) * 8512], a2);
    a3 = fmaf(Xs[tg][k + 3], wcol[(long)(k + 3) * 8512], a3);
  }
  zf[(long)(t0 + tg) * 64 + h] = (a0 + a1) + (a2 + a3);
}

// --------------------------- conv(K=4)+SiLU (fp32 math, fp16 out) -> x16,B16,C16
__global__ __launch_bounds__(256) void conv_silu_kernel(const float* __restrict__ hbcf,
                                                        const float* __restrict__ convw,
                                                        const float* __restrict__ convb,
                                                        _Float16* __restrict__ x16,
                                                        _Float16* __restrict__ B16,
                                                        _Float16* __restrict__ C16) {
  int q = blockIdx.x * 256 + threadIdx.x;  // [0,4352)
  int t = blockIdx.y;                      // [0,4096)
  int l = t & 2047;
  const float* col = hbcf + (long)t * 4352 + q;
  float4 wq = *reinterpret_cast<const float4*>(convw + q * 4);
  float a = convb[q];
  if (l >= 3) a += col[-3 * 4352] * wq.x;
  if (l >= 2) a += col[-2 * 4352] * wq.y;
  if (l >= 1) a += col[-1 * 4352] * wq.z;
  a += col[0] * wq.w;
  _Float16 o = (_Float16)siluf(a);
  if (q < 4096) x16[(long)t * 4096 + q] = o;
  else if (q < 4224) B16[(long)t * 128 + (q - 4096)] = o;
  else C16[(long)t * 128 + (q - 4224)] = o;
}

// ------------------------------------------- global transpose x16 -> xT16 [q][t]
__global__ __launch_bounds__(256) void xtrans(const unsigned short* __restrict__ src,
                                              unsigned short* __restrict__ dst) {
  __shared__ unsigned short tile[64][66];
  int c0 = blockIdx.x * 64, r0 = blockIdx.y * 64;
  int tx = threadIdx.x & 15, ty = threadIdx.x >> 4;  // 16 x 16
#pragma unroll
  for (int i = 0; i < 4; i++) {
    int r = ty + i * 16;
    ushort4 v = *(const ushort4*)&src[(long)(r0 + r) * 4096 + c0 + 4 * tx];
    tile[r][4 * tx] = v.x; tile[r][4 * tx + 1] = v.y;
    tile[r][4 * tx + 2] = v.z; tile[r][4 * tx + 3] = v.w;
  }
  __syncthreads();
#pragma unroll
  for (int i = 0; i < 4; i++) {
    int c = ty + i * 16;
    ushort4 v;
    v.x = tile[4 * tx + 0][c]; v.y = tile[4 * tx + 1][c];
    v.z = tile[4 * tx + 2][c]; v.w = tile[4 * tx + 3][c];
    *(ushort4*)&dst[(long)(c0 + c) * 4096 + r0 + 4 * tx] = v;
  }
}

// ------------------------------------------------- dt softplus + chunk cumsum
__global__ __launch_bounds__(256) void dt_cum_kernel(const float* __restrict__ zf,
                                                     const float* __restrict__ dtb,
                                                     const float* __restrict__ Alog,
                                                     float* __restrict__ dt_f,
                                                     float* __restrict__ cum_f,
                                                     float* __restrict__ cuml) {
  int bc = blockIdx.x;
  int h = threadIdx.x & 63, seg = threadIdx.x >> 6;
  int t0 = bc * 256;
  float Ah = -expf(Alog[h]);
  float bias = dtb[h];
  __shared__ float segsum[4][64];
  float s = 0.f;
  for (int j = 0; j < 64; j++) {
    int t = t0 + seg * 64 + j;
    float z = zf[(long)t * 64 + h] + bias;
    float v = (z > 20.f) ? z : log1pf(expf(z));
    dt_f[(long)t * 64 + h] = v;
    s += v * Ah;
  }
  segsum[seg][h] = s;
  __syncthreads();
  float run = 0.f;
  for (int k = 0; k < seg; k++) run += segsum[k][h];
  for (int j = 0; j < 64; j++) {
    int t = t0 + seg * 64 + j;
    run += dt_f[(long)t * 64 + h] * Ah;
    cum_f[(long)t * 64 + h] = run;
  }
  if (seg == 3) cuml[bc * 64 + h] = run;
}

// --------------------------------- states via MFMA: states[bc,h,p,n] (64x128)
// states[p][n] = sum_t (w_t * x[t][p]) * B[t][n];  w folded into A-operand.
__global__ __launch_bounds__(256) void states_mfma(const unsigned short* __restrict__ xT16,
                                                   const unsigned short* __restrict__ B16,
                                                   const float* __restrict__ dt_f,
                                                   const float* __restrict__ cum_f,
                                                   const float* __restrict__ cuml,
                                                   float* __restrict__ states) {
  int h = blockIdx.x, bc = blockIdx.y;
  int t0 = bc * 256, tid = threadIdx.x;
  __shared__ float w_s[256];
  __shared__ unsigned short Aw[64 * 40];   // [p][tt] pad 40
  __shared__ unsigned short BT[128 * 40];  // [n][tt] pad 40
  {
    int t = t0 + tid;
    w_s[tid] = expf(cuml[bc * 64 + h] - cum_f[(long)t * 64 + h]) * dt_f[(long)t * 64 + h];
  }
  __syncthreads();
  int wv = tid >> 6, lane = tid & 63;
  int mr = lane & 15, koff = (lane >> 4) * 8;
  f32x4 acc[4][2];
#pragma unroll
  for (int mi = 0; mi < 4; mi++)
#pragma unroll
    for (int nj = 0; nj < 2; nj++) acc[mi][nj] = f32x4{0.f, 0.f, 0.f, 0.f};
  for (int kt = 0; kt < 8; kt++) {
    {  // form Aw: thread = p*4 + tq, 8 t-elems each
      int p = tid >> 2, tq = tid & 3;
      const unsigned short* g = &xT16[((long)(h * 64 + p)) * 4096 + t0 + kt * 32 + tq * 8];
      ushort4 u0 = *(const ushort4*)g, u1 = *(const ushort4*)(g + 4);
      const float* wp = &w_s[kt * 32 + tq * 8];
      ushort4 o0, o1;
      o0.x = f2h(h2f(u0.x) * wp[0]); o0.y = f2h(h2f(u0.y) * wp[1]);
      o0.z = f2h(h2f(u0.z) * wp[2]); o0.w = f2h(h2f(u0.w) * wp[3]);
      o1.x = f2h(h2f(u1.x) * wp[4]); o1.y = f2h(h2f(u1.y) * wp[5]);
      o1.z = f2h(h2f(u1.z) * wp[6]); o1.w = f2h(h2f(u1.w) * wp[7]);
      *(ushort4*)&Aw[p * 40 + tq * 8] = o0;
      *(ushort4*)&Aw[p * 40 + tq * 8 + 4] = o1;
    }
    {  // form BT: thread = tl*8 + ng; copy B16[t][n] -> BT[n][tl]
      int tl = tid >> 3, ng = tid & 7;
      const unsigned short* g = &B16[((long)(t0 + kt * 32 + tl)) * 128 + ng * 16];
#pragma unroll
      for (int j = 0; j < 16; j++) BT[(ng * 16 + j) * 40 + tl] = g[j];
    }
    __syncthreads();
    f16x8 af[4], bf[2];
#pragma unroll
    for (int mi = 0; mi < 4; mi++)
      af[mi] = *(const f16x8*)&Aw[(mi * 16 + mr) * 40 + koff];
#pragma unroll
    for (int nj = 0; nj < 2; nj++)
      bf[nj] = *(const f16x8*)&BT[((wv * 2 + nj) * 16 + mr) * 40 + koff];
#pragma unroll
    for (int mi = 0; mi < 4; mi++)
#pragma unroll
      for (int nj = 0; nj < 2; nj++)
        acc[mi][nj] = __builtin_amdgcn_mfma_f32_16x16x32_f16(af[mi], bf[nj],
                                                             acc[mi][nj], 0, 0, 0);
    __syncthreads();
  }
  int cl = lane & 15, rq = (lane >> 4) * 4;
  long base = ((long)(bc * 64 + h)) * 8192;
#pragma unroll
  for (int mi = 0; mi < 4; mi++)
#pragma unroll
    for (int r = 0; r < 4; r++) {
      int p = mi * 16 + rq + r;
#pragma unroll
      for (int nj = 0; nj < 2; nj++) {
        int n = (wv * 2 + nj) * 16 + cl;
        states[base + p * 128 + n] = acc[mi][nj][r];
      }
    }
}

// --------------------------------- inter-chunk recurrence (in-place -> prevs)
__global__ __launch_bounds__(256) void recur_kernel(float* __restrict__ states,
                                                    const float* __restrict__ cuml) {
  int bh = blockIdx.x;
  int b = bh >> 6, h = bh & 63;
  int tid = threadIdx.x;
  float4 prev[8];
#pragma unroll
  for (int j = 0; j < 8; j++) prev[j] = make_float4(0.f, 0.f, 0.f, 0.f);
  for (int c = 0; c < 8; c++) {
    int bc = b * 8 + c;
    float cd = expf(cuml[bc * 64 + h]);
    long base = (long)(bc * 64 + h) * 8192;
#pragma unroll
    for (int j = 0; j < 8; j++) {
      long o = base + j * 1024 + tid * 4;
      float4 st = *reinterpret_cast<const float4*>(&states[o]);
      *reinterpret_cast<float4*>(&states[o]) = prev[j];
      prev[j].x = fmaf(cd, prev[j].x, st.x);
      prev[j].y = fmaf(cd, prev[j].y, st.y);
      prev[j].z = fmaf(cd, prev[j].z, st.z);
      prev[j].w = fmaf(cd, prev[j].w, st.w);
    }
  }
}

// ---------------- fused Y = Ydiag + Yoff + D*x  via MFMA, per (h, bc) block
// Ydiag[i][p] = sum_j S[i][j]*x[j][p],  S = CBT*exp(cum_i-cum_j)*dt_j, causal.
// Yoff[i][p]  = sum_n (C[i][n]*fac_i)*PS[p][n],  fac_i = exp(cum_i).
__global__ __launch_bounds__(256) void yfused(const unsigned short* __restrict__ xT16,
                                              const unsigned short* __restrict__ x16,
                                              const unsigned short* __restrict__ C16,
                                              const float* __restrict__ CBT,
                                              const float* __restrict__ states,
                                              const float* __restrict__ dt_f,
                                              const float* __restrict__ cum_f,
                                              const float* __restrict__ Dp,
                                              float* __restrict__ Ysum) {
  int h = blockIdx.x, bc = blockIdx.y;
  int t0 = bc * 256, tid = threadIdx.x;
  __shared__ unsigned short Sb[256 * 40];   // S / Afac tile [256][32] pad 40
  __shared__ unsigned short Xb[64 * 264];   // xT [64][256] pad 264; later PS16 [64][136]
  __shared__ float cum_s[256], dt_s[256];
  int i = tid;
  cum_s[i] = cum_f[(long)(t0 + i) * 64 + h];
  dt_s[i] = dt_f[(long)(t0 + i) * 64 + h];
  {  // stage xT tile: thread = p*4 + tq, 64 t-elems each
    int p = tid >> 2, tq = tid & 3;
    const unsigned short* g = &xT16[((long)(h * 64 + p)) * 4096 + t0 + tq * 64];
    unsigned short* l = &Xb[p * 264 + tq * 64];
#pragma unroll
    for (int c = 0; c < 8; c++)
      *(uint4*)(l + c * 8) = *(const uint4*)(g + c * 8);
  }
  __syncthreads();
  float cum_i = cum_s[i];
  const float* cbrow = CBT + (long)bc * 65536 + (long)i * 256;
  int wv = tid >> 6, lane = tid & 63;
  int mr = lane & 15, koff = (lane >> 4) * 8;
  f32x4 acc[4][4];
#pragma unroll
  for (int mi = 0; mi < 4; mi++)
#pragma unroll
    for (int ni = 0; ni < 4; ni++) acc[mi][ni] = f32x4{0.f, 0.f, 0.f, 0.f};
  // ---------------- ydiag phase: K = 256 over j, 8 k-tiles
  for (int kt = 0; kt < 8; kt++) {
    int k0 = kt * 32;
#pragma unroll
    for (int c = 0; c < 8; c++) {
      float4 cb = *(const float4*)&cbrow[k0 + c * 4];
      ushort4 o;
      {
        int j = k0 + c * 4 + 0;
        float s = (j <= i) ? cb.x * expf(cum_i - cum_s[j]) * dt_s[j] : 0.f;
        o.x = f2h(s);
      }
      {
        int j = k0 + c * 4 + 1;
        float s = (j <= i) ? cb.y * expf(cum_i - cum_s[j]) * dt_s[j] : 0.f;
        o.y = f2h(s);
      }
      {
        int j = k0 + c * 4 + 2;
        float s = (j <= i) ? cb.z * expf(cum_i - cum_s[j]) * dt_s[j] : 0.f;
        o.z = f2h(s);
      }
      {
        int j = k0 + c * 4 + 3;
        float s = (j <= i) ? cb.w * expf(cum_i - cum_s[j]) * dt_s[j] : 0.f;
        o.w = f2h(s);
      }
      *(ushort4*)&Sb[i * 40 + c * 4] = o;
    }
    __syncthreads();
    if (kt <= 2 * wv + 1) {
      f16x8 af[4], bf[4];
#pragma unroll
      for (int mi = 0; mi < 4; mi++)
        af[mi] = *(const f16x8*)&Sb[(64 * wv + mi * 16 + mr) * 40 + koff];
#pragma unroll
      for (int ni = 0; ni < 4; ni++)
        bf[ni] = *(const f16x8*)&Xb[(ni * 16 + mr) * 264 + k0 + koff];
#pragma unroll
      for (int mi = 0; mi < 4; mi++)
#pragma unroll
        for (int ni = 0; ni < 4; ni++)
          acc[mi][ni] = __builtin_amdgcn_mfma_f32_16x16x32_f16(af[mi], bf[ni],
                                                               acc[mi][ni], 0, 0, 0);
    }
    __syncthreads();
  }
  // ---------------- yoff phase: stage PS16 into Xb (xT dead)
  {
    int p = tid >> 2, nq = tid & 3;
    const float* g = &states[((long)(bc * 64 + h)) * 8192 + p * 128 + nq * 32];
    unsigned short* l = &Xb[p * 136 + nq * 32];
#pragma unroll
    for (int c = 0; c < 8; c++) {
      float4 v = *(const float4*)(g + c * 4);
      ushort4 u;
      u.x = f2h(v.x); u.y = f2h(v.y); u.z = f2h(v.z); u.w = f2h(v.w);
      *(ushort4*)(l + c * 4) = u;
    }
  }
  float fac_i = expf(cum_i);
  for (int kn = 0; kn < 4; kn++) {
    {  // form Afac row i
      const unsigned short* g = &C16[((long)(t0 + i)) * 128 + kn * 32];
#pragma unroll
      for (int c = 0; c < 8; c++) {
        ushort4 u = *(const ushort4*)(g + c * 4);
        ushort4 o;
        o.x = f2h(h2f(u.x) * fac_i); o.y = f2h(h2f(u.y) * fac_i);
        o.z = f2h(h2f(u.z) * fac_i); o.w = f2h(h2f(u.w) * fac_i);
        *(ushort4*)&Sb[i * 40 + c * 4] = o;
      }
    }
    __syncthreads();
    f16x8 af[4], bf[4];
#pragma unroll
    for (int mi = 0; mi < 4; mi++)
      af[mi] = *(const f16x8*)&Sb[(64 * wv + mi * 16 + mr) * 40 + koff];
#pragma unroll
    for (int ni = 0; ni < 4; ni++)
      bf[ni] = *(const f16x8*)&Xb[(ni * 16 + mr) * 136 + kn * 32 + koff];
#pragma unroll
    for (int mi = 0; mi < 4; mi++)
#pragma unroll
      for (int ni = 0; ni < 4; ni++)
        acc[mi][ni] = __builtin_amdgcn_mfma_f32_16x16x32_f16(af[mi], bf[ni],
                                                             acc[mi][ni], 0, 0, 0);
    __syncthreads();
  }
  // epilogue: + D*x, store Ysum fp32
  float Dh = Dp[h];
  int cl = lane & 15, rq = (lane >> 4) * 4;
#pragma unroll
  for (int mi = 0; mi < 4; mi++)
#pragma unroll
    for (int r = 0; r < 4; r++) {
      long row = t0 + 64 * wv + mi * 16 + rq + r;
      float* yr = &Ysum[row * 4096 + h * 64];
      const unsigned short* xr = &x16[row * 4096 + h * 64];
#pragma unroll
      for (int ni = 0; ni < 4; ni++) {
        int p = ni * 16 + cl;
        yr[p] = acc[mi][ni][r] + Dh * h2f(xr[p]);
      }
    }
}

// ------------------------------------------------- gate*SiLU + RMSNorm -> fp16
__global__ __launch_bounds__(256) void norm_kernel(const float* __restrict__ Ysum,
                                                   const _Float16* __restrict__ gate,
                                                   const float* __restrict__ nw,
                                                   _Float16* __restrict__ hid) {
  int t = blockIdx.x;
  int tid = threadIdx.x;
  float hv[16];
  float ss = 0.f;
#pragma unroll
  for (int k = 0; k < 4; k++) {
    int d = tid * 4 + k * 1024;
    float4 y = *reinterpret_cast<const float4*>(&Ysum[(long)t * 4096 + d]);
    ushort4 gu = *reinterpret_cast<const ushort4*>(gate + (long)t * 4096 + d);
    float h0 = y.x * siluf(h2f(gu.x)), h1 = y.y * siluf(h2f(gu.y));
    float h2 = y.z * siluf(h2f(gu.z)), h3 = y.w * siluf(h2f(gu.w));
    hv[k * 4 + 0] = h0; hv[k * 4 + 1] = h1; hv[k * 4 + 2] = h2; hv[k * 4 + 3] = h3;
    ss += h0 * h0 + h1 * h1 + h2 * h2 + h3 * h3;
  }
#pragma unroll
  for (int o = 32; o > 0; o >>= 1) ss += __shfl_down(ss, o, 64);
  __shared__ float ws4[4];
  if ((tid & 63) == 0) ws4[tid >> 6] = ss;
  __syncthreads();
  float var = (ws4[0] + ws4[1] + ws4[2] + ws4[3]) * (1.f / 4096.f);
  float scale = rsqrtf(var + 1e-5f);
#pragma unroll
  for (int k = 0; k < 4; k++) {
    int d = tid * 4 + k * 1024;
    ushort4 u;
#pragma unroll
    for (int c = 0; c < 4; c++)
      ((unsigned short*)&u)[c] = f2h(hv[k * 4 + c] * scale * nw[d + c]);
    *reinterpret_cast<ushort4*>(hid + (long)t * 4096 + d) = u;
  }
}

// =============================================================== launch
extern "C" void kernel_launch(void* const* d_in, const int* in_sizes, int n_in,
                              void* d_out, int out_size, void* d_ws, size_t ws_size,
                              hipStream_t stream) {
  (void)in_sizes; (void)n_in; (void)out_size; (void)ws_size;
  const float* hs    = (const float*)d_in[0];
  const float* Win   = (const float*)d_in[1];
  const float* convw = (const float*)d_in[2];
  const float* convb = (const float*)d_in[3];
  const float* dtb   = (const float*)d_in[4];
  const float* Alog  = (const float*)d_in[5];
  const float* Dp    = (const float*)d_in[6];
  const float* nw    = (const float*)d_in[7];
  const float* Wout  = (const float*)d_in[8];
  float* out = (float*)d_out;

  char* base = (char*)d_ws;
  size_t off = 0;
  auto take = [&](size_t n) { char* r = base + off; off += (n + 255) & ~(size_t)255; return r; };
  float*    hbcf  = (float*)take(4096UL * 4352 * 4);    // gemm_in -> conv; then Ysum
  _Float16* gateh = (_Float16*)take(4096UL * 4096 * 2); // gemm_in -> norm
  _Float16* Ah    = (_Float16*)take(4096UL * 2048 * 2); // cast -> gemm_in; then WoutT
  _Float16* WtH   = (_Float16*)take(8448UL * 2048 * 2); // trans -> gemm_in; then x16
  _Float16* xT16  = (_Float16*)take(4096UL * 4096 * 2); // xtrans -> states/yfused
  _Float16* B16   = (_Float16*)take(4096UL * 128 * 2);
  _Float16* C16   = (_Float16*)take(4096UL * 128 * 2);
  float*    zf    = (float*)take(4096UL * 64 * 4);
  float*    dt_f  = (float*)take(4096UL * 64 * 4);
  float*    cum_f = (float*)take(4096UL * 64 * 4);
  float*    cuml  = (float*)take(16UL * 64 * 4);
  float*    CBT   = (float*)take(16UL * 256 * 256 * 4);
  float*    states= (float*)take(1024UL * 8192 * 4);    // -> prevs in-place; then hid
  // overlays:
  float*    Ysum  = hbcf;               // live yfused..norm
  _Float16* WoutT = Ah;                 // written after gemm_in
  _Float16* x16   = WtH;                // 33.6MB in 34.6MB, written by conv
  _Float16* hid   = (_Float16*)states;  // live norm..out_proj

  dim3 tb(32, 8);
  // 1. casts / transposes / exact dt slice
  cast_f16<<<8192, 256, 0, stream>>>(hs, Ah);
  transpose_win<<<dim3(264, 64), tb, 0, stream>>>(Win, WtH);
  dtz_kernel<<<1024, 256, 0, stream>>>(hs, Win, zf);
  // 2. fp16 in_proj GEMM (256^2 8-phase) -> gate (fp16) + hbc (fp32)
  gemm_in8<<<dim3(528), 512, 0, stream>>>(Ah, WtH, gateh, hbcf);
  // 3. out_proj weight transpose into dead Ah
  transpose_wout<<<dim3(64, 128), tb, 0, stream>>>(Wout, WoutT, 4096, 2048);
  // 4. conv + silu -> x16, B16, C16 (fp16)
  conv_silu_kernel<<<dim3(17, 4096), 256, 0, stream>>>(hbcf, convw, convb, x16, B16, C16);
  // 5. dt softplus + cumsum (fp32-exact)
  dt_cum_kernel<<<16, 256, 0, stream>>>(zf, dtb, Alog, dt_f, cum_f, cuml);
  // 6. x16 -> xT16 global transpose
  xtrans<<<dim3(64, 64), 256, 0, stream>>>((const unsigned short*)x16, (unsigned short*)xT16);
  // 7. CBT = C.B^T per chunk (fp16 MFMA, fp32 out)
  gemm_bt<<<dim3(2, 2, 16), 256, 0, stream>>>(C16, B16, CBT, 128, 256,
                                              32768, 32768, 65536);
  // 8. per-chunk states (fp16 MFMA, fp32 out)
  states_mfma<<<dim3(64, 16), 256, 0, stream>>>((const unsigned short*)xT16,
                                                (const unsigned short*)B16,
                                                dt_f, cum_f, cuml, states);
  // 9. inter-chunk recurrence (in-place, fp32)
  recur_kernel<<<128, 256, 0, stream>>>(states, cuml);
  // 10. fused Ydiag + Yoff + D*x -> Ysum (overlays dead hbcf)
  yfused<<<dim3(64, 16), 256, 0, stream>>>((const unsigned short*)xT16,
                                           (const unsigned short*)x16,
                                           (const unsigned short*)C16,
                                           CBT, states, dt_f, cum_f, Dp, Ysum);
  // 11. gate + RMSNorm -> hid fp16 (overlays dead states)
  norm_kernel<<<4096, 256, 0, stream>>>(Ysum, gateh, nw, hid);
  // 12. out_proj GEMM (fp16) -> d_out fp32
  gemm_bt<<<dim3(16, 32, 1), 256, 0, stream>>>(hid, WoutT, out, 4096, 2048, 0, 0, 0);
}

// Round 3
// 787.248 us; speedup vs baseline: 1.1454x; 1.0574x over previous
//
#include <hip/hip_runtime.h>
#include <hip/hip_bf16.h>

// Mamba2 mixer forward, MI355X. B=2, L=2048, D_MODEL=2048, H=64, P=64, N=128,
// G=1, K=4, CHUNK=256. T = 4096 tokens, 16 chunks.
// fp16 MFMA for: in_proj (8-phase 256^2, bank-uniform LDS swizzle), CBT, states,
// ydiag+yoff (fused), out_proj (8-phase 256^2 split-K). fp32 kept for: conv math,
// dt/cumsum (exact), inter-chunk recurrence, epilogues.

typedef __attribute__((ext_vector_type(8))) _Float16 f16x8;
typedef __attribute__((ext_vector_type(4))) float f32x4;

#define GLD16(gp, lp) __builtin_amdgcn_global_load_lds( \
    (__attribute__((address_space(1))) void*)(gp),      \
    (__attribute__((address_space(3))) void*)(lp), 16, 0, 0)

__device__ __forceinline__ unsigned short f2h(float v) {
  _Float16 h = (_Float16)v;
  return *reinterpret_cast<unsigned short*>(&h);
}
__device__ __forceinline__ float h2f(unsigned short u) {
  _Float16 h = *reinterpret_cast<_Float16*>(&u);
  return (float)h;
}
__device__ __forceinline__ float siluf(float x) { return x / (1.f + expf(-x)); }

// ---------------------------------------------------------------- cast X->fp16
__global__ __launch_bounds__(256) void cast_f16(const float* __restrict__ s,
                                                _Float16* __restrict__ d) {
  long i = ((long)blockIdx.x * 256 + threadIdx.x) * 4;
  float4 v = *reinterpret_cast<const float4*>(s + i);
  ushort4 u;
  u.x = f2h(v.x); u.y = f2h(v.y); u.z = f2h(v.z); u.w = f2h(v.w);
  *reinterpret_cast<ushort4*>(d + i) = u;
}

// --------------------------- transpose Win cols [0,8448) -> fp16 [n][k]
__global__ __launch_bounds__(256) void transpose_win(const float* __restrict__ src,
                                                     _Float16* __restrict__ dst) {
  __shared__ float tile[32][33];
  int c0 = blockIdx.x * 32, r0 = blockIdx.y * 32;
  int tx = threadIdx.x, ty = threadIdx.y;  // 32 x 8
#pragma unroll
  for (int i = 0; i < 4; i++)
    tile[ty + i * 8][tx] = src[(long)(r0 + ty + i * 8) * 8512 + c0 + tx];
  __syncthreads();
#pragma unroll
  for (int i = 0; i < 4; i++) {
    int c = c0 + ty + i * 8, r = r0 + tx;
    dst[(long)c * 2048 + r] = (_Float16)tile[tx][ty + i * 8];
  }
}

// ------------------ transpose+cast fp32 RxC -> fp16 [C][R] (for out_proj W)
__global__ __launch_bounds__(256) void transpose_wout(const float* __restrict__ src,
                                                      _Float16* __restrict__ dst,
                                                      int R, int C) {
  __shared__ float tile[32][33];
  int c0 = blockIdx.x * 32, r0 = blockIdx.y * 32;
  int tx = threadIdx.x, ty = threadIdx.y;
#pragma unroll
  for (int i = 0; i < 4; i++)
    tile[ty + i * 8][tx] = src[(long)(r0 + ty + i * 8) * C + c0 + tx];
  __syncthreads();
#pragma unroll
  for (int i = 0; i < 4; i++) {
    int c = c0 + ty + i * 8, r = r0 + tx;
    dst[(long)c * R + r] = (_Float16)tile[tx][ty + i * 8];
  }
}

// ===================== in_proj GEMM: 256^2 tile, BK=64, 8-wave 8-phase =======
// A[4096,2048] f16 row-major, Bt[8448,2048] f16 row-major (Win^T).
// C cols [0,4096) -> gate (fp16, ld 4096); cols [4096,8448) -> hbcf (fp32, ld 4352).
// LDS 128 KiB: 8 regions x 16 KiB (128 rows x 128B). Bank-uniform swizzle:
// physical col16 = logical col16 ^ (row & 7); every lane-octet of a b128 read
// covers all 8 column slots exactly once (zero excess bank cycles). Source is
// pre-swizzled (gload_lds writes linearly: row=tid>>3, col16=tid&7). The k32
// XOR is applied to the REGION-RELATIVE OFFSET (bit 6 of the offset comes only
// from col16*16), never to the flat pointer, so LDS base alignment is moot.
__global__ __launch_bounds__(512, 2) void gemm_in8(const _Float16* __restrict__ A,
                                                   const _Float16* __restrict__ Bt,
                                                   _Float16* __restrict__ gate,
                                                   float* __restrict__ hbcf) {
  __shared__ __attribute__((aligned(128))) char ldsB[131072];
  const int tid = threadIdx.x;
  const int lane = tid & 63;
  const int wv = tid >> 6;
  const int wr = wv >> 2, wc = wv & 3;  // 2 (M) x 4 (N) waves; wave C = 128x64
  // bijective XCD swizzle (grid 528 = 8*66)
  const int wg = blockIdx.x;
  const int swz = (wg & 7) * 66 + (wg >> 3);
  const int bx = swz % 33, by = swz / 33;  // bx: N-tile [0,33), by: M-tile [0,16)

  // -------- staging geometry: half-tile = 128 rows x 64 halfs (16 KiB),
  // 2 x GLD16/thread; dest row = tid>>3 (+64), dest col16 = tid&7.
  const int srow = tid >> 3;
  const int scolg = (tid & 7) ^ (srow & 7);  // inverse-swizzled source col16
  const _Float16* Ab = A + (long)by * 256 * 2048 + (long)srow * 2048 + scolg * 8;
  const _Float16* Bb = Bt + (long)bx * 256 * 2048 + (long)srow * 2048 + scolg * 8;
  const int ldst = tid << 4;

#define STAGE_A(tau, h) do {                                              \
    const _Float16* g_ = Ab + (long)(h) * 262144 + (tau) * 64;            \
    char* l_ = ldsB + ((((tau) & 1) << 2) + (h)) * 16384 + ldst;          \
    GLD16(g_, l_); GLD16(g_ + 131072, l_ + 8192); } while (0)
#define STAGE_B(tau, h) do {                                              \
    const _Float16* g_ = Bb + (long)(h) * 262144 + (tau) * 64;            \
    char* l_ = ldsB + ((((tau) & 1) << 2) + 2 + (h)) * 16384 + ldst;      \
    GLD16(g_, l_); GLD16(g_ + 131072, l_ + 8192); } while (0)

  // -------- fragment-read offsets (swizzled): col16 = (lane>>4 + 4*k32) ^ (fr&7);
  // k32 flips bit2 of col16 -> XOR the offset with 64.
  const int fr = lane & 15;
  const int c16 = (lane >> 4) ^ (fr & 7);
  const int aOff = wr * 16384 + fr * 128 + c16 * 16;
  const int bOff = (2 + (wc >> 1)) * 16384 + ((wc & 1) * 64 + fr) * 128 + c16 * 16;
#define RD_A(b, mi, k32) (*(const f16x8*)(ldsB + ((aOff + (b) * 65536 + (mi) * 2048) ^ ((k32) * 64))))
#define RD_B(b, ni, k32) (*(const f16x8*)(ldsB + ((bOff + (b) * 65536 + (ni) * 2048) ^ ((k32) * 64))))

#define BAR() __builtin_amdgcn_s_barrier()
#define WLG0() asm volatile("s_waitcnt lgkmcnt(0)" ::: "memory")
#define WLG8() asm volatile("s_waitcnt lgkmcnt(8)" ::: "memory")
#define WVM4() asm volatile("s_waitcnt vmcnt(4)" ::: "memory")

  f32x4 acc[8][4];
#pragma unroll
  for (int mi = 0; mi < 8; ++mi)
#pragma unroll
    for (int ni = 0; ni < 4; ++ni) acc[mi][ni] = f32x4{0.f, 0.f, 0.f, 0.f};

  // prologue: tile0 {A0,A1,B0,B1} + tile1 {B0,B1}; keep last 2 half-tiles in flight
  STAGE_A(0, 0); STAGE_A(0, 1); STAGE_B(0, 0); STAGE_B(0, 1);
  STAGE_B(1, 0); STAGE_B(1, 1);
  WVM4(); BAR();

#define MFMA_Q(MI0, MI1, x0, x1, x2, x3, PB)                                        \
  __builtin_amdgcn_s_setprio(1);                                                    \
  _Pragma("unroll") for (int ni = 0; ni < 4; ++ni) {                                \
    acc[MI0][ni] = __builtin_amdgcn_mfma_f32_16x16x32_f16(x0, PB[ni][0], acc[MI0][ni], 0, 0, 0); \
    acc[MI0][ni] = __builtin_amdgcn_mfma_f32_16x16x32_f16(x1, PB[ni][1], acc[MI0][ni], 0, 0, 0); \
    acc[MI1][ni] = __builtin_amdgcn_mfma_f32_16x16x32_f16(x2, PB[ni][0], acc[MI1][ni], 0, 0, 0); \
    acc[MI1][ni] = __builtin_amdgcn_mfma_f32_16x16x32_f16(x3, PB[ni][1], acc[MI1][ni], 0, 0, 0); \
  }                                                                                 \
  __builtin_amdgcn_s_setprio(0);

  // 32 K-tiles of 64; 2 tiles per iteration, 8 phases. Stage schedule:
  // p0:A0(t+1) p1:A1(t+1) p2:B0(t+2) p3:B1(t+2) p4:A0(t+2) p5:A1(t+2)
  // p6:B0(t+3) p7:B1(t+3); vmcnt(4) at end of p3/p7.
  for (int u = 0; u < 16; ++u) {
    const int t1 = 2 * u + 1;
    const int t2 = (2 * u + 2) & 31;  // wrap on last iter: harmless reload
    const int t3 = (2 * u + 3) & 31;
    // ---- p0 (tile 2u, buf0, quadrant 0) + B-frags for buf0
    f16x8 PB0[4][2];
#pragma unroll
    for (int ni = 0; ni < 4; ++ni) { PB0[ni][0] = RD_B(0, ni, 0); PB0[ni][1] = RD_B(0, ni, 1); }
    {
      f16x8 x0 = RD_A(0, 0, 0), x1 = RD_A(0, 0, 1), x2 = RD_A(0, 1, 0), x3 = RD_A(0, 1, 1);
      STAGE_A(t1, 0); WLG8(); BAR(); WLG0();
      MFMA_Q(0, 1, x0, x1, x2, x3, PB0) BAR();
    }
    // ---- p1
    {
      f16x8 x0 = RD_A(0, 2, 0), x1 = RD_A(0, 2, 1), x2 = RD_A(0, 3, 0), x3 = RD_A(0, 3, 1);
      STAGE_A(t1, 1); BAR(); WLG0();
      MFMA_Q(2, 3, x0, x1, x2, x3, PB0) BAR();
    }
    // ---- p2
    {
      f16x8 x0 = RD_A(0, 4, 0), x1 = RD_A(0, 4, 1), x2 = RD_A(0, 5, 0), x3 = RD_A(0, 5, 1);
      STAGE_B(t2, 0); BAR(); WLG0();
      MFMA_Q(4, 5, x0, x1, x2, x3, PB0) BAR();
    }
    // ---- p3
    {
      f16x8 x0 = RD_A(0, 6, 0), x1 = RD_A(0, 6, 1), x2 = RD_A(0, 7, 0), x3 = RD_A(0, 7, 1);
      STAGE_B(t2, 1); BAR(); WLG0();
      MFMA_Q(6, 7, x0, x1, x2, x3, PB0) WVM4(); BAR();
    }
    // ---- p4 (tile 2u+1, buf1, quadrant 0) + B-frags for buf1
    f16x8 PB1[4][2];
#pragma unroll
    for (int ni = 0; ni < 4; ++ni) { PB1[ni][0] = RD_B(1, ni, 0); PB1[ni][1] = RD_B(1, ni, 1); }
    {
      f16x8 x0 = RD_A(1, 0, 0), x1 = RD_A(1, 0, 1), x2 = RD_A(1, 1, 0), x3 = RD_A(1, 1, 1);
      STAGE_A(t2, 0); WLG8(); BAR(); WLG0();
      MFMA_Q(0, 1, x0, x1, x2, x3, PB1) BAR();
    }
    // ---- p5
    {
      f16x8 x0 = RD_A(1, 2, 0), x1 = RD_A(1, 2, 1), x2 = RD_A(1, 3, 0), x3 = RD_A(1, 3, 1);
      STAGE_A(t2, 1); BAR(); WLG0();
      MFMA_Q(2, 3, x0, x1, x2, x3, PB1) BAR();
    }
    // ---- p6
    {
      f16x8 x0 = RD_A(1, 4, 0), x1 = RD_A(1, 4, 1), x2 = RD_A(1, 5, 0), x3 = RD_A(1, 5, 1);
      STAGE_B(t3, 0); BAR(); WLG0();
      MFMA_Q(4, 5, x0, x1, x2, x3, PB1) BAR();
    }
    // ---- p7
    {
      f16x8 x0 = RD_A(1, 6, 0), x1 = RD_A(1, 6, 1), x2 = RD_A(1, 7, 0), x3 = RD_A(1, 7, 1);
      STAGE_B(t3, 1); BAR(); WLG0();
      MFMA_Q(6, 7, x0, x1, x2, x3, PB1) WVM4(); BAR();
    }
  }
  // -------- epilogue: block-uniform gate/hbcf split at bx == 16
  const int m0 = by * 256 + wr * 128;
  const int n0 = bx * 256 + wc * 64;
  const int cl = lane & 15, rq = (lane >> 4) * 4;
  if (bx < 16) {
#pragma unroll
    for (int mi = 0; mi < 8; ++mi)
#pragma unroll
      for (int r = 0; r < 4; ++r) {
        long rowoff = (long)(m0 + mi * 16 + rq + r) * 4096 + n0 + cl;
#pragma unroll
        for (int ni = 0; ni < 4; ++ni) gate[rowoff + ni * 16] = (_Float16)acc[mi][ni][r];
      }
  } else {
#pragma unroll
    for (int mi = 0; mi < 8; ++mi)
#pragma unroll
      for (int r = 0; r < 4; ++r) {
        long rowoff = (long)(m0 + mi * 16 + rq + r) * 4352 + (n0 - 4096) + cl;
#pragma unroll
        for (int ni = 0; ni < 4; ++ni) hbcf[rowoff + ni * 16] = acc[mi][ni][r];
      }
  }
#undef STAGE_A
#undef STAGE_B
#undef RD_A
#undef RD_B
}

// ===================== out_proj GEMM: 256^2 tile, split-K (z=2), 8-phase =====
// A = hid [4096,4096] f16, Bt = WoutT [2048,4096] f16. Each z-block computes a
// K-half (2048) partial into Cp[z] (fp32, ld 2048). grid 256 = 16 M x 8 N x 2 z
// -> exactly 1 block/CU, no tail. Same LDS layout/swizzle/schedule as gemm_in8.
__global__ __launch_bounds__(512, 2) void gemm_out8(const _Float16* __restrict__ A,
                                                    const _Float16* __restrict__ Bt,
                                                    float* __restrict__ Cp) {
  __shared__ __attribute__((aligned(128))) char ldsB[131072];
  const int tid = threadIdx.x;
  const int lane = tid & 63;
  const int wv = tid >> 6;
  const int wr = wv >> 2, wc = wv & 3;
  const int wg = blockIdx.x;
  const int z = wg >> 7;                 // K-half
  const int r7 = wg & 127;
  const int sw = (r7 & 7) * 16 + (r7 >> 3);  // XCD swizzle over 128
  const int by = sw >> 3, bx = sw & 7;

  const int srow = tid >> 3;
  const int scolg = (tid & 7) ^ (srow & 7);
  const _Float16* Ab = A + (long)by * 256 * 4096 + (long)z * 2048 +
                       (long)srow * 4096 + scolg * 8;
  const _Float16* Bb = Bt + (long)bx * 256 * 4096 + (long)z * 2048 +
                       (long)srow * 4096 + scolg * 8;
  const int ldst = tid << 4;

#define STAGE_A(tau, h) do {                                              \
    const _Float16* g_ = Ab + (long)(h) * 524288 + (tau) * 64;            \
    char* l_ = ldsB + ((((tau) & 1) << 2) + (h)) * 16384 + ldst;          \
    GLD16(g_, l_); GLD16(g_ + 262144, l_ + 8192); } while (0)
#define STAGE_B(tau, h) do {                                              \
    const _Float16* g_ = Bb + (long)(h) * 524288 + (tau) * 64;            \
    char* l_ = ldsB + ((((tau) & 1) << 2) + 2 + (h)) * 16384 + ldst;      \
    GLD16(g_, l_); GLD16(g_ + 262144, l_ + 8192); } while (0)

  const int fr = lane & 15;
  const int c16 = (lane >> 4) ^ (fr & 7);
  const int aOff = wr * 16384 + fr * 128 + c16 * 16;
  const int bOff = (2 + (wc >> 1)) * 16384 + ((wc & 1) * 64 + fr) * 128 + c16 * 16;
#define RD_A(b, mi, k32) (*(const f16x8*)(ldsB + ((aOff + (b) * 65536 + (mi) * 2048) ^ ((k32) * 64))))
#define RD_B(b, ni, k32) (*(const f16x8*)(ldsB + ((bOff + (b) * 65536 + (ni) * 2048) ^ ((k32) * 64))))

  f32x4 acc[8][4];
#pragma unroll
  for (int mi = 0; mi < 8; ++mi)
#pragma unroll
    for (int ni = 0; ni < 4; ++ni) acc[mi][ni] = f32x4{0.f, 0.f, 0.f, 0.f};

  STAGE_A(0, 0); STAGE_A(0, 1); STAGE_B(0, 0); STAGE_B(0, 1);
  STAGE_B(1, 0); STAGE_B(1, 1);
  WVM4(); BAR();

  for (int u = 0; u < 16; ++u) {
    const int t1 = 2 * u + 1;
    const int t2 = (2 * u + 2) & 31;
    const int t3 = (2 * u + 3) & 31;
    f16x8 PB0[4][2];
#pragma unroll
    for (int ni = 0; ni < 4; ++ni) { PB0[ni][0] = RD_B(0, ni, 0); PB0[ni][1] = RD_B(0, ni, 1); }
    {
      f16x8 x0 = RD_A(0, 0, 0), x1 = RD_A(0, 0, 1), x2 = RD_A(0, 1, 0), x3 = RD_A(0, 1, 1);
      STAGE_A(t1, 0); WLG8(); BAR(); WLG0();
      MFMA_Q(0, 1, x0, x1, x2, x3, PB0) BAR();
    }
    {
      f16x8 x0 = RD_A(0, 2, 0), x1 = RD_A(0, 2, 1), x2 = RD_A(0, 3, 0), x3 = RD_A(0, 3, 1);
      STAGE_A(t1, 1); BAR(); WLG0();
      MFMA_Q(2, 3, x0, x1, x2, x3, PB0) BAR();
    }
    {
      f16x8 x0 = RD_A(0, 4, 0), x1 = RD_A(0, 4, 1), x2 = RD_A(0, 5, 0), x3 = RD_A(0, 5, 1);
      STAGE_B(t2, 0); BAR(); WLG0();
      MFMA_Q(4, 5, x0, x1, x2, x3, PB0) BAR();
    }
    {
      f16x8 x0 = RD_A(0, 6, 0), x1 = RD_A(0, 6, 1), x2 = RD_A(0, 7, 0), x3 = RD_A(0, 7, 1);
      STAGE_B(t2, 1); BAR(); WLG0();
      MFMA_Q(6, 7, x0, x1, x2, x3, PB0) WVM4(); BAR();
    }
    f16x8 PB1[4][2];
#pragma unroll
    for (int ni = 0; ni < 4; ++ni) { PB1[ni][0] = RD_B(1, ni, 0); PB1[ni][1] = RD_B(1, ni, 1); }
    {
      f16x8 x0 = RD_A(1, 0, 0), x1 = RD_A(1, 0, 1), x2 = RD_A(1, 1, 0), x3 = RD_A(1, 1, 1);
      STAGE_A(t2, 0); WLG8(); BAR(); WLG0();
      MFMA_Q(0, 1, x0, x1, x2, x3, PB1) BAR();
    }
    {
      f16x8 x0 = RD_A(1, 2, 0), x1 = RD_A(1, 2, 1), x2 = RD_A(1, 3, 0), x3 = RD_A(1, 3, 1);
      STAGE_A(t2, 1); BAR(); WLG0();
      MFMA_Q(2, 3, x0, x1, x2, x3, PB1) BAR();
    }
    {
      f16x8 x0 = RD_A(1, 4, 0), x1 = RD_A(1, 4, 1), x2 = RD_A(1, 5, 0), x3 = RD_A(1, 5, 1);
      STAGE_B(t3, 0); BAR(); WLG0();
      MFMA_Q(4, 5, x0, x1, x2, x3, PB1) BAR();
    }
    {
      f16x8 x0 = RD_A(1, 6, 0), x1 = RD_A(1, 6, 1), x2 = RD_A(1, 7, 0), x3 = RD_A(1, 7, 1);
      STAGE_B(t3, 1); BAR(); WLG0();
      MFMA_Q(6, 7, x0, x1, x2, x3, PB1) WVM4(); BAR();
    }
  }
  const int m0 = by * 256 + wr * 128;
  const int n0 = bx * 256 + wc * 64;
  const int cl = lane & 15, rq = (lane >> 4) * 4;
  float* Cb = Cp + (long)z * 8388608;
#pragma unroll
  for (int mi = 0; mi < 8; ++mi)
#pragma unroll
    for (int r = 0; r < 4; ++r) {
      long rowoff = (long)(m0 + mi * 16 + rq + r) * 2048 + n0 + cl;
#pragma unroll
      for (int ni = 0; ni < 4; ++ni) Cb[rowoff + ni * 16] = acc[mi][ni][r];
    }
#undef STAGE_A
#undef STAGE_B
#undef RD_A
#undef RD_B
#undef BAR
#undef WLG0
#undef WLG8
#undef WVM4
#undef MFMA_Q
}

// -------------------------------------------- sum the two split-K partials
__global__ __launch_bounds__(256) void add_out(const float* __restrict__ p,
                                               float* __restrict__ o) {
  long i = ((long)blockIdx.x * 256 + threadIdx.x) * 4;
  float4 a = *reinterpret_cast<const float4*>(p + i);
  float4 b = *reinterpret_cast<const float4*>(p + 8388608 + i);
  float4 r;
  r.x = a.x + b.x; r.y = a.y + b.y; r.z = a.z + b.z; r.w = a.w + b.w;
  *reinterpret_cast<float4*>(o + i) = r;
}

// --------------------------- fp16 GEMM (B^T), z-batched, fp32 out (CBT only)
__global__ __launch_bounds__(256) void gemm_bt(const _Float16* __restrict__ A,
                                               const _Float16* __restrict__ Bt,
                                               float* __restrict__ Cf,
                                               int K, int ldc,
                                               long zsA, long zsB, long zsC) {
  __shared__ uint4 As4[512];
  __shared__ uint4 Bs4[512];
  _Float16* As = (_Float16*)As4;
  _Float16* Bs = (_Float16*)Bs4;
  const int tid = threadIdx.x;
  const int wv = tid >> 6;
  const int lane = tid & 63;
  const _Float16* Ab = A + (long)blockIdx.z * zsA + (long)blockIdx.y * 128 * K;
  const _Float16* Bb = Bt + (long)blockIdx.z * zsB + (long)blockIdx.x * 128 * K;
  const int c0 = wv * 128 + lane;
  const int c1 = c0 + 64;
  const long ra0 = (long)(c0 >> 2) * K + (c0 & 3) * 8;
  const long ra1 = (long)(c1 >> 2) * K + (c1 & 3) * 8;
  f32x4 acc[4][4];
#pragma unroll
  for (int mi = 0; mi < 4; mi++)
#pragma unroll
    for (int ni = 0; ni < 4; ni++) acc[mi][ni] = f32x4{0.f, 0.f, 0.f, 0.f};
  const int mrow = (wv & 1) * 64 + (lane & 15);
  const int nrow = (wv >> 1) * 64 + (lane & 15);
  const int koff = (lane >> 4) * 8;
  for (int k0 = 0; k0 < K; k0 += 32) {
    GLD16(Ab + ra0 + k0, (char*)As + c0 * 16);
    GLD16(Ab + ra1 + k0, (char*)As + c1 * 16);
    GLD16(Bb + ra0 + k0, (char*)Bs + c0 * 16);
    GLD16(Bb + ra1 + k0, (char*)Bs + c1 * 16);
    __syncthreads();
    f16x8 af[4], bfr[4];
#pragma unroll
    for (int mi = 0; mi < 4; mi++)
      af[mi] = *(const f16x8*)(As + (mrow + mi * 16) * 32 + koff);
#pragma unroll
    for (int ni = 0; ni < 4; ni++)
      bfr[ni] = *(const f16x8*)(Bs + (nrow + ni * 16) * 32 + koff);
#pragma unroll
    for (int mi = 0; mi < 4; mi++)
#pragma unroll
      for (int ni = 0; ni < 4; ni++)
        acc[mi][ni] = __builtin_amdgcn_mfma_f32_16x16x32_f16(af[mi], bfr[ni],
                                                             acc[mi][ni], 0, 0, 0);
    __syncthreads();
  }
  const int m0 = blockIdx.y * 128 + (wv & 1) * 64;
  const int n0 = blockIdx.x * 128 + (wv >> 1) * 64;
  const int cl = lane & 15, rq = (lane >> 4) * 4;
  const long zc = (long)blockIdx.z * zsC;
#pragma unroll
  for (int mi = 0; mi < 4; mi++)
#pragma unroll
    for (int r = 0; r < 4; r++) {
      long rowoff = zc + (long)(m0 + mi * 16 + rq + r) * ldc + n0 + cl;
#pragma unroll
      for (int ni = 0; ni < 4; ni++) Cf[rowoff + ni * 16] = acc[mi][ni][r];
    }
}

// ---------------------------------------- fp32 dt pre-activation (exact slice)
__global__ __launch_bounds__(256) void dtz_kernel(const float* __restrict__ hs,
                                                  const float* __restrict__ Win,
                                                  float* __restrict__ zf) {
  __shared__ float Xs[4][2048];
  int t0 = blockIdx.x * 4;
  int tid = threadIdx.x;
#pragma unroll
  for (int i = 0; i < 8; i++) {
    int e = tid * 4 + i * 1024;
    int tok = e >> 11, k = e & 2047;
    *reinterpret_cast<float4*>(&Xs[tok][k]) =
        *reinterpret_cast<const float4*>(&hs[(long)(t0 + tok) * 2048 + k]);
  }
  __syncthreads();
  int h = tid & 63, tg = tid >> 6;
  float a0 = 0.f, a1 = 0.f, a2 = 0.f, a3 = 0.f;
  const float* wcol = Win + 8448 + h;
  for (int k = 0; k < 2048; k += 4) {
    a0 = fmaf(Xs[tg][k + 0], wcol[(long)(k + 0) * 8512], a0);
    a1 = fmaf(Xs[tg][k + 1], wcol[(long)(k + 1) * 8512], a1);
    a2 = fmaf(Xs[tg][k + 2], wcol[(long)(k + 2) * 8512], a2);
    a3 = fmaf(Xs[tg][k + 3], wcol[(long)(k + 3) * 8512], a3);
  }
  zf[(long)(t0 + tg) * 64 + h] = (a0 + a1) + (a2 + a3);
}

// --------------------------- conv(K=4)+SiLU (fp32 math, fp16 out) -> x16,B16,C16
__global__ __launch_bounds__(256) void conv_silu_kernel(const float* __restrict__ hbcf,
                                                        const float* __restrict__ convw,
                                                        const float* __restrict__ convb,
                                                        _Float16* __restrict__ x16,
                                                        _Float16* __restrict__ B16,
                                                        _Float16* __restrict__ C16) {
  int q = blockIdx.x * 256 + threadIdx.x;  // [0,4352)
  int t = blockIdx.y;                      // [0,4096)
  int l = t & 2047;
  const float* col = hbcf + (long)t * 4352 + q;
  float4 wq = *reinterpret_cast<const float4*>(convw + q * 4);
  float a = convb[q];
  if (l >= 3) a += col[-3 * 4352] * wq.x;
  if (l >= 2) a += col[-2 * 4352] * wq.y;
  if (l >= 1) a += col[-1 * 4352] * wq.z;
  a += col[0] * wq.w;
  _Float16 o = (_Float16)siluf(a);
  if (q < 4096) x16[(long)t * 4096 + q] = o;
  else if (q < 4224) B16[(long)t * 128 + (q - 4096)] = o;
  else C16[(long)t * 128 + (q - 4224)] = o;
}

// ------------------------------------------- global transpose x16 -> xT16 [q][t]
__global__ __launch_bounds__(256) void xtrans(const unsigned short* __restrict__ src,
                                              unsigned short* __restrict__ dst) {
  __shared__ unsigned short tile[64][66];
  int c0 = blockIdx.x * 64, r0 = blockIdx.y * 64;
  int tx = threadIdx.x & 15, ty = threadIdx.x >> 4;  // 16 x 16
#pragma unroll
  for (int i = 0; i < 4; i++) {
    int r = ty + i * 16;
    ushort4 v = *(const ushort4*)&src[(long)(r0 + r) * 4096 + c0 + 4 * tx];
    tile[r][4 * tx] = v.x; tile[r][4 * tx + 1] = v.y;
    tile[r][4 * tx + 2] = v.z; tile[r][4 * tx + 3] = v.w;
  }
  __syncthreads();
#pragma unroll
  for (int i = 0; i < 4; i++) {
    int c = ty + i * 16;
    ushort4 v;
    v.x = tile[4 * tx + 0][c]; v.y = tile[4 * tx + 1][c];
    v.z = tile[4 * tx + 2][c]; v.w = tile[4 * tx + 3][c];
    *(ushort4*)&dst[(long)(c0 + c) * 4096 + r0 + 4 * tx] = v;
  }
}

// ------------------------------------------------- dt softplus + chunk cumsum
__global__ __launch_bounds__(256) void dt_cum_kernel(const float* __restrict__ zf,
                                                     const float* __restrict__ dtb,
                                                     const float* __restrict__ Alog,
                                                     float* __restrict__ dt_f,
                                                     float* __restrict__ cum_f,
                                                     float* __restrict__ cuml) {
  int bc = blockIdx.x;
  int h = threadIdx.x & 63, seg = threadIdx.x >> 6;
  int t0 = bc * 256;
  float Ah = -expf(Alog[h]);
  float bias = dtb[h];
  __shared__ float segsum[4][64];
  float s = 0.f;
  for (int j = 0; j < 64; j++) {
    int t = t0 + seg * 64 + j;
    float z = zf[(long)t * 64 + h] + bias;
    float v = (z > 20.f) ? z : log1pf(expf(z));
    dt_f[(long)t * 64 + h] = v;
    s += v * Ah;
  }
  segsum[seg][h] = s;
  __syncthreads();
  float run = 0.f;
  for (int k = 0; k < seg; k++) run += segsum[k][h];
  for (int j = 0; j < 64; j++) {
    int t = t0 + seg * 64 + j;
    run += dt_f[(long)t * 64 + h] * Ah;
    cum_f[(long)t * 64 + h] = run;
  }
  if (seg == 3) cuml[bc * 64 + h] = run;
}

// --------------------------------- states via MFMA: states[bc,h,p,n] (64x128)
// states[p][n] = sum_t (w_t * x[t][p]) * B[t][n];  w folded into A-operand.
__global__ __launch_bounds__(256) void states_mfma(const unsigned short* __restrict__ xT16,
                                                   const unsigned short* __restrict__ B16,
                                                   const float* __restrict__ dt_f,
                                                   const float* __restrict__ cum_f,
                                                   const float* __restrict__ cuml,
                                                   float* __restrict__ states) {
  int h = blockIdx.x, bc = blockIdx.y;
  int t0 = bc * 256, tid = threadIdx.x;
  __shared__ float w_s[256];
  __shared__ unsigned short Aw[64 * 40];   // [p][tt] pad 40
  __shared__ unsigned short BT[128 * 40];  // [n][tt] pad 40
  {
    int t = t0 + tid;
    w_s[tid] = expf(cuml[bc * 64 + h] - cum_f[(long)t * 64 + h]) * dt_f[(long)t * 64 + h];
  }
  __syncthreads();
  int wv = tid >> 6, lane = tid & 63;
  int mr = lane & 15, koff = (lane >> 4) * 8;
  f32x4 acc[4][2];
#pragma unroll
  for (int mi = 0; mi < 4; mi++)
#pragma unroll
    for (int nj = 0; nj < 2; nj++) acc[mi][nj] = f32x4{0.f, 0.f, 0.f, 0.f};
  for (int kt = 0; kt < 8; kt++) {
    {  // form Aw: thread = p*4 + tq, 8 t-elems each
      int p = tid >> 2, tq = tid & 3;
      const unsigned short* g = &xT16[((long)(h * 64 + p)) * 4096 + t0 + kt * 32 + tq * 8];
      ushort4 u0 = *(const ushort4*)g, u1 = *(const ushort4*)(g + 4);
      const float* wp = &w_s[kt * 32 + tq * 8];
      ushort4 o0, o1;
      o0.x = f2h(h2f(u0.x) * wp[0]); o0.y = f2h(h2f(u0.y) * wp[1]);
      o0.z = f2h(h2f(u0.z) * wp[2]); o0.w = f2h(h2f(u0.w) * wp[3]);
      o1.x = f2h(h2f(u1.x) * wp[4]); o1.y = f2h(h2f(u1.y) * wp[5]);
      o1.z = f2h(h2f(u1.z) * wp[6]); o1.w = f2h(h2f(u1.w) * wp[7]);
      *(ushort4*)&Aw[p * 40 + tq * 8] = o0;
      *(ushort4*)&Aw[p * 40 + tq * 8 + 4] = o1;
    }
    {  // form BT: thread = tl*8 + ng; copy B16[t][n] -> BT[n][tl]
      int tl = tid >> 3, ng = tid & 7;
      const unsigned short* g = &B16[((long)(t0 + kt * 32 + tl)) * 128 + ng * 16];
#pragma unroll
      for (int j = 0; j < 16; j++) BT[(ng * 16 + j) * 40 + tl] = g[j];
    }
    __syncthreads();
    f16x8 af[4], bf[2];
#pragma unroll
    for (int mi = 0; mi < 4; mi++)
      af[mi] = *(const f16x8*)&Aw[(mi * 16 + mr) * 40 + koff];
#pragma unroll
    for (int nj = 0; nj < 2; nj++)
      bf[nj] = *(const f16x8*)&BT[((wv * 2 + nj) * 16 + mr) * 40 + koff];
#pragma unroll
    for (int mi = 0; mi < 4; mi++)
#pragma unroll
      for (int nj = 0; nj < 2; nj++)
        acc[mi][nj] = __builtin_amdgcn_mfma_f32_16x16x32_f16(af[mi], bf[nj],
                                                             acc[mi][nj], 0, 0, 0);
    __syncthreads();
  }
  int cl = lane & 15, rq = (lane >> 4) * 4;
  long base = ((long)(bc * 64 + h)) * 8192;
#pragma unroll
  for (int mi = 0; mi < 4; mi++)
#pragma unroll
    for (int r = 0; r < 4; r++) {
      int p = mi * 16 + rq + r;
#pragma unroll
      for (int nj = 0; nj < 2; nj++) {
        int n = (wv * 2 + nj) * 16 + cl;
        states[base + p * 128 + n] = acc[mi][nj][r];
      }
    }
}

// --------------------------------- inter-chunk recurrence (in-place -> prevs)
__global__ __launch_bounds__(256) void recur_kernel(float* __restrict__ states,
                                                    const float* __restrict__ cuml) {
  int bh = blockIdx.x;
  int b = bh >> 6, h = bh & 63;
  int tid = threadIdx.x;
  float4 prev[8];
#pragma unroll
  for (int j = 0; j < 8; j++) prev[j] = make_float4(0.f, 0.f, 0.f, 0.f);
  for (int c = 0; c < 8; c++) {
    int bc = b * 8 + c;
    float cd = expf(cuml[bc * 64 + h]);
    long base = (long)(bc * 64 + h) * 8192;
#pragma unroll
    for (int j = 0; j < 8; j++) {
      long o = base + j * 1024 + tid * 4;
      float4 st = *reinterpret_cast<const float4*>(&states[o]);
      *reinterpret_cast<float4*>(&states[o]) = prev[j];
      prev[j].x = fmaf(cd, prev[j].x, st.x);
      prev[j].y = fmaf(cd, prev[j].y, st.y);
      prev[j].z = fmaf(cd, prev[j].z, st.z);
      prev[j].w = fmaf(cd, prev[j].w, st.w);
    }
  }
}

// ---------------- fused Y = Ydiag + Yoff + D*x  via MFMA, per (h, bc) block
// Ydiag[i][p] = sum_j S[i][j]*x[j][p],  S = CBT*exp(cum_i-cum_j)*dt_j, causal.
// Yoff[i][p]  = sum_n (C[i][n]*fac_i)*PS[p][n],  fac_i = exp(cum_i).
__global__ __launch_bounds__(256) void yfused(const unsigned short* __restrict__ xT16,
                                              const unsigned short* __restrict__ x16,
                                              const unsigned short* __restrict__ C16,
                                              const float* __restrict__ CBT,
                                              const float* __restrict__ states,
                                              const float* __restrict__ dt_f,
                                              const float* __restrict__ cum_f,
                                              const float* __restrict__ Dp,
                                              float* __restrict__ Ysum) {
  int h = blockIdx.x, bc = blockIdx.y;
  int t0 = bc * 256, tid = threadIdx.x;
  __shared__ unsigned short Sb[256 * 40];   // S / Afac tile [256][32] pad 40
  __shared__ unsigned short Xb[64 * 264];   // xT [64][256] pad 264; later PS16 [64][136]
  __shared__ float cum_s[256], dt_s[256];
  int i = tid;
  cum_s[i] = cum_f[(long)(t0 + i) * 64 + h];
  dt_s[i] = dt_f[(long)(t0 + i) * 64 + h];
  {  // stage xT tile: thread = p*4 + tq, 64 t-elems each
    int p = tid >> 2, tq = tid & 3;
    const unsigned short* g = &xT16[((long)(h * 64 + p)) * 4096 + t0 + tq * 64];
    unsigned short* l = &Xb[p * 264 + tq * 64];
#pragma unroll
    for (int c = 0; c < 8; c++)
      *(uint4*)(l + c * 8) = *(const uint4*)(g + c * 8);
  }
  __syncthreads();
  float cum_i = cum_s[i];
  const float* cbrow = CBT + (long)bc * 65536 + (long)i * 256;
  int wv = tid >> 6, lane = tid & 63;
  int mr = lane & 15, koff = (lane >> 4) * 8;
  f32x4 acc[4][4];
#pragma unroll
  for (int mi = 0; mi < 4; mi++)
#pragma unroll
    for (int ni = 0; ni < 4; ni++) acc[mi][ni] = f32x4{0.f, 0.f, 0.f, 0.f};
  // ---------------- ydiag phase: K = 256 over j, 8 k-tiles
  for (int kt = 0; kt < 8; kt++) {
    int k0 = kt * 32;
#pragma unroll
    for (int c = 0; c < 8; c++) {
      float4 cb = *(const float4*)&cbrow[k0 + c * 4];
      ushort4 o;
      {
        int j = k0 + c * 4 + 0;
        float s = (j <= i) ? cb.x * expf(cum_i - cum_s[j]) * dt_s[j] : 0.f;
        o.x = f2h(s);
      }
      {
        int j = k0 + c * 4 + 1;
        float s = (j <= i) ? cb.y * expf(cum_i - cum_s[j]) * dt_s[j] : 0.f;
        o.y = f2h(s);
      }
      {
        int j = k0 + c * 4 + 2;
        float s = (j <= i) ? cb.z * expf(cum_i - cum_s[j]) * dt_s[j] : 0.f;
        o.z = f2h(s);
      }
      {
        int j = k0 + c * 4 + 3;
        float s = (j <= i) ? cb.w * expf(cum_i - cum_s[j]) * dt_s[j] : 0.f;
        o.w = f2h(s);
      }
      *(ushort4*)&Sb[i * 40 + c * 4] = o;
    }
    __syncthreads();
    if (kt <= 2 * wv + 1) {
      f16x8 af[4], bf[4];
#pragma unroll
      for (int mi = 0; mi < 4; mi++)
        af[mi] = *(const f16x8*)&Sb[(64 * wv + mi * 16 + mr) * 40 + koff];
#pragma unroll
      for (int ni = 0; ni < 4; ni++)
        bf[ni] = *(const f16x8*)&Xb[(ni * 16 + mr) * 264 + k0 + koff];
#pragma unroll
      for (int mi = 0; mi < 4; mi++)
#pragma unroll
        for (int ni = 0; ni < 4; ni++)
          acc[mi][ni] = __builtin_amdgcn_mfma_f32_16x16x32_f16(af[mi], bf[ni],
                                                               acc[mi][ni], 0, 0, 0);
    }
    __syncthreads();
  }
  // ---------------- yoff phase: stage PS16 into Xb (xT dead)
  {
    int p = tid >> 2, nq = tid & 3;
    const float* g = &states[((long)(bc * 64 + h)) * 8192 + p * 128 + nq * 32];
    unsigned short* l = &Xb[p * 136 + nq * 32];
#pragma unroll
    for (int c = 0; c < 8; c++) {
      float4 v = *(const float4*)(g + c * 4);
      ushort4 u;
      u.x = f2h(v.x); u.y = f2h(v.y); u.z = f2h(v.z); u.w = f2h(v.w);
      *(ushort4*)(l + c * 4) = u;
    }
  }
  float fac_i = expf(cum_i);
  for (int kn = 0; kn < 4; kn++) {
    {  // form Afac row i
      const unsigned short* g = &C16[((long)(t0 + i)) * 128 + kn * 32];
#pragma unroll
      for (int c = 0; c < 8; c++) {
        ushort4 u = *(const ushort4*)(g + c * 4);
        ushort4 o;
        o.x = f2h(h2f(u.x) * fac_i); o.y = f2h(h2f(u.y) * fac_i);
        o.z = f2h(h2f(u.z) * fac_i); o.w = f2h(h2f(u.w) * fac_i);
        *(ushort4*)&Sb[i * 40 + c * 4] = o;
      }
    }
    __syncthreads();
    f16x8 af[4], bf[4];
#pragma unroll
    for (int mi = 0; mi < 4; mi++)
      af[mi] = *(const f16x8*)&Sb[(64 * wv + mi * 16 + mr) * 40 + koff];
#pragma unroll
    for (int ni = 0; ni < 4; ni++)
      bf[ni] = *(const f16x8*)&Xb[(ni * 16 + mr) * 136 + kn * 32 + koff];
#pragma unroll
    for (int mi = 0; mi < 4; mi++)
#pragma unroll
      for (int ni = 0; ni < 4; ni++)
        acc[mi][ni] = __builtin_amdgcn_mfma_f32_16x16x32_f16(af[mi], bf[ni],
                                                             acc[mi][ni], 0, 0, 0);
    __syncthreads();
  }
  // epilogue: + D*x, store Ysum fp32
  float Dh = Dp[h];
  int cl = lane & 15, rq = (lane >> 4) * 4;
#pragma unroll
  for (int mi = 0; mi < 4; mi++)
#pragma unroll
    for (int r = 0; r < 4; r++) {
      long row = t0 + 64 * wv + mi * 16 + rq + r;
      float* yr = &Ysum[row * 4096 + h * 64];
      const unsigned short* xr = &x16[row * 4096 + h * 64];
#pragma unroll
      for (int ni = 0; ni < 4; ni++) {
        int p = ni * 16 + cl;
        yr[p] = acc[mi][ni][r] + Dh * h2f(xr[p]);
      }
    }
}

// ------------------------------------------------- gate*SiLU + RMSNorm -> fp16
__global__ __launch_bounds__(256) void norm_kernel(const float* __restrict__ Ysum,
                                                   const _Float16* __restrict__ gate,
                                                   const float* __restrict__ nw,
                                                   _Float16* __restrict__ hid) {
  int t = blockIdx.x;
  int tid = threadIdx.x;
  float hv[16];
  float ss = 0.f;
#pragma unroll
  for (int k = 0; k < 4; k++) {
    int d = tid * 4 + k * 1024;
    float4 y = *reinterpret_cast<const float4*>(&Ysum[(long)t * 4096 + d]);
    ushort4 gu = *reinterpret_cast<const ushort4*>(gate + (long)t * 4096 + d);
    float h0 = y.x * siluf(h2f(gu.x)), h1 = y.y * siluf(h2f(gu.y));
    float h2 = y.z * siluf(h2f(gu.z)), h3 = y.w * siluf(h2f(gu.w));
    hv[k * 4 + 0] = h0; hv[k * 4 + 1] = h1; hv[k * 4 + 2] = h2; hv[k * 4 + 3] = h3;
    ss += h0 * h0 + h1 * h1 + h2 * h2 + h3 * h3;
  }
#pragma unroll
  for (int o = 32; o > 0; o >>= 1) ss += __shfl_down(ss, o, 64);
  __shared__ float ws4[4];
  if ((tid & 63) == 0) ws4[tid >> 6] = ss;
  __syncthreads();
  float var = (ws4[0] + ws4[1] + ws4[2] + ws4[3]) * (1.f / 4096.f);
  float scale = rsqrtf(var + 1e-5f);
#pragma unroll
  for (int k = 0; k < 4; k++) {
    int d = tid * 4 + k * 1024;
    ushort4 u;
#pragma unroll
    for (int c = 0; c < 4; c++)
      ((unsigned short*)&u)[c] = f2h(hv[k * 4 + c] * scale * nw[d + c]);
    *reinterpret_cast<ushort4*>(hid + (long)t * 4096 + d) = u;
  }
}

// =============================================================== launch
extern "C" void kernel_launch(void* const* d_in, const int* in_sizes, int n_in,
                              void* d_out, int out_size, void* d_ws, size_t ws_size,
                              hipStream_t stream) {
  (void)in_sizes; (void)n_in; (void)out_size; (void)ws_size;
  const float* hs    = (const float*)d_in[0];
  const float* Win   = (const float*)d_in[1];
  const float* convw = (const float*)d_in[2];
  const float* convb = (const float*)d_in[3];
  const float* dtb   = (const float*)d_in[4];
  const float* Alog  = (const float*)d_in[5];
  const float* Dp    = (const float*)d_in[6];
  const float* nw    = (const float*)d_in[7];
  const float* Wout  = (const float*)d_in[8];
  float* out = (float*)d_out;

  char* base = (char*)d_ws;
  size_t off = 0;
  auto take = [&](size_t n) { char* r = base + off; off += (n + 255) & ~(size_t)255; return r; };
  float*    hbcf  = (float*)take(4096UL * 4352 * 4);    // gemm_in -> conv; then Ysum; then out-partials
  _Float16* gateh = (_Float16*)take(4096UL * 4096 * 2); // gemm_in -> norm
  _Float16* Ah    = (_Float16*)take(4096UL * 2048 * 2); // cast -> gemm_in; then WoutT
  _Float16* WtH   = (_Float16*)take(8448UL * 2048 * 2); // trans -> gemm_in; then x16
  _Float16* xT16  = (_Float16*)take(4096UL * 4096 * 2); // xtrans -> states/yfused
  _Float16* B16   = (_Float16*)take(4096UL * 128 * 2);
  _Float16* C16   = (_Float16*)take(4096UL * 128 * 2);
  float*    zf    = (float*)take(4096UL * 64 * 4);
  float*    dt_f  = (float*)take(4096UL * 64 * 4);
  float*    cum_f = (float*)take(4096UL * 64 * 4);
  float*    cuml  = (float*)take(16UL * 64 * 4);
  float*    CBT   = (float*)take(16UL * 256 * 256 * 4);
  float*    states= (float*)take(1024UL * 8192 * 4);    // -> prevs in-place; then hid
  // overlays:
  float*    Ysum  = hbcf;               // live yfused..norm
  float*    oparts= hbcf;               // live gemm_out8..add_out (2 x 33.5MB in 71MB)
  _Float16* WoutT = Ah;                 // written after gemm_in
  _Float16* x16   = WtH;                // 33.6MB in 34.6MB, written by conv
  _Float16* hid   = (_Float16*)states;  // live norm..out_proj

  dim3 tb(32, 8);
  // 1. casts / transposes / exact dt slice
  cast_f16<<<8192, 256, 0, stream>>>(hs, Ah);
  transpose_win<<<dim3(264, 64), tb, 0, stream>>>(Win, WtH);
  dtz_kernel<<<1024, 256, 0, stream>>>(hs, Win, zf);
  // 2. fp16 in_proj GEMM (256^2 8-phase) -> gate (fp16) + hbc (fp32)
  gemm_in8<<<dim3(528), 512, 0, stream>>>(Ah, WtH, gateh, hbcf);
  // 3. out_proj weight transpose into dead Ah
  transpose_wout<<<dim3(64, 128), tb, 0, stream>>>(Wout, WoutT, 4096, 2048);
  // 4. conv + silu -> x16, B16, C16 (fp16)
  conv_silu_kernel<<<dim3(17, 4096), 256, 0, stream>>>(hbcf, convw, convb, x16, B16, C16);
  // 5. dt softplus + cumsum (fp32-exact)
  dt_cum_kernel<<<16, 256, 0, stream>>>(zf, dtb, Alog, dt_f, cum_f, cuml);
  // 6. x16 -> xT16 global transpose
  xtrans<<<dim3(64, 64), 256, 0, stream>>>((const unsigned short*)x16, (unsigned short*)xT16);
  // 7. CBT = C.B^T per chunk (fp16 MFMA, fp32 out)
  gemm_bt<<<dim3(2, 2, 16), 256, 0, stream>>>(C16, B16, CBT, 128, 256,
                                              32768, 32768, 65536);
  // 8. per-chunk states (fp16 MFMA, fp32 out)
  states_mfma<<<dim3(64, 16), 256, 0, stream>>>((const unsigned short*)xT16,
                                                (const unsigned short*)B16,
                                                dt_f, cum_f, cuml, states);
  // 9. inter-chunk recurrence (in-place, fp32)
  recur_kernel<<<128, 256, 0, stream>>>(states, cuml);
  // 10. fused Ydiag + Yoff + D*x -> Ysum (overlays dead hbcf)
  yfused<<<dim3(64, 16), 256, 0, stream>>>((const unsigned short*)xT16,
                                           (const unsigned short*)x16,
                                           (const unsigned short*)C16,
                                           CBT, states, dt_f, cum_f, Dp, Ysum);
  // 11. gate + RMSNorm -> hid fp16 (overlays dead states)
  norm_kernel<<<4096, 256, 0, stream>>>(Ysum, gateh, nw, hid);
  // 12. out_proj GEMM (256^2 8-phase, split-K z=2) -> partials in dead Ysum/hbcf
  gemm_out8<<<dim3(256), 512, 0, stream>>>(hid, WoutT, oparts);
  // 13. sum partials -> d_out fp32
  add_out<<<8192, 256, 0, stream>>>(oparts, out);
}

// Round 4
// 777.302 us; speedup vs baseline: 1.1600x; 1.0128x over previous
//
#include <hip/hip_runtime.h>
#include <hip/hip_bf16.h>

// Mamba2 mixer forward, MI355X. B=2, L=2048, D_MODEL=2048, H=64, P=64, N=128,
// G=1, K=4, CHUNK=256. T = 4096 tokens, 16 chunks.
// fp16 MFMA for: in_proj (8-phase 256^2, bank-uniform LDS swizzle, tail-flattened
// grid: 512 full tiles + 128 K-split remainder tiles in ONE launch), CBT, states,
// ydiag+yoff (fused), out_proj (8-phase 256^2 split-K). fp32 kept for: conv math,
// dt/cumsum (exact), inter-chunk recurrence, epilogues.

typedef __attribute__((ext_vector_type(8))) _Float16 f16x8;
typedef __attribute__((ext_vector_type(4))) float f32x4;

#define GLD16(gp, lp) __builtin_amdgcn_global_load_lds( \
    (__attribute__((address_space(1))) void*)(gp),      \
    (__attribute__((address_space(3))) void*)(lp), 16, 0, 0)

__device__ __forceinline__ unsigned short f2h(float v) {
  _Float16 h = (_Float16)v;
  return *reinterpret_cast<unsigned short*>(&h);
}
__device__ __forceinline__ float h2f(unsigned short u) {
  _Float16 h = *reinterpret_cast<_Float16*>(&u);
  return (float)h;
}
__device__ __forceinline__ float siluf(float x) { return x / (1.f + expf(-x)); }

// ---------------------------------------------------------------- cast X->fp16
__global__ __launch_bounds__(256) void cast_f16(const float* __restrict__ s,
                                                _Float16* __restrict__ d) {
  long i = ((long)blockIdx.x * 256 + threadIdx.x) * 4;
  float4 v = *reinterpret_cast<const float4*>(s + i);
  ushort4 u;
  u.x = f2h(v.x); u.y = f2h(v.y); u.z = f2h(v.z); u.w = f2h(v.w);
  *reinterpret_cast<ushort4*>(d + i) = u;
}

// --------------------------- transpose Win cols [0,8448) -> fp16 [n][k]
__global__ __launch_bounds__(256) void transpose_win(const float* __restrict__ src,
                                                     _Float16* __restrict__ dst) {
  __shared__ float tile[32][33];
  int c0 = blockIdx.x * 32, r0 = blockIdx.y * 32;
  int tx = threadIdx.x, ty = threadIdx.y;  // 32 x 8
#pragma unroll
  for (int i = 0; i < 4; i++)
    tile[ty + i * 8][tx] = src[(long)(r0 + ty + i * 8) * 8512 + c0 + tx];
  __syncthreads();
#pragma unroll
  for (int i = 0; i < 4; i++) {
    int c = c0 + ty + i * 8, r = r0 + tx;
    dst[(long)c * 2048 + r] = (_Float16)tile[tx][ty + i * 8];
  }
}

// ------------------ transpose+cast fp32 RxC -> fp16 [C][R] (for out_proj W)
__global__ __launch_bounds__(256) void transpose_wout(const float* __restrict__ src,
                                                      _Float16* __restrict__ dst,
                                                      int R, int C) {
  __shared__ float tile[32][33];
  int c0 = blockIdx.x * 32, r0 = blockIdx.y * 32;
  int tx = threadIdx.x, ty = threadIdx.y;
#pragma unroll
  for (int i = 0; i < 4; i++)
    tile[ty + i * 8][tx] = src[(long)(r0 + ty + i * 8) * C + c0 + tx];
  __syncthreads();
#pragma unroll
  for (int i = 0; i < 4; i++) {
    int c = c0 + ty + i * 8, r = r0 + tx;
    dst[(long)c * R + r] = (_Float16)tile[tx][ty + i * 8];
  }
}

// ===================== in_proj GEMM: 256^2 tile, BK=64, 8-wave 8-phase =======
// A[4096,2048] f16 row-major, Bt[8448,2048] f16 row-major (Win^T).
// Grid 640 (one launch, tail-flattened):
//   wg [0,512):   full tiles, N-cols [0,8192): swizzled 16 M x 32 N, K=2048.
//                 cols [0,4096) -> gate (fp16, ld 4096); [4096,8192) -> hbcf.
//   wg [512,640): remainder strip N-cols [8192,8448), 16 M-tiles x 8 K-slices
//                 (K=256 each) -> fp32 partials rparts[z][4096][256].
// LDS 128 KiB: 8 regions x 16 KiB (128 rows x 128B). Bank-uniform swizzle:
// physical col16 = logical col16 ^ (row & 7); offsets XORed (not pointers).
__global__ __launch_bounds__(512, 2) void gemm_in8(const _Float16* __restrict__ A,
                                                   const _Float16* __restrict__ Bt,
                                                   _Float16* __restrict__ gate,
                                                   float* __restrict__ hbcf,
                                                   float* __restrict__ rparts) {
  __shared__ __attribute__((aligned(128))) char ldsB[131072];
  const int tid = threadIdx.x;
  const int lane = tid & 63;
  const int wv = tid >> 6;
  const int wr = wv >> 2, wc = wv & 3;  // 2 (M) x 4 (N) waves; wave C = 128x64
  const int wg = blockIdx.x;
  const bool rem = wg >= 512;
  int by, bxn, kbase, zz;
  if (!rem) {  // bijective XCD swizzle over 512 = 8 * 64
    const int swz = (wg & 7) * 64 + (wg >> 3);
    by = swz >> 5; bxn = swz & 31; kbase = 0; zz = 0;
  } else {
    const int idx = wg - 512;
    by = idx & 15; zz = idx >> 4; bxn = 32; kbase = zz * 256;
  }

  // staging geometry: half-tile = 128 rows x 64 halfs (16 KiB), 2 GLD16/thread.
  const int srow = tid >> 3;
  const int scolg = (tid & 7) ^ (srow & 7);  // inverse-swizzled source col16
  const _Float16* Ab = A + (long)by * 524288 + (long)srow * 2048 + scolg * 8 + kbase;
  const _Float16* Bb = Bt + (long)bxn * 524288 + (long)srow * 2048 + scolg * 8 + kbase;
  const int ldst = tid << 4;

#define STAGE_A(tau, h) do {                                              \
    const _Float16* g_ = Ab + (long)(h) * 262144 + (tau) * 64;            \
    char* l_ = ldsB + ((((tau) & 1) << 2) + (h)) * 16384 + ldst;          \
    GLD16(g_, l_); GLD16(g_ + 131072, l_ + 8192); } while (0)
#define STAGE_B(tau, h) do {                                              \
    const _Float16* g_ = Bb + (long)(h) * 262144 + (tau) * 64;            \
    char* l_ = ldsB + ((((tau) & 1) << 2) + 2 + (h)) * 16384 + ldst;      \
    GLD16(g_, l_); GLD16(g_ + 131072, l_ + 8192); } while (0)

  // fragment-read offsets (swizzled): col16 = (lane>>4 + 4*k32) ^ (fr&7);
  // k32 flips bit2 of col16 -> XOR the offset with 64.
  const int fr = lane & 15;
  const int c16 = (lane >> 4) ^ (fr & 7);
  const int aOff = wr * 16384 + fr * 128 + c16 * 16;
  const int bOff = (2 + (wc >> 1)) * 16384 + ((wc & 1) * 64 + fr) * 128 + c16 * 16;
#define RD_A(b, mi, k32) (*(const f16x8*)(ldsB + ((aOff + (b) * 65536 + (mi) * 2048) ^ ((k32) * 64))))
#define RD_B(b, ni, k32) (*(const f16x8*)(ldsB + ((bOff + (b) * 65536 + (ni) * 2048) ^ ((k32) * 64))))

#define BAR() __builtin_amdgcn_s_barrier()
#define WLG0() asm volatile("s_waitcnt lgkmcnt(0)" ::: "memory")
#define WLG8() asm volatile("s_waitcnt lgkmcnt(8)" ::: "memory")
#define WVM4() asm volatile("s_waitcnt vmcnt(4)" ::: "memory")

  f32x4 acc[8][4];
#pragma unroll
  for (int mi = 0; mi < 8; ++mi)
#pragma unroll
    for (int ni = 0; ni < 4; ++ni) acc[mi][ni] = f32x4{0.f, 0.f, 0.f, 0.f};

  // prologue: tile0 {A0,A1,B0,B1} + tile1 {B0,B1}
  STAGE_A(0, 0); STAGE_A(0, 1); STAGE_B(0, 0); STAGE_B(0, 1);
  STAGE_B(1, 0); STAGE_B(1, 1);
  WVM4(); BAR();

#define MFMA_Q(MI0, MI1, x0, x1, x2, x3, PB)                                        \
  __builtin_amdgcn_s_setprio(1);                                                    \
  _Pragma("unroll") for (int ni = 0; ni < 4; ++ni) {                                \
    acc[MI0][ni] = __builtin_amdgcn_mfma_f32_16x16x32_f16(x0, PB[ni][0], acc[MI0][ni], 0, 0, 0); \
    acc[MI0][ni] = __builtin_amdgcn_mfma_f32_16x16x32_f16(x1, PB[ni][1], acc[MI0][ni], 0, 0, 0); \
    acc[MI1][ni] = __builtin_amdgcn_mfma_f32_16x16x32_f16(x2, PB[ni][0], acc[MI1][ni], 0, 0, 0); \
    acc[MI1][ni] = __builtin_amdgcn_mfma_f32_16x16x32_f16(x3, PB[ni][1], acc[MI1][ni], 0, 0, 0); \
  }                                                                                 \
  __builtin_amdgcn_s_setprio(0);

  // one u-iteration = 2 K-tiles, 8 phases. Stage schedule:
  // p0:A0(t+1) p1:A1(t+1) p2:B0(t+2) p3:B1(t+2) p4:A0(t+2) p5:A1(t+2)
  // p6:B0(t+3) p7:B1(t+3); vmcnt(4) at end of p3/p7. msk wraps prefetch
  // indices into the block's K-range (wrap reload is harmless).
#define ITER8(u, msk) do {                                                          \
    const int t1 = (2 * (u) + 1) & (msk);                                           \
    const int t2 = (2 * (u) + 2) & (msk);                                           \
    const int t3 = (2 * (u) + 3) & (msk);                                           \
    f16x8 PB0[4][2];                                                                \
    _Pragma("unroll") for (int ni = 0; ni < 4; ++ni) {                              \
      PB0[ni][0] = RD_B(0, ni, 0); PB0[ni][1] = RD_B(0, ni, 1); }                   \
    {                                                                               \
      f16x8 x0 = RD_A(0, 0, 0), x1 = RD_A(0, 0, 1), x2 = RD_A(0, 1, 0), x3 = RD_A(0, 1, 1); \
      STAGE_A(t1, 0); WLG8(); BAR(); WLG0();                                        \
      MFMA_Q(0, 1, x0, x1, x2, x3, PB0) BAR();                                      \
    }                                                                               \
    {                                                                               \
      f16x8 x0 = RD_A(0, 2, 0), x1 = RD_A(0, 2, 1), x2 = RD_A(0, 3, 0), x3 = RD_A(0, 3, 1); \
      STAGE_A(t1, 1); BAR(); WLG0();                                                \
      MFMA_Q(2, 3, x0, x1, x2, x3, PB0) BAR();                                      \
    }                                                                               \
    {                                                                               \
      f16x8 x0 = RD_A(0, 4, 0), x1 = RD_A(0, 4, 1), x2 = RD_A(0, 5, 0), x3 = RD_A(0, 5, 1); \
      STAGE_B(t2, 0); BAR(); WLG0();                                                \
      MFMA_Q(4, 5, x0, x1, x2, x3, PB0) BAR();                                      \
    }                                                                               \
    {                                                                               \
      f16x8 x0 = RD_A(0, 6, 0), x1 = RD_A(0, 6, 1), x2 = RD_A(0, 7, 0), x3 = RD_A(0, 7, 1); \
      STAGE_B(t2, 1); BAR(); WLG0();                                                \
      MFMA_Q(6, 7, x0, x1, x2, x3, PB0) WVM4(); BAR();                              \
    }                                                                               \
    f16x8 PB1[4][2];                                                                \
    _Pragma("unroll") for (int ni = 0; ni < 4; ++ni) {                              \
      PB1[ni][0] = RD_B(1, ni, 0); PB1[ni][1] = RD_B(1, ni, 1); }                   \
    {                                                                               \
      f16x8 x0 = RD_A(1, 0, 0), x1 = RD_A(1, 0, 1), x2 = RD_A(1, 1, 0), x3 = RD_A(1, 1, 1); \
      STAGE_A(t2, 0); WLG8(); BAR(); WLG0();                                        \
      MFMA_Q(0, 1, x0, x1, x2, x3, PB1) BAR();                                      \
    }                                                                               \
    {                                                                               \
      f16x8 x0 = RD_A(1, 2, 0), x1 = RD_A(1, 2, 1), x2 = RD_A(1, 3, 0), x3 = RD_A(1, 3, 1); \
      STAGE_A(t2, 1); BAR(); WLG0();                                                \
      MFMA_Q(2, 3, x0, x1, x2, x3, PB1) BAR();                                      \
    }                                                                               \
    {                                                                               \
      f16x8 x0 = RD_A(1, 4, 0), x1 = RD_A(1, 4, 1), x2 = RD_A(1, 5, 0), x3 = RD_A(1, 5, 1); \
      STAGE_B(t3, 0); BAR(); WLG0();                                                \
      MFMA_Q(4, 5, x0, x1, x2, x3, PB1) BAR();                                      \
    }                                                                               \
    {                                                                               \
      f16x8 x0 = RD_A(1, 6, 0), x1 = RD_A(1, 6, 1), x2 = RD_A(1, 7, 0), x3 = RD_A(1, 7, 1); \
      STAGE_B(t3, 1); BAR(); WLG0();                                                \
      MFMA_Q(6, 7, x0, x1, x2, x3, PB1) WVM4(); BAR();                              \
    }                                                                               \
  } while (0)

  if (!rem) {
    for (int u = 0; u < 16; ++u) ITER8(u, 31);
  } else {
    for (int u = 0; u < 2; ++u) ITER8(u, 3);
  }

  // -------- epilogue (block-uniform branches)
  const int m0 = by * 256 + wr * 128;
  const int cl = lane & 15, rq = (lane >> 4) * 4;
  if (!rem) {
    const int n0 = bxn * 256 + wc * 64;
    if (bxn < 16) {
#pragma unroll
      for (int mi = 0; mi < 8; ++mi)
#pragma unroll
        for (int r = 0; r < 4; ++r) {
          long rowoff = (long)(m0 + mi * 16 + rq + r) * 4096 + n0 + cl;
#pragma unroll
          for (int ni = 0; ni < 4; ++ni) gate[rowoff + ni * 16] = (_Float16)acc[mi][ni][r];
        }
    } else {
#pragma unroll
      for (int mi = 0; mi < 8; ++mi)
#pragma unroll
        for (int r = 0; r < 4; ++r) {
          long rowoff = (long)(m0 + mi * 16 + rq + r) * 4352 + (n0 - 4096) + cl;
#pragma unroll
          for (int ni = 0; ni < 4; ++ni) hbcf[rowoff + ni * 16] = acc[mi][ni][r];
        }
    }
  } else {
    float* rp = rparts + (long)zz * 1048576;
    const int ncol = wc * 64;
#pragma unroll
    for (int mi = 0; mi < 8; ++mi)
#pragma unroll
      for (int r = 0; r < 4; ++r) {
        long rowoff = (long)(m0 + mi * 16 + rq + r) * 256 + ncol + cl;
#pragma unroll
        for (int ni = 0; ni < 4; ++ni) rp[rowoff + ni * 16] = acc[mi][ni][r];
      }
  }
#undef STAGE_A
#undef STAGE_B
#undef RD_A
#undef RD_B
#undef ITER8
}

// ------------- reduce the 8 remainder K-partials into hbcf cols [4096,4352)
__global__ __launch_bounds__(256) void add_rem(const float* __restrict__ rp,
                                               float* __restrict__ hbcf) {
  long e = ((long)blockIdx.x * 256 + threadIdx.x) * 4;  // e in [0, 1048576)
  float4 s = *reinterpret_cast<const float4*>(rp + e);
#pragma unroll
  for (int z = 1; z < 8; ++z) {
    float4 v = *reinterpret_cast<const float4*>(rp + (long)z * 1048576 + e);
    s.x += v.x; s.y += v.y; s.z += v.z; s.w += v.w;
  }
  long row = e >> 8, col = e & 255;
  *reinterpret_cast<float4*>(hbcf + row * 4352 + 4096 + col) = s;
}

// ===================== out_proj GEMM: 256^2 tile, split-K (z=2), 8-phase =====
// A = hid [4096,4096] f16, Bt = WoutT [2048,4096] f16. Each z-block computes a
// K-half (2048) partial into Cp[z] (fp32, ld 2048). grid 256 = 16 M x 8 N x 2 z
// -> exactly 1 block/CU, no tail. Same LDS layout/swizzle/schedule as gemm_in8.
__global__ __launch_bounds__(512, 2) void gemm_out8(const _Float16* __restrict__ A,
                                                    const _Float16* __restrict__ Bt,
                                                    float* __restrict__ Cp) {
  __shared__ __attribute__((aligned(128))) char ldsB[131072];
  const int tid = threadIdx.x;
  const int lane = tid & 63;
  const int wv = tid >> 6;
  const int wr = wv >> 2, wc = wv & 3;
  const int wg = blockIdx.x;
  const int z = wg >> 7;                 // K-half
  const int r7 = wg & 127;
  const int sw = (r7 & 7) * 16 + (r7 >> 3);  // XCD swizzle over 128
  const int by = sw >> 3, bx = sw & 7;

  const int srow = tid >> 3;
  const int scolg = (tid & 7) ^ (srow & 7);
  const _Float16* Ab = A + (long)by * 256 * 4096 + (long)z * 2048 +
                       (long)srow * 4096 + scolg * 8;
  const _Float16* Bb = Bt + (long)bx * 256 * 4096 + (long)z * 2048 +
                       (long)srow * 4096 + scolg * 8;
  const int ldst = tid << 4;

#define STAGE_A(tau, h) do {                                              \
    const _Float16* g_ = Ab + (long)(h) * 524288 + (tau) * 64;            \
    char* l_ = ldsB + ((((tau) & 1) << 2) + (h)) * 16384 + ldst;          \
    GLD16(g_, l_); GLD16(g_ + 262144, l_ + 8192); } while (0)
#define STAGE_B(tau, h) do {                                              \
    const _Float16* g_ = Bb + (long)(h) * 524288 + (tau) * 64;            \
    char* l_ = ldsB + ((((tau) & 1) << 2) + 2 + (h)) * 16384 + ldst;      \
    GLD16(g_, l_); GLD16(g_ + 262144, l_ + 8192); } while (0)

  const int fr = lane & 15;
  const int c16 = (lane >> 4) ^ (fr & 7);
  const int aOff = wr * 16384 + fr * 128 + c16 * 16;
  const int bOff = (2 + (wc >> 1)) * 16384 + ((wc & 1) * 64 + fr) * 128 + c16 * 16;
#define RD_A(b, mi, k32) (*(const f16x8*)(ldsB + ((aOff + (b) * 65536 + (mi) * 2048) ^ ((k32) * 64))))
#define RD_B(b, ni, k32) (*(const f16x8*)(ldsB + ((bOff + (b) * 65536 + (ni) * 2048) ^ ((k32) * 64))))

  f32x4 acc[8][4];
#pragma unroll
  for (int mi = 0; mi < 8; ++mi)
#pragma unroll
    for (int ni = 0; ni < 4; ++ni) acc[mi][ni] = f32x4{0.f, 0.f, 0.f, 0.f};

  STAGE_A(0, 0); STAGE_A(0, 1); STAGE_B(0, 0); STAGE_B(0, 1);
  STAGE_B(1, 0); STAGE_B(1, 1);
  WVM4(); BAR();

  for (int u = 0; u < 16; ++u) {
    const int t1 = 2 * u + 1;
    const int t2 = (2 * u + 2) & 31;
    const int t3 = (2 * u + 3) & 31;
    f16x8 PB0[4][2];
#pragma unroll
    for (int ni = 0; ni < 4; ++ni) { PB0[ni][0] = RD_B(0, ni, 0); PB0[ni][1] = RD_B(0, ni, 1); }
    {
      f16x8 x0 = RD_A(0, 0, 0), x1 = RD_A(0, 0, 1), x2 = RD_A(0, 1, 0), x3 = RD_A(0, 1, 1);
      STAGE_A(t1, 0); WLG8(); BAR(); WLG0();
      MFMA_Q(0, 1, x0, x1, x2, x3, PB0) BAR();
    }
    {
      f16x8 x0 = RD_A(0, 2, 0), x1 = RD_A(0, 2, 1), x2 = RD_A(0, 3, 0), x3 = RD_A(0, 3, 1);
      STAGE_A(t1, 1); BAR(); WLG0();
      MFMA_Q(2, 3, x0, x1, x2, x3, PB0) BAR();
    }
    {
      f16x8 x0 = RD_A(0, 4, 0), x1 = RD_A(0, 4, 1), x2 = RD_A(0, 5, 0), x3 = RD_A(0, 5, 1);
      STAGE_B(t2, 0); BAR(); WLG0();
      MFMA_Q(4, 5, x0, x1, x2, x3, PB0) BAR();
    }
    {
      f16x8 x0 = RD_A(0, 6, 0), x1 = RD_A(0, 6, 1), x2 = RD_A(0, 7, 0), x3 = RD_A(0, 7, 1);
      STAGE_B(t2, 1); BAR(); WLG0();
      MFMA_Q(6, 7, x0, x1, x2, x3, PB0) WVM4(); BAR();
    }
    f16x8 PB1[4][2];
#pragma unroll
    for (int ni = 0; ni < 4; ++ni) { PB1[ni][0] = RD_B(1, ni, 0); PB1[ni][1] = RD_B(1, ni, 1); }
    {
      f16x8 x0 = RD_A(1, 0, 0), x1 = RD_A(1, 0, 1), x2 = RD_A(1, 1, 0), x3 = RD_A(1, 1, 1);
      STAGE_A(t2, 0); WLG8(); BAR(); WLG0();
      MFMA_Q(0, 1, x0, x1, x2, x3, PB1) BAR();
    }
    {
      f16x8 x0 = RD_A(1, 2, 0), x1 = RD_A(1, 2, 1), x2 = RD_A(1, 3, 0), x3 = RD_A(1, 3, 1);
      STAGE_A(t2, 1); BAR(); WLG0();
      MFMA_Q(2, 3, x0, x1, x2, x3, PB1) BAR();
    }
    {
      f16x8 x0 = RD_A(1, 4, 0), x1 = RD_A(1, 4, 1), x2 = RD_A(1, 5, 0), x3 = RD_A(1, 5, 1);
      STAGE_B(t3, 0); BAR(); WLG0();
      MFMA_Q(4, 5, x0, x1, x2, x3, PB1) BAR();
    }
    {
      f16x8 x0 = RD_A(1, 6, 0), x1 = RD_A(1, 6, 1), x2 = RD_A(1, 7, 0), x3 = RD_A(1, 7, 1);
      STAGE_B(t3, 1); BAR(); WLG0();
      MFMA_Q(6, 7, x0, x1, x2, x3, PB1) WVM4(); BAR();
    }
  }
  const int m0 = by * 256 + wr * 128;
  const int n0 = bx * 256 + wc * 64;
  const int cl = lane & 15, rq = (lane >> 4) * 4;
  float* Cb = Cp + (long)z * 8388608;
#pragma unroll
  for (int mi = 0; mi < 8; ++mi)
#pragma unroll
    for (int r = 0; r < 4; ++r) {
      long rowoff = (long)(m0 + mi * 16 + rq + r) * 2048 + n0 + cl;
#pragma unroll
      for (int ni = 0; ni < 4; ++ni) Cb[rowoff + ni * 16] = acc[mi][ni][r];
    }
#undef STAGE_A
#undef STAGE_B
#undef RD_A
#undef RD_B
#undef BAR
#undef WLG0
#undef WLG8
#undef WVM4
#undef MFMA_Q
}

// -------------------------------------------- sum the two split-K partials
__global__ __launch_bounds__(256) void add_out(const float* __restrict__ p,
                                               float* __restrict__ o) {
  long i = ((long)blockIdx.x * 256 + threadIdx.x) * 4;
  float4 a = *reinterpret_cast<const float4*>(p + i);
  float4 b = *reinterpret_cast<const float4*>(p + 8388608 + i);
  float4 r;
  r.x = a.x + b.x; r.y = a.y + b.y; r.z = a.z + b.z; r.w = a.w + b.w;
  *reinterpret_cast<float4*>(o + i) = r;
}

// --------------------------- fp16 GEMM (B^T), z-batched, fp32 out (CBT only)
__global__ __launch_bounds__(256) void gemm_bt(const _Float16* __restrict__ A,
                                               const _Float16* __restrict__ Bt,
                                               float* __restrict__ Cf,
                                               int K, int ldc,
                                               long zsA, long zsB, long zsC) {
  __shared__ uint4 As4[512];
  __shared__ uint4 Bs4[512];
  _Float16* As = (_Float16*)As4;
  _Float16* Bs = (_Float16*)Bs4;
  const int tid = threadIdx.x;
  const int wv = tid >> 6;
  const int lane = tid & 63;
  const _Float16* Ab = A + (long)blockIdx.z * zsA + (long)blockIdx.y * 128 * K;
  const _Float16* Bb = Bt + (long)blockIdx.z * zsB + (long)blockIdx.x * 128 * K;
  const int c0 = wv * 128 + lane;
  const int c1 = c0 + 64;
  const long ra0 = (long)(c0 >> 2) * K + (c0 & 3) * 8;
  const long ra1 = (long)(c1 >> 2) * K + (c1 & 3) * 8;
  f32x4 acc[4][4];
#pragma unroll
  for (int mi = 0; mi < 4; mi++)
#pragma unroll
    for (int ni = 0; ni < 4; ni++) acc[mi][ni] = f32x4{0.f, 0.f, 0.f, 0.f};
  const int mrow = (wv & 1) * 64 + (lane & 15);
  const int nrow = (wv >> 1) * 64 + (lane & 15);
  const int koff = (lane >> 4) * 8;
  for (int k0 = 0; k0 < K; k0 += 32) {
    GLD16(Ab + ra0 + k0, (char*)As + c0 * 16);
    GLD16(Ab + ra1 + k0, (char*)As + c1 * 16);
    GLD16(Bb + ra0 + k0, (char*)Bs + c0 * 16);
    GLD16(Bb + ra1 + k0, (char*)Bs + c1 * 16);
    __syncthreads();
    f16x8 af[4], bfr[4];
#pragma unroll
    for (int mi = 0; mi < 4; mi++)
      af[mi] = *(const f16x8*)(As + (mrow + mi * 16) * 32 + koff);
#pragma unroll
    for (int ni = 0; ni < 4; ni++)
      bfr[ni] = *(const f16x8*)(Bs + (nrow + ni * 16) * 32 + koff);
#pragma unroll
    for (int mi = 0; mi < 4; mi++)
#pragma unroll
      for (int ni = 0; ni < 4; ni++)
        acc[mi][ni] = __builtin_amdgcn_mfma_f32_16x16x32_f16(af[mi], bfr[ni],
                                                             acc[mi][ni], 0, 0, 0);
    __syncthreads();
  }
  const int m0 = blockIdx.y * 128 + (wv & 1) * 64;
  const int n0 = blockIdx.x * 128 + (wv >> 1) * 64;
  const int cl = lane & 15, rq = (lane >> 4) * 4;
  const long zc = (long)blockIdx.z * zsC;
#pragma unroll
  for (int mi = 0; mi < 4; mi++)
#pragma unroll
    for (int r = 0; r < 4; r++) {
      long rowoff = zc + (long)(m0 + mi * 16 + rq + r) * ldc + n0 + cl;
#pragma unroll
      for (int ni = 0; ni < 4; ni++) Cf[rowoff + ni * 16] = acc[mi][ni][r];
    }
}

// ---------------------------------------- fp32 dt pre-activation (exact slice)
__global__ __launch_bounds__(256) void dtz_kernel(const float* __restrict__ hs,
                                                  const float* __restrict__ Win,
                                                  float* __restrict__ zf) {
  __shared__ float Xs[4][2048];
  int t0 = blockIdx.x * 4;
  int tid = threadIdx.x;
#pragma unroll
  for (int i = 0; i < 8; i++) {
    int e = tid * 4 + i * 1024;
    int tok = e >> 11, k = e & 2047;
    *reinterpret_cast<float4*>(&Xs[tok][k]) =
        *reinterpret_cast<const float4*>(&hs[(long)(t0 + tok) * 2048 + k]);
  }
  __syncthreads();
  int h = tid & 63, tg = tid >> 6;
  float a0 = 0.f, a1 = 0.f, a2 = 0.f, a3 = 0.f;
  const float* wcol = Win + 8448 + h;
  for (int k = 0; k < 2048; k += 4) {
    a0 = fmaf(Xs[tg][k + 0], wcol[(long)(k + 0) * 8512], a0);
    a1 = fmaf(Xs[tg][k + 1], wcol[(long)(k + 1) * 8512], a1);
    a2 = fmaf(Xs[tg][k + 2], wcol[(long)(k + 2) * 8512], a2);
    a3 = fmaf(Xs[tg][k + 3], wcol[(long)(k + 3) * 8512], a3);
  }
  zf[(long)(t0 + tg) * 64 + h] = (a0 + a1) + (a2 + a3);
}

// --------------------------- conv(K=4)+SiLU (fp32 math, fp16 out) -> x16,B16,C16
__global__ __launch_bounds__(256) void conv_silu_kernel(const float* __restrict__ hbcf,
                                                        const float* __restrict__ convw,
                                                        const float* __restrict__ convb,
                                                        _Float16* __restrict__ x16,
                                                        _Float16* __restrict__ B16,
                                                        _Float16* __restrict__ C16) {
  int q = blockIdx.x * 256 + threadIdx.x;  // [0,4352)
  int t = blockIdx.y;                      // [0,4096)
  int l = t & 2047;
  const float* col = hbcf + (long)t * 4352 + q;
  float4 wq = *reinterpret_cast<const float4*>(convw + q * 4);
  float a = convb[q];
  if (l >= 3) a += col[-3 * 4352] * wq.x;
  if (l >= 2) a += col[-2 * 4352] * wq.y;
  if (l >= 1) a += col[-1 * 4352] * wq.z;
  a += col[0] * wq.w;
  _Float16 o = (_Float16)siluf(a);
  if (q < 4096) x16[(long)t * 4096 + q] = o;
  else if (q < 4224) B16[(long)t * 128 + (q - 4096)] = o;
  else C16[(long)t * 128 + (q - 4224)] = o;
}

// ------------------------------------------- global transpose x16 -> xT16 [q][t]
__global__ __launch_bounds__(256) void xtrans(const unsigned short* __restrict__ src,
                                              unsigned short* __restrict__ dst) {
  __shared__ unsigned short tile[64][66];
  int c0 = blockIdx.x * 64, r0 = blockIdx.y * 64;
  int tx = threadIdx.x & 15, ty = threadIdx.x >> 4;  // 16 x 16
#pragma unroll
  for (int i = 0; i < 4; i++) {
    int r = ty + i * 16;
    ushort4 v = *(const ushort4*)&src[(long)(r0 + r) * 4096 + c0 + 4 * tx];
    tile[r][4 * tx] = v.x; tile[r][4 * tx + 1] = v.y;
    tile[r][4 * tx + 2] = v.z; tile[r][4 * tx + 3] = v.w;
  }
  __syncthreads();
#pragma unroll
  for (int i = 0; i < 4; i++) {
    int c = ty + i * 16;
    ushort4 v;
    v.x = tile[4 * tx + 0][c]; v.y = tile[4 * tx + 1][c];
    v.z = tile[4 * tx + 2][c]; v.w = tile[4 * tx + 3][c];
    *(ushort4*)&dst[(long)(c0 + c) * 4096 + r0 + 4 * tx] = v;
  }
}

// ------------------------------------------------- dt softplus + chunk cumsum
__global__ __launch_bounds__(256) void dt_cum_kernel(const float* __restrict__ zf,
                                                     const float* __restrict__ dtb,
                                                     const float* __restrict__ Alog,
                                                     float* __restrict__ dt_f,
                                                     float* __restrict__ cum_f,
                                                     float* __restrict__ cuml) {
  int bc = blockIdx.x;
  int h = threadIdx.x & 63, seg = threadIdx.x >> 6;
  int t0 = bc * 256;
  float Ah = -expf(Alog[h]);
  float bias = dtb[h];
  __shared__ float segsum[4][64];
  float s = 0.f;
  for (int j = 0; j < 64; j++) {
    int t = t0 + seg * 64 + j;
    float z = zf[(long)t * 64 + h] + bias;
    float v = (z > 20.f) ? z : log1pf(expf(z));
    dt_f[(long)t * 64 + h] = v;
    s += v * Ah;
  }
  segsum[seg][h] = s;
  __syncthreads();
  float run = 0.f;
  for (int k = 0; k < seg; k++) run += segsum[k][h];
  for (int j = 0; j < 64; j++) {
    int t = t0 + seg * 64 + j;
    run += dt_f[(long)t * 64 + h] * Ah;
    cum_f[(long)t * 64 + h] = run;
  }
  if (seg == 3) cuml[bc * 64 + h] = run;
}

// --------------------------------- states via MFMA: states[bc,h,p,n] (64x128)
// states[p][n] = sum_t (w_t * x[t][p]) * B[t][n];  w folded into A-operand.
__global__ __launch_bounds__(256) void states_mfma(const unsigned short* __restrict__ xT16,
                                                   const unsigned short* __restrict__ B16,
                                                   const float* __restrict__ dt_f,
                                                   const float* __restrict__ cum_f,
                                                   const float* __restrict__ cuml,
                                                   float* __restrict__ states) {
  int h = blockIdx.x, bc = blockIdx.y;
  int t0 = bc * 256, tid = threadIdx.x;
  __shared__ float w_s[256];
  __shared__ unsigned short Aw[64 * 40];   // [p][tt] pad 40
  __shared__ unsigned short BT[128 * 40];  // [n][tt] pad 40
  {
    int t = t0 + tid;
    w_s[tid] = expf(cuml[bc * 64 + h] - cum_f[(long)t * 64 + h]) * dt_f[(long)t * 64 + h];
  }
  __syncthreads();
  int wv = tid >> 6, lane = tid & 63;
  int mr = lane & 15, koff = (lane >> 4) * 8;
  f32x4 acc[4][2];
#pragma unroll
  for (int mi = 0; mi < 4; mi++)
#pragma unroll
    for (int nj = 0; nj < 2; nj++) acc[mi][nj] = f32x4{0.f, 0.f, 0.f, 0.f};
  for (int kt = 0; kt < 8; kt++) {
    {  // form Aw: thread = p*4 + tq, 8 t-elems each
      int p = tid >> 2, tq = tid & 3;
      const unsigned short* g = &xT16[((long)(h * 64 + p)) * 4096 + t0 + kt * 32 + tq * 8];
      ushort4 u0 = *(const ushort4*)g, u1 = *(const ushort4*)(g + 4);
      const float* wp = &w_s[kt * 32 + tq * 8];
      ushort4 o0, o1;
      o0.x = f2h(h2f(u0.x) * wp[0]); o0.y = f2h(h2f(u0.y) * wp[1]);
      o0.z = f2h(h2f(u0.z) * wp[2]); o0.w = f2h(h2f(u0.w) * wp[3]);
      o1.x = f2h(h2f(u1.x) * wp[4]); o1.y = f2h(h2f(u1.y) * wp[5]);
      o1.z = f2h(h2f(u1.z) * wp[6]); o1.w = f2h(h2f(u1.w) * wp[7]);
      *(ushort4*)&Aw[p * 40 + tq * 8] = o0;
      *(ushort4*)&Aw[p * 40 + tq * 8 + 4] = o1;
    }
    {  // form BT: thread = tl*8 + ng; copy B16[t][n] -> BT[n][tl]
      int tl = tid >> 3, ng = tid & 7;
      const unsigned short* g = &B16[((long)(t0 + kt * 32 + tl)) * 128 + ng * 16];
#pragma unroll
      for (int j = 0; j < 16; j++) BT[(ng * 16 + j) * 40 + tl] = g[j];
    }
    __syncthreads();
    f16x8 af[4], bf[2];
#pragma unroll
    for (int mi = 0; mi < 4; mi++)
      af[mi] = *(const f16x8*)&Aw[(mi * 16 + mr) * 40 + koff];
#pragma unroll
    for (int nj = 0; nj < 2; nj++)
      bf[nj] = *(const f16x8*)&BT[((wv * 2 + nj) * 16 + mr) * 40 + koff];
#pragma unroll
    for (int mi = 0; mi < 4; mi++)
#pragma unroll
      for (int nj = 0; nj < 2; nj++)
        acc[mi][nj] = __builtin_amdgcn_mfma_f32_16x16x32_f16(af[mi], bf[nj],
                                                             acc[mi][nj], 0, 0, 0);
    __syncthreads();
  }
  int cl = lane & 15, rq = (lane >> 4) * 4;
  long base = ((long)(bc * 64 + h)) * 8192;
#pragma unroll
  for (int mi = 0; mi < 4; mi++)
#pragma unroll
    for (int r = 0; r < 4; r++) {
      int p = mi * 16 + rq + r;
#pragma unroll
      for (int nj = 0; nj < 2; nj++) {
        int n = (wv * 2 + nj) * 16 + cl;
        states[base + p * 128 + n] = acc[mi][nj][r];
      }
    }
}

// --------------------------------- inter-chunk recurrence (in-place -> prevs)
__global__ __launch_bounds__(256) void recur_kernel(float* __restrict__ states,
                                                    const float* __restrict__ cuml) {
  int bh = blockIdx.x;
  int b = bh >> 6, h = bh & 63;
  int tid = threadIdx.x;
  float4 prev[8];
#pragma unroll
  for (int j = 0; j < 8; j++) prev[j] = make_float4(0.f, 0.f, 0.f, 0.f);
  for (int c = 0; c < 8; c++) {
    int bc = b * 8 + c;
    float cd = expf(cuml[bc * 64 + h]);
    long base = (long)(bc * 64 + h) * 8192;
#pragma unroll
    for (int j = 0; j < 8; j++) {
      long o = base + j * 1024 + tid * 4;
      float4 st = *reinterpret_cast<const float4*>(&states[o]);
      *reinterpret_cast<float4*>(&states[o]) = prev[j];
      prev[j].x = fmaf(cd, prev[j].x, st.x);
      prev[j].y = fmaf(cd, prev[j].y, st.y);
      prev[j].z = fmaf(cd, prev[j].z, st.z);
      prev[j].w = fmaf(cd, prev[j].w, st.w);
    }
  }
}

// ---------------- fused Y = Ydiag + Yoff + D*x  via MFMA, per (h, bc) block
// Ydiag[i][p] = sum_j S[i][j]*x[j][p],  S = CBT*exp(cum_i-cum_j)*dt_j, causal.
// Yoff[i][p]  = sum_n (C[i][n]*fac_i)*PS[p][n],  fac_i = exp(cum_i).
__global__ __launch_bounds__(256) void yfused(const unsigned short* __restrict__ xT16,
                                              const unsigned short* __restrict__ x16,
                                              const unsigned short* __restrict__ C16,
                                              const float* __restrict__ CBT,
                                              const float* __restrict__ states,
                                              const float* __restrict__ dt_f,
                                              const float* __restrict__ cum_f,
                                              const float* __restrict__ Dp,
                                              float* __restrict__ Ysum) {
  int h = blockIdx.x, bc = blockIdx.y;
  int t0 = bc * 256, tid = threadIdx.x;
  __shared__ unsigned short Sb[256 * 40];   // S / Afac tile [256][32] pad 40
  __shared__ unsigned short Xb[64 * 264];   // xT [64][256] pad 264; later PS16 [64][136]
  __shared__ float cum_s[256], dt_s[256];
  int i = tid;
  cum_s[i] = cum_f[(long)(t0 + i) * 64 + h];
  dt_s[i] = dt_f[(long)(t0 + i) * 64 + h];
  {  // stage xT tile: thread = p*4 + tq, 64 t-elems each
    int p = tid >> 2, tq = tid & 3;
    const unsigned short* g = &xT16[((long)(h * 64 + p)) * 4096 + t0 + tq * 64];
    unsigned short* l = &Xb[p * 264 + tq * 64];
#pragma unroll
    for (int c = 0; c < 8; c++)
      *(uint4*)(l + c * 8) = *(const uint4*)(g + c * 8);
  }
  __syncthreads();
  float cum_i = cum_s[i];
  const float* cbrow = CBT + (long)bc * 65536 + (long)i * 256;
  int wv = tid >> 6, lane = tid & 63;
  int mr = lane & 15, koff = (lane >> 4) * 8;
  f32x4 acc[4][4];
#pragma unroll
  for (int mi = 0; mi < 4; mi++)
#pragma unroll
    for (int ni = 0; ni < 4; ni++) acc[mi][ni] = f32x4{0.f, 0.f, 0.f, 0.f};
  // ---------------- ydiag phase: K = 256 over j, 8 k-tiles
  for (int kt = 0; kt < 8; kt++) {
    int k0 = kt * 32;
#pragma unroll
    for (int c = 0; c < 8; c++) {
      float4 cb = *(const float4*)&cbrow[k0 + c * 4];
      ushort4 o;
      {
        int j = k0 + c * 4 + 0;
        float s = (j <= i) ? cb.x * expf(cum_i - cum_s[j]) * dt_s[j] : 0.f;
        o.x = f2h(s);
      }
      {
        int j = k0 + c * 4 + 1;
        float s = (j <= i) ? cb.y * expf(cum_i - cum_s[j]) * dt_s[j] : 0.f;
        o.y = f2h(s);
      }
      {
        int j = k0 + c * 4 + 2;
        float s = (j <= i) ? cb.z * expf(cum_i - cum_s[j]) * dt_s[j] : 0.f;
        o.z = f2h(s);
      }
      {
        int j = k0 + c * 4 + 3;
        float s = (j <= i) ? cb.w * expf(cum_i - cum_s[j]) * dt_s[j] : 0.f;
        o.w = f2h(s);
      }
      *(ushort4*)&Sb[i * 40 + c * 4] = o;
    }
    __syncthreads();
    if (kt <= 2 * wv + 1) {
      f16x8 af[4], bf[4];
#pragma unroll
      for (int mi = 0; mi < 4; mi++)
        af[mi] = *(const f16x8*)&Sb[(64 * wv + mi * 16 + mr) * 40 + koff];
#pragma unroll
      for (int ni = 0; ni < 4; ni++)
        bf[ni] = *(const f16x8*)&Xb[(ni * 16 + mr) * 264 + k0 + koff];
#pragma unroll
      for (int mi = 0; mi < 4; mi++)
#pragma unroll
        for (int ni = 0; ni < 4; ni++)
          acc[mi][ni] = __builtin_amdgcn_mfma_f32_16x16x32_f16(af[mi], bf[ni],
                                                               acc[mi][ni], 0, 0, 0);
    }
    __syncthreads();
  }
  // ---------------- yoff phase: stage PS16 into Xb (xT dead)
  {
    int p = tid >> 2, nq = tid & 3;
    const float* g = &states[((long)(bc * 64 + h)) * 8192 + p * 128 + nq * 32];
    unsigned short* l = &Xb[p * 136 + nq * 32];
#pragma unroll
    for (int c = 0; c < 8; c++) {
      float4 v = *(const float4*)(g + c * 4);
      ushort4 u;
      u.x = f2h(v.x); u.y = f2h(v.y); u.z = f2h(v.z); u.w = f2h(v.w);
      *(ushort4*)(l + c * 4) = u;
    }
  }
  float fac_i = expf(cum_i);
  for (int kn = 0; kn < 4; kn++) {
    {  // form Afac row i
      const unsigned short* g = &C16[((long)(t0 + i)) * 128 + kn * 32];
#pragma unroll
      for (int c = 0; c < 8; c++) {
        ushort4 u = *(const ushort4*)(g + c * 4);
        ushort4 o;
        o.x = f2h(h2f(u.x) * fac_i); o.y = f2h(h2f(u.y) * fac_i);
        o.z = f2h(h2f(u.z) * fac_i); o.w = f2h(h2f(u.w) * fac_i);
        *(ushort4*)&Sb[i * 40 + c * 4] = o;
      }
    }
    __syncthreads();
    f16x8 af[4], bf[4];
#pragma unroll
    for (int mi = 0; mi < 4; mi++)
      af[mi] = *(const f16x8*)&Sb[(64 * wv + mi * 16 + mr) * 40 + koff];
#pragma unroll
    for (int ni = 0; ni < 4; ni++)
      bf[ni] = *(const f16x8*)&Xb[(ni * 16 + mr) * 136 + kn * 32 + koff];
#pragma unroll
    for (int mi = 0; mi < 4; mi++)
#pragma unroll
      for (int ni = 0; ni < 4; ni++)
        acc[mi][ni] = __builtin_amdgcn_mfma_f32_16x16x32_f16(af[mi], bf[ni],
                                                             acc[mi][ni], 0, 0, 0);
    __syncthreads();
  }
  // epilogue: + D*x, store Ysum fp32
  float Dh = Dp[h];
  int cl = lane & 15, rq = (lane >> 4) * 4;
#pragma unroll
  for (int mi = 0; mi < 4; mi++)
#pragma unroll
    for (int r = 0; r < 4; r++) {
      long row = t0 + 64 * wv + mi * 16 + rq + r;
      float* yr = &Ysum[row * 4096 + h * 64];
      const unsigned short* xr = &x16[row * 4096 + h * 64];
#pragma unroll
      for (int ni = 0; ni < 4; ni++) {
        int p = ni * 16 + cl;
        yr[p] = acc[mi][ni][r] + Dh * h2f(xr[p]);
      }
    }
}

// ------------------------------------------------- gate*SiLU + RMSNorm -> fp16
__global__ __launch_bounds__(256) void norm_kernel(const float* __restrict__ Ysum,
                                                   const _Float16* __restrict__ gate,
                                                   const float* __restrict__ nw,
                                                   _Float16* __restrict__ hid) {
  int t = blockIdx.x;
  int tid = threadIdx.x;
  float hv[16];
  float ss = 0.f;
#pragma unroll
  for (int k = 0; k < 4; k++) {
    int d = tid * 4 + k * 1024;
    float4 y = *reinterpret_cast<const float4*>(&Ysum[(long)t * 4096 + d]);
    ushort4 gu = *reinterpret_cast<const ushort4*>(gate + (long)t * 4096 + d);
    float h0 = y.x * siluf(h2f(gu.x)), h1 = y.y * siluf(h2f(gu.y));
    float h2 = y.z * siluf(h2f(gu.z)), h3 = y.w * siluf(h2f(gu.w));
    hv[k * 4 + 0] = h0; hv[k * 4 + 1] = h1; hv[k * 4 + 2] = h2; hv[k * 4 + 3] = h3;
    ss += h0 * h0 + h1 * h1 + h2 * h2 + h3 * h3;
  }
#pragma unroll
  for (int o = 32; o > 0; o >>= 1) ss += __shfl_down(ss, o, 64);
  __shared__ float ws4[4];
  if ((tid & 63) == 0) ws4[tid >> 6] = ss;
  __syncthreads();
  float var = (ws4[0] + ws4[1] + ws4[2] + ws4[3]) * (1.f / 4096.f);
  float scale = rsqrtf(var + 1e-5f);
#pragma unroll
  for (int k = 0; k < 4; k++) {
    int d = tid * 4 + k * 1024;
    ushort4 u;
#pragma unroll
    for (int c = 0; c < 4; c++)
      ((unsigned short*)&u)[c] = f2h(hv[k * 4 + c] * scale * nw[d + c]);
    *reinterpret_cast<ushort4*>(hid + (long)t * 4096 + d) = u;
  }
}

// =============================================================== launch
extern "C" void kernel_launch(void* const* d_in, const int* in_sizes, int n_in,
                              void* d_out, int out_size, void* d_ws, size_t ws_size,
                              hipStream_t stream) {
  (void)in_sizes; (void)n_in; (void)out_size; (void)ws_size;
  const float* hs    = (const float*)d_in[0];
  const float* Win   = (const float*)d_in[1];
  const float* convw = (const float*)d_in[2];
  const float* convb = (const float*)d_in[3];
  const float* dtb   = (const float*)d_in[4];
  const float* Alog  = (const float*)d_in[5];
  const float* Dp    = (const float*)d_in[6];
  const float* nw    = (const float*)d_in[7];
  const float* Wout  = (const float*)d_in[8];
  float* out = (float*)d_out;

  char* base = (char*)d_ws;
  size_t off = 0;
  auto take = [&](size_t n) { char* r = base + off; off += (n + 255) & ~(size_t)255; return r; };
  float*    hbcf  = (float*)take(4096UL * 4352 * 4);    // gemm_in -> conv; then Ysum; then out-partials
  _Float16* gateh = (_Float16*)take(4096UL * 4096 * 2); // gemm_in -> norm
  _Float16* Ah    = (_Float16*)take(4096UL * 2048 * 2); // cast -> gemm_in; then WoutT
  _Float16* WtH   = (_Float16*)take(8448UL * 2048 * 2); // trans -> gemm_in; then x16
  _Float16* xT16  = (_Float16*)take(4096UL * 4096 * 2); // xtrans -> states/yfused
  _Float16* B16   = (_Float16*)take(4096UL * 128 * 2);
  _Float16* C16   = (_Float16*)take(4096UL * 128 * 2);
  float*    zf    = (float*)take(4096UL * 64 * 4);
  float*    dt_f  = (float*)take(4096UL * 64 * 4);
  float*    cum_f = (float*)take(4096UL * 64 * 4);
  float*    cuml  = (float*)take(16UL * 64 * 4);
  float*    CBT   = (float*)take(16UL * 256 * 256 * 4);
  float*    states= (float*)take(1024UL * 8192 * 4);    // rparts scratch; -> states -> prevs; then hid
  // overlays:
  float*    Ysum  = hbcf;               // live yfused..norm
  float*    oparts= hbcf;               // live gemm_out8..add_out (2 x 33.5MB in 71MB)
  float*    rparts= states;             // live gemm_in8..add_rem (8 x 4MB = 32MB exact)
  _Float16* WoutT = Ah;                 // written after gemm_in
  _Float16* x16   = WtH;                // 33.6MB in 34.6MB, written by conv
  _Float16* hid   = (_Float16*)states;  // live norm..out_proj

  dim3 tb(32, 8);
  // 1. casts / transposes / exact dt slice
  cast_f16<<<8192, 256, 0, stream>>>(hs, Ah);
  transpose_win<<<dim3(264, 64), tb, 0, stream>>>(Win, WtH);
  dtz_kernel<<<1024, 256, 0, stream>>>(hs, Win, zf);
  // 2. fp16 in_proj GEMM (256^2 8-phase; 512 full tiles + 128 K-split remainder)
  gemm_in8<<<dim3(640), 512, 0, stream>>>(Ah, WtH, gateh, hbcf, rparts);
  // 2b. reduce remainder partials into hbcf cols [4096,4352)
  add_rem<<<1024, 256, 0, stream>>>(rparts, hbcf);
  // 3. out_proj weight transpose into dead Ah
  transpose_wout<<<dim3(64, 128), tb, 0, stream>>>(Wout, WoutT, 4096, 2048);
  // 4. conv + silu -> x16, B16, C16 (fp16)
  conv_silu_kernel<<<dim3(17, 4096), 256, 0, stream>>>(hbcf, convw, convb, x16, B16, C16);
  // 5. dt softplus + cumsum (fp32-exact)
  dt_cum_kernel<<<16, 256, 0, stream>>>(zf, dtb, Alog, dt_f, cum_f, cuml);
  // 6. x16 -> xT16 global transpose
  xtrans<<<dim3(64, 64), 256, 0, stream>>>((const unsigned short*)x16, (unsigned short*)xT16);
  // 7. CBT = C.B^T per chunk (fp16 MFMA, fp32 out)
  gemm_bt<<<dim3(2, 2, 16), 256, 0, stream>>>(C16, B16, CBT, 128, 256,
                                              32768, 32768, 65536);
  // 8. per-chunk states (fp16 MFMA, fp32 out)
  states_mfma<<<dim3(64, 16), 256, 0, stream>>>((const unsigned short*)xT16,
                                                (const unsigned short*)B16,
                                                dt_f, cum_f, cuml, states);
  // 9. inter-chunk recurrence (in-place, fp32)
  recur_kernel<<<128, 256, 0, stream>>>(states, cuml);
  // 10. fused Ydiag + Yoff + D*x -> Ysum (overlays dead hbcf)
  yfused<<<dim3(64, 16), 256, 0, stream>>>((const unsigned short*)xT16,
                                           (const unsigned short*)x16,
                                           (const unsigned short*)C16,
                                           CBT, states, dt_f, cum_f, Dp, Ysum);
  // 11. gate + RMSNorm -> hid fp16 (overlays dead states)
  norm_kernel<<<4096, 256, 0, stream>>>(Ysum, gateh, nw, hid);
  // 12. out_proj GEMM (256^2 8-phase, split-K z=2) -> partials in dead Ysum/hbcf
  gemm_out8<<<dim3(256), 512, 0, stream>>>(hid, WoutT, oparts);
  // 13. sum partials -> d_out fp32
  add_out<<<8192, 256, 0, stream>>>(oparts, out);
}

// Round 5
// 714.129 us; speedup vs baseline: 1.2626x; 1.0885x over previous
//
#include <hip/hip_runtime.h>
#include <hip/hip_bf16.h>

// Mamba2 mixer forward, MI355X. B=2, L=2048, D_MODEL=2048, H=64, P=64, N=128,
// G=1, K=4, CHUNK=256. T = 4096 tokens, 16 chunks.
// Round 5: horizontal fusion (16 -> 10 launches): prep = dtz||cast||twin;
// fuse2 = dt_cum||add_rem||twout; convx = rolling-tap conv+SiLU fused with
// x->xT transpose; fuse3 = states||CBT. GEMMs unchanged from round 4.

typedef __attribute__((ext_vector_type(8))) _Float16 f16x8;
typedef __attribute__((ext_vector_type(4))) float f32x4;

#define GLD16(gp, lp) __builtin_amdgcn_global_load_lds( \
    (__attribute__((address_space(1))) void*)(gp),      \
    (__attribute__((address_space(3))) void*)(lp), 16, 0, 0)

__device__ __forceinline__ unsigned short f2h(float v) {
  _Float16 h = (_Float16)v;
  return *reinterpret_cast<unsigned short*>(&h);
}
__device__ __forceinline__ float h2f(unsigned short u) {
  _Float16 h = *reinterpret_cast<_Float16*>(&u);
  return (float)h;
}
__device__ __forceinline__ float siluf(float x) { return x / (1.f + expf(-x)); }

// ===================== prep: dtz (1024) || cast_f16 (8192) || twin (16896) ===
// dtz first: its 2048-iteration per-block loop is the longest serial segment.
__global__ __launch_bounds__(256) void prep(const float* __restrict__ hs,
                                            const float* __restrict__ Win,
                                            _Float16* __restrict__ Ah,
                                            _Float16* __restrict__ WtH,
                                            float* __restrict__ zf) {
  __shared__ __attribute__((aligned(16))) char smemP[32768];
  const int bid = blockIdx.x;
  const int tid = threadIdx.x;
  if (bid < 1024) {
    // ---- dtz: fp32 dt pre-activation (exact slice)
    float (*Xs)[2048] = reinterpret_cast<float (*)[2048]>(smemP);
    int t0 = bid * 4;
#pragma unroll
    for (int i = 0; i < 8; i++) {
      int e = tid * 4 + i * 1024;
      int tok = e >> 11, k = e & 2047;
      *reinterpret_cast<float4*>(&Xs[tok][k]) =
          *reinterpret_cast<const float4*>(&hs[(long)(t0 + tok) * 2048 + k]);
    }
    __syncthreads();
    int h = tid & 63, tg = tid >> 6;
    float a0 = 0.f, a1 = 0.f, a2 = 0.f, a3 = 0.f;
    const float* wcol = Win + 8448 + h;
    for (int k = 0; k < 2048; k += 4) {
      a0 = fmaf(Xs[tg][k + 0], wcol[(long)(k + 0) * 8512], a0);
      a1 = fmaf(Xs[tg][k + 1], wcol[(long)(k + 1) * 8512], a1);
      a2 = fmaf(Xs[tg][k + 2], wcol[(long)(k + 2) * 8512], a2);
      a3 = fmaf(Xs[tg][k + 3], wcol[(long)(k + 3) * 8512], a3);
    }
    zf[(long)(t0 + tg) * 64 + h] = (a0 + a1) + (a2 + a3);
  } else if (bid < 9216) {
    // ---- cast X -> fp16
    long i = ((long)(bid - 1024) * 256 + tid) * 4;
    float4 v = *reinterpret_cast<const float4*>(hs + i);
    ushort4 u;
    u.x = f2h(v.x); u.y = f2h(v.y); u.z = f2h(v.z); u.w = f2h(v.w);
    *reinterpret_cast<ushort4*>((unsigned short*)Ah + i) = u;
  } else {
    // ---- transpose Win cols [0,8448) -> fp16 [n][k]
    float (*tile)[33] = reinterpret_cast<float (*)[33]>(smemP);
    int i = bid - 9216;
    int c0 = (i % 264) * 32, r0 = (i / 264) * 32;
    int tx = tid & 31, ty = tid >> 5;
#pragma unroll
    for (int j = 0; j < 4; j++)
      tile[ty + j * 8][tx] = Win[(long)(r0 + ty + j * 8) * 8512 + c0 + tx];
    __syncthreads();
#pragma unroll
    for (int j = 0; j < 4; j++) {
      int c = c0 + ty + j * 8, r = r0 + tx;
      WtH[(long)c * 2048 + r] = (_Float16)tile[tx][ty + j * 8];
    }
  }
}

// ===================== in_proj GEMM: 256^2 tile, BK=64, 8-wave 8-phase =======
// (unchanged from round 4: 512 full tiles + 128 K-split remainder, one launch)
__global__ __launch_bounds__(512, 2) void gemm_in8(const _Float16* __restrict__ A,
                                                   const _Float16* __restrict__ Bt,
                                                   _Float16* __restrict__ gate,
                                                   float* __restrict__ hbcf,
                                                   float* __restrict__ rparts) {
  __shared__ __attribute__((aligned(128))) char ldsB[131072];
  const int tid = threadIdx.x;
  const int lane = tid & 63;
  const int wv = tid >> 6;
  const int wr = wv >> 2, wc = wv & 3;  // 2 (M) x 4 (N) waves; wave C = 128x64
  const int wg = blockIdx.x;
  const bool rem = wg >= 512;
  int by, bxn, kbase, zz;
  if (!rem) {  // bijective XCD swizzle over 512 = 8 * 64
    const int swz = (wg & 7) * 64 + (wg >> 3);
    by = swz >> 5; bxn = swz & 31; kbase = 0; zz = 0;
  } else {
    const int idx = wg - 512;
    by = idx & 15; zz = idx >> 4; bxn = 32; kbase = zz * 256;
  }

  const int srow = tid >> 3;
  const int scolg = (tid & 7) ^ (srow & 7);  // inverse-swizzled source col16
  const _Float16* Ab = A + (long)by * 524288 + (long)srow * 2048 + scolg * 8 + kbase;
  const _Float16* Bb = Bt + (long)bxn * 524288 + (long)srow * 2048 + scolg * 8 + kbase;
  const int ldst = tid << 4;

#define STAGE_A(tau, h) do {                                              \
    const _Float16* g_ = Ab + (long)(h) * 262144 + (tau) * 64;            \
    char* l_ = ldsB + ((((tau) & 1) << 2) + (h)) * 16384 + ldst;          \
    GLD16(g_, l_); GLD16(g_ + 131072, l_ + 8192); } while (0)
#define STAGE_B(tau, h) do {                                              \
    const _Float16* g_ = Bb + (long)(h) * 262144 + (tau) * 64;            \
    char* l_ = ldsB + ((((tau) & 1) << 2) + 2 + (h)) * 16384 + ldst;      \
    GLD16(g_, l_); GLD16(g_ + 131072, l_ + 8192); } while (0)

  const int fr = lane & 15;
  const int c16 = (lane >> 4) ^ (fr & 7);
  const int aOff = wr * 16384 + fr * 128 + c16 * 16;
  const int bOff = (2 + (wc >> 1)) * 16384 + ((wc & 1) * 64 + fr) * 128 + c16 * 16;
#define RD_A(b, mi, k32) (*(const f16x8*)(ldsB + ((aOff + (b) * 65536 + (mi) * 2048) ^ ((k32) * 64))))
#define RD_B(b, ni, k32) (*(const f16x8*)(ldsB + ((bOff + (b) * 65536 + (ni) * 2048) ^ ((k32) * 64))))

#define BAR() __builtin_amdgcn_s_barrier()
#define WLG0() asm volatile("s_waitcnt lgkmcnt(0)" ::: "memory")
#define WLG8() asm volatile("s_waitcnt lgkmcnt(8)" ::: "memory")
#define WVM4() asm volatile("s_waitcnt vmcnt(4)" ::: "memory")

  f32x4 acc[8][4];
#pragma unroll
  for (int mi = 0; mi < 8; ++mi)
#pragma unroll
    for (int ni = 0; ni < 4; ++ni) acc[mi][ni] = f32x4{0.f, 0.f, 0.f, 0.f};

  STAGE_A(0, 0); STAGE_A(0, 1); STAGE_B(0, 0); STAGE_B(0, 1);
  STAGE_B(1, 0); STAGE_B(1, 1);
  WVM4(); BAR();

#define MFMA_Q(MI0, MI1, x0, x1, x2, x3, PB)                                        \
  __builtin_amdgcn_s_setprio(1);                                                    \
  _Pragma("unroll") for (int ni = 0; ni < 4; ++ni) {                                \
    acc[MI0][ni] = __builtin_amdgcn_mfma_f32_16x16x32_f16(x0, PB[ni][0], acc[MI0][ni], 0, 0, 0); \
    acc[MI0][ni] = __builtin_amdgcn_mfma_f32_16x16x32_f16(x1, PB[ni][1], acc[MI0][ni], 0, 0, 0); \
    acc[MI1][ni] = __builtin_amdgcn_mfma_f32_16x16x32_f16(x2, PB[ni][0], acc[MI1][ni], 0, 0, 0); \
    acc[MI1][ni] = __builtin_amdgcn_mfma_f32_16x16x32_f16(x3, PB[ni][1], acc[MI1][ni], 0, 0, 0); \
  }                                                                                 \
  __builtin_amdgcn_s_setprio(0);

#define ITER8(u, msk) do {                                                          \
    const int t1 = (2 * (u) + 1) & (msk);                                           \
    const int t2 = (2 * (u) + 2) & (msk);                                           \
    const int t3 = (2 * (u) + 3) & (msk);                                           \
    f16x8 PB0[4][2];                                                                \
    _Pragma("unroll") for (int ni = 0; ni < 4; ++ni) {                              \
      PB0[ni][0] = RD_B(0, ni, 0); PB0[ni][1] = RD_B(0, ni, 1); }                   \
    {                                                                               \
      f16x8 x0 = RD_A(0, 0, 0), x1 = RD_A(0, 0, 1), x2 = RD_A(0, 1, 0), x3 = RD_A(0, 1, 1); \
      STAGE_A(t1, 0); WLG8(); BAR(); WLG0();                                        \
      MFMA_Q(0, 1, x0, x1, x2, x3, PB0) BAR();                                      \
    }                                                                               \
    {                                                                               \
      f16x8 x0 = RD_A(0, 2, 0), x1 = RD_A(0, 2, 1), x2 = RD_A(0, 3, 0), x3 = RD_A(0, 3, 1); \
      STAGE_A(t1, 1); BAR(); WLG0();                                                \
      MFMA_Q(2, 3, x0, x1, x2, x3, PB0) BAR();                                      \
    }                                                                               \
    {                                                                               \
      f16x8 x0 = RD_A(0, 4, 0), x1 = RD_A(0, 4, 1), x2 = RD_A(0, 5, 0), x3 = RD_A(0, 5, 1); \
      STAGE_B(t2, 0); BAR(); WLG0();                                                \
      MFMA_Q(4, 5, x0, x1, x2, x3, PB0) BAR();                                      \
    }                                                                               \
    {                                                                               \
      f16x8 x0 = RD_A(0, 6, 0), x1 = RD_A(0, 6, 1), x2 = RD_A(0, 7, 0), x3 = RD_A(0, 7, 1); \
      STAGE_B(t2, 1); BAR(); WLG0();                                                \
      MFMA_Q(6, 7, x0, x1, x2, x3, PB0) WVM4(); BAR();                              \
    }                                                                               \
    f16x8 PB1[4][2];                                                                \
    _Pragma("unroll") for (int ni = 0; ni < 4; ++ni) {                              \
      PB1[ni][0] = RD_B(1, ni, 0); PB1[ni][1] = RD_B(1, ni, 1); }                   \
    {                                                                               \
      f16x8 x0 = RD_A(1, 0, 0), x1 = RD_A(1, 0, 1), x2 = RD_A(1, 1, 0), x3 = RD_A(1, 1, 1); \
      STAGE_A(t2, 0); WLG8(); BAR(); WLG0();                                        \
      MFMA_Q(0, 1, x0, x1, x2, x3, PB1) BAR();                                      \
    }                                                                               \
    {                                                                               \
      f16x8 x0 = RD_A(1, 2, 0), x1 = RD_A(1, 2, 1), x2 = RD_A(1, 3, 0), x3 = RD_A(1, 3, 1); \
      STAGE_A(t2, 1); BAR(); WLG0();                                                \
      MFMA_Q(2, 3, x0, x1, x2, x3, PB1) BAR();                                      \
    }                                                                               \
    {                                                                               \
      f16x8 x0 = RD_A(1, 4, 0), x1 = RD_A(1, 4, 1), x2 = RD_A(1, 5, 0), x3 = RD_A(1, 5, 1); \
      STAGE_B(t3, 0); BAR(); WLG0();                                                \
      MFMA_Q(4, 5, x0, x1, x2, x3, PB1) BAR();                                      \
    }                                                                               \
    {                                                                               \
      f16x8 x0 = RD_A(1, 6, 0), x1 = RD_A(1, 6, 1), x2 = RD_A(1, 7, 0), x3 = RD_A(1, 7, 1); \
      STAGE_B(t3, 1); BAR(); WLG0();                                                \
      MFMA_Q(6, 7, x0, x1, x2, x3, PB1) WVM4(); BAR();                              \
    }                                                                               \
  } while (0)

  if (!rem) {
    for (int u = 0; u < 16; ++u) ITER8(u, 31);
  } else {
    for (int u = 0; u < 2; ++u) ITER8(u, 3);
  }

  const int m0 = by * 256 + wr * 128;
  const int cl = lane & 15, rq = (lane >> 4) * 4;
  if (!rem) {
    const int n0 = bxn * 256 + wc * 64;
    if (bxn < 16) {
#pragma unroll
      for (int mi = 0; mi < 8; ++mi)
#pragma unroll
        for (int r = 0; r < 4; ++r) {
          long rowoff = (long)(m0 + mi * 16 + rq + r) * 4096 + n0 + cl;
#pragma unroll
          for (int ni = 0; ni < 4; ++ni) gate[rowoff + ni * 16] = (_Float16)acc[mi][ni][r];
        }
    } else {
#pragma unroll
      for (int mi = 0; mi < 8; ++mi)
#pragma unroll
        for (int r = 0; r < 4; ++r) {
          long rowoff = (long)(m0 + mi * 16 + rq + r) * 4352 + (n0 - 4096) + cl;
#pragma unroll
          for (int ni = 0; ni < 4; ++ni) hbcf[rowoff + ni * 16] = acc[mi][ni][r];
        }
    }
  } else {
    float* rp = rparts + (long)zz * 1048576;
    const int ncol = wc * 64;
#pragma unroll
    for (int mi = 0; mi < 8; ++mi)
#pragma unroll
      for (int r = 0; r < 4; ++r) {
        long rowoff = (long)(m0 + mi * 16 + rq + r) * 256 + ncol + cl;
#pragma unroll
        for (int ni = 0; ni < 4; ++ni) rp[rowoff + ni * 16] = acc[mi][ni][r];
      }
  }
#undef STAGE_A
#undef STAGE_B
#undef RD_A
#undef RD_B
#undef ITER8
}

// ============ fuse2: dt_cum (16) || add_rem (1024) || transpose_wout (8192) ==
__global__ __launch_bounds__(256) void fuse2(const float* __restrict__ zf,
                                             const float* __restrict__ dtb,
                                             const float* __restrict__ Alog,
                                             float* __restrict__ dt_f,
                                             float* __restrict__ cum_f,
                                             float* __restrict__ cuml,
                                             const float* __restrict__ rp,
                                             float* __restrict__ hbcf,
                                             const float* __restrict__ Wout,
                                             _Float16* __restrict__ WoutT) {
  __shared__ __attribute__((aligned(16))) char smem2[4352];
  const int bid = blockIdx.x;
  const int tid = threadIdx.x;
  if (bid < 16) {
    // ---- dt softplus + chunk cumsum
    float (*segsum)[64] = reinterpret_cast<float (*)[64]>(smem2);
    int bc = bid;
    int h = tid & 63, seg = tid >> 6;
    int t0 = bc * 256;
    float Ah = -expf(Alog[h]);
    float bias = dtb[h];
    float s = 0.f;
    for (int j = 0; j < 64; j++) {
      int t = t0 + seg * 64 + j;
      float z = zf[(long)t * 64 + h] + bias;
      float v = (z > 20.f) ? z : log1pf(expf(z));
      dt_f[(long)t * 64 + h] = v;
      s += v * Ah;
    }
    segsum[seg][h] = s;
    __syncthreads();
    float run = 0.f;
    for (int k = 0; k < seg; k++) run += segsum[k][h];
    for (int j = 0; j < 64; j++) {
      int t = t0 + seg * 64 + j;
      run += dt_f[(long)t * 64 + h] * Ah;
      cum_f[(long)t * 64 + h] = run;
    }
    if (seg == 3) cuml[bc * 64 + h] = run;
  } else if (bid < 1040) {
    // ---- reduce 8 remainder K-partials into hbcf cols [4096,4352)
    long e = ((long)(bid - 16) * 256 + tid) * 4;
    float4 s = *reinterpret_cast<const float4*>(rp + e);
#pragma unroll
    for (int z = 1; z < 8; ++z) {
      float4 v = *reinterpret_cast<const float4*>(rp + (long)z * 1048576 + e);
      s.x += v.x; s.y += v.y; s.z += v.z; s.w += v.w;
    }
    long row = e >> 8, col = e & 255;
    *reinterpret_cast<float4*>(hbcf + row * 4352 + 4096 + col) = s;
  } else {
    // ---- transpose+cast Wout [4096,2048] fp32 -> WoutT [2048][4096] fp16
    float (*tile)[33] = reinterpret_cast<float (*)[33]>(smem2);
    int i = bid - 1040;
    int c0 = (i & 63) * 32, r0 = (i >> 6) * 32;
    int tx = tid & 31, ty = tid >> 5;
#pragma unroll
    for (int j = 0; j < 4; j++)
      tile[ty + j * 8][tx] = Wout[(long)(r0 + ty + j * 8) * 2048 + c0 + tx];
    __syncthreads();
#pragma unroll
    for (int j = 0; j < 4; j++) {
      int c = c0 + ty + j * 8, r = r0 + tx;
      WoutT[(long)c * 4096 + r] = (_Float16)tile[tx][ty + j * 8];
    }
  }
}

// ======= convx: conv(K=4)+SiLU (rolling taps) fused with x -> xT transpose ===
// grid (68, 64): bx<64 -> x-tile (64 q x 64 t): write x16 row-major + xT16 via
// LDS transpose. bx in [64,68) -> B/C cols [4096,4352): row-major only.
__global__ __launch_bounds__(256) void convx(const float* __restrict__ hbcf,
                                             const float* __restrict__ convw,
                                             const float* __restrict__ convb,
                                             _Float16* __restrict__ x16,
                                             _Float16* __restrict__ B16,
                                             _Float16* __restrict__ C16,
                                             unsigned short* __restrict__ xT16) {
  __shared__ unsigned short tile[64][66];
  const int bx = blockIdx.x, t0 = blockIdx.y * 64;
  const int tid = threadIdx.x;
  const int tq = tid & 63, tg = tid >> 6;
  const int q0 = (bx < 64) ? bx * 64 : 4096 + (bx - 64) * 64;
  const int q = q0 + tq;
  const int ts = t0 + tg * 16;
  const int bstart = ts & ~2047;  // batch start (t and t+15 share a batch)
  const float* colq = hbcf + q;
  float4 wq = *reinterpret_cast<const float4*>(convw + q * 4);
  float bconv = convb[q];
  float v3 = (ts - 3 >= bstart) ? colq[(long)(ts - 3) * 4352] : 0.f;
  float v2 = (ts - 2 >= bstart) ? colq[(long)(ts - 2) * 4352] : 0.f;
  float v1 = (ts - 1 >= bstart) ? colq[(long)(ts - 1) * 4352] : 0.f;
  if (bx < 64) {
#pragma unroll
    for (int j = 0; j < 16; ++j) {
      int t = ts + j;
      float v0 = colq[(long)t * 4352];
      float a = bconv + v3 * wq.x + v2 * wq.y + v1 * wq.z + v0 * wq.w;
      unsigned short o = f2h(siluf(a));
      ((unsigned short*)x16)[(long)t * 4096 + q] = o;
      tile[tg * 16 + j][tq] = o;
      v3 = v2; v2 = v1; v1 = v0;
    }
    __syncthreads();
    int tx = tid & 15, ty = tid >> 4;
#pragma unroll
    for (int i = 0; i < 4; ++i) {
      int c = ty + i * 16;
      ushort4 v;
      v.x = tile[4 * tx + 0][c]; v.y = tile[4 * tx + 1][c];
      v.z = tile[4 * tx + 2][c]; v.w = tile[4 * tx + 3][c];
      *(ushort4*)&xT16[(long)(q0 + c) * 4096 + t0 + 4 * tx] = v;
    }
  } else {
#pragma unroll
    for (int j = 0; j < 16; ++j) {
      int t = ts + j;
      float v0 = colq[(long)t * 4352];
      float a = bconv + v3 * wq.x + v2 * wq.y + v1 * wq.z + v0 * wq.w;
      _Float16 o = (_Float16)siluf(a);
      if (q < 4224) B16[(long)t * 128 + (q - 4096)] = o;
      else C16[(long)t * 128 + (q - 4224)] = o;
      v3 = v2; v2 = v1; v1 = v0;
    }
  }
}

// ================== fuse3: states_mfma (1024) || CBT gemm (64) ==============
__global__ __launch_bounds__(256) void fuse3(const unsigned short* __restrict__ xT16,
                                             const _Float16* __restrict__ B16,
                                             const _Float16* __restrict__ C16,
                                             const float* __restrict__ dt_f,
                                             const float* __restrict__ cum_f,
                                             const float* __restrict__ cuml,
                                             float* __restrict__ states,
                                             float* __restrict__ CBT) {
  __shared__ __attribute__((aligned(16))) char smem3[16384];
  const int bid = blockIdx.x;
  const int tid = threadIdx.x;
  const int wv = tid >> 6, lane = tid & 63;
  const int mr = lane & 15, koff = (lane >> 4) * 8;
  if (bid < 1024) {
    // ---- states[bc,h,p,n] (64x128): sum_t (w_t * x[t][p]) * B[t][n]
    float* w_s = (float*)smem3;                              // 1 KiB
    unsigned short* Aw = (unsigned short*)(smem3 + 1024);    // 64*40 sh
    unsigned short* BT = (unsigned short*)(smem3 + 6144);    // 128*40 sh
    int h = bid & 63, bc = bid >> 6;
    int t0 = bc * 256;
    {
      int t = t0 + tid;
      w_s[tid] = expf(cuml[bc * 64 + h] - cum_f[(long)t * 64 + h]) * dt_f[(long)t * 64 + h];
    }
    __syncthreads();
    f32x4 acc[4][2];
#pragma unroll
    for (int mi = 0; mi < 4; mi++)
#pragma unroll
      for (int nj = 0; nj < 2; nj++) acc[mi][nj] = f32x4{0.f, 0.f, 0.f, 0.f};
    for (int kt = 0; kt < 8; kt++) {
      {
        int p = tid >> 2, tq2 = tid & 3;
        const unsigned short* g = &xT16[((long)(h * 64 + p)) * 4096 + t0 + kt * 32 + tq2 * 8];
        ushort4 u0 = *(const ushort4*)g, u1 = *(const ushort4*)(g + 4);
        const float* wp = &w_s[kt * 32 + tq2 * 8];
        ushort4 o0, o1;
        o0.x = f2h(h2f(u0.x) * wp[0]); o0.y = f2h(h2f(u0.y) * wp[1]);
        o0.z = f2h(h2f(u0.z) * wp[2]); o0.w = f2h(h2f(u0.w) * wp[3]);
        o1.x = f2h(h2f(u1.x) * wp[4]); o1.y = f2h(h2f(u1.y) * wp[5]);
        o1.z = f2h(h2f(u1.z) * wp[6]); o1.w = f2h(h2f(u1.w) * wp[7]);
        *(ushort4*)&Aw[p * 40 + tq2 * 8] = o0;
        *(ushort4*)&Aw[p * 40 + tq2 * 8 + 4] = o1;
      }
      {
        int tl = tid >> 3, ng = tid & 7;
        const unsigned short* g = (const unsigned short*)B16 +
                                  ((long)(t0 + kt * 32 + tl)) * 128 + ng * 16;
#pragma unroll
        for (int j = 0; j < 16; j++) BT[(ng * 16 + j) * 40 + tl] = g[j];
      }
      __syncthreads();
      f16x8 af[4], bf[2];
#pragma unroll
      for (int mi = 0; mi < 4; mi++)
        af[mi] = *(const f16x8*)&Aw[(mi * 16 + mr) * 40 + koff];
#pragma unroll
      for (int nj = 0; nj < 2; nj++)
        bf[nj] = *(const f16x8*)&BT[((wv * 2 + nj) * 16 + mr) * 40 + koff];
#pragma unroll
      for (int mi = 0; mi < 4; mi++)
#pragma unroll
        for (int nj = 0; nj < 2; nj++)
          acc[mi][nj] = __builtin_amdgcn_mfma_f32_16x16x32_f16(af[mi], bf[nj],
                                                               acc[mi][nj], 0, 0, 0);
      __syncthreads();
    }
    int cl = lane & 15, rq = (lane >> 4) * 4;
    long base = ((long)(bc * 64 + h)) * 8192;
#pragma unroll
    for (int mi = 0; mi < 4; mi++)
#pragma unroll
      for (int r = 0; r < 4; r++) {
        int p = mi * 16 + rq + r;
#pragma unroll
        for (int nj = 0; nj < 2; nj++) {
          int n = (wv * 2 + nj) * 16 + cl;
          states[base + p * 128 + n] = acc[mi][nj][r];
        }
      }
  } else {
    // ---- CBT = C.B^T per chunk (128x128 tile, K=128), 64 blocks
    _Float16* As = (_Float16*)smem3;
    _Float16* Bs = (_Float16*)(smem3 + 8192);
    int i = bid - 1024;
    int bx = i & 1, by = (i >> 1) & 1, bz = i >> 2;
    const _Float16* Ab = C16 + (long)bz * 32768 + (long)by * 128 * 128;
    const _Float16* Bb = B16 + (long)bz * 32768 + (long)bx * 128 * 128;
    const int c0 = wv * 128 + lane;
    const int c1 = c0 + 64;
    const long ra0 = (long)(c0 >> 2) * 128 + (c0 & 3) * 8;
    const long ra1 = (long)(c1 >> 2) * 128 + (c1 & 3) * 8;
    f32x4 acc[4][4];
#pragma unroll
    for (int mi = 0; mi < 4; mi++)
#pragma unroll
      for (int ni = 0; ni < 4; ni++) acc[mi][ni] = f32x4{0.f, 0.f, 0.f, 0.f};
    const int mrow = (wv & 1) * 64 + (lane & 15);
    const int nrow = (wv >> 1) * 64 + (lane & 15);
    for (int k0 = 0; k0 < 128; k0 += 32) {
      GLD16(Ab + ra0 + k0, (char*)As + c0 * 16);
      GLD16(Ab + ra1 + k0, (char*)As + c1 * 16);
      GLD16(Bb + ra0 + k0, (char*)Bs + c0 * 16);
      GLD16(Bb + ra1 + k0, (char*)Bs + c1 * 16);
      __syncthreads();
      f16x8 af[4], bfr[4];
#pragma unroll
      for (int mi = 0; mi < 4; mi++)
        af[mi] = *(const f16x8*)(As + (mrow + mi * 16) * 32 + koff);
#pragma unroll
      for (int ni = 0; ni < 4; ni++)
        bfr[ni] = *(const f16x8*)(Bs + (nrow + ni * 16) * 32 + koff);
#pragma unroll
      for (int mi = 0; mi < 4; mi++)
#pragma unroll
        for (int ni = 0; ni < 4; ni++)
          acc[mi][ni] = __builtin_amdgcn_mfma_f32_16x16x32_f16(af[mi], bfr[ni],
                                                               acc[mi][ni], 0, 0, 0);
      __syncthreads();
    }
    const int m0 = by * 128 + (wv & 1) * 64;
    const int n0 = bx * 128 + (wv >> 1) * 64;
    const int cl = lane & 15, rq = (lane >> 4) * 4;
    const long zc = (long)bz * 65536;
#pragma unroll
    for (int mi = 0; mi < 4; mi++)
#pragma unroll
      for (int r = 0; r < 4; r++) {
        long rowoff = zc + (long)(m0 + mi * 16 + rq + r) * 256 + n0 + cl;
#pragma unroll
        for (int ni = 0; ni < 4; ni++) CBT[rowoff + ni * 16] = acc[mi][ni][r];
      }
  }
}

// --------------------------------- inter-chunk recurrence (in-place -> prevs)
__global__ __launch_bounds__(256) void recur_kernel(float* __restrict__ states,
                                                    const float* __restrict__ cuml) {
  int bh = blockIdx.x;
  int b = bh >> 6, h = bh & 63;
  int tid = threadIdx.x;
  float4 prev[8];
#pragma unroll
  for (int j = 0; j < 8; j++) prev[j] = make_float4(0.f, 0.f, 0.f, 0.f);
  for (int c = 0; c < 8; c++) {
    int bc = b * 8 + c;
    float cd = expf(cuml[bc * 64 + h]);
    long base = (long)(bc * 64 + h) * 8192;
#pragma unroll
    for (int j = 0; j < 8; j++) {
      long o = base + j * 1024 + tid * 4;
      float4 st = *reinterpret_cast<const float4*>(&states[o]);
      *reinterpret_cast<float4*>(&states[o]) = prev[j];
      prev[j].x = fmaf(cd, prev[j].x, st.x);
      prev[j].y = fmaf(cd, prev[j].y, st.y);
      prev[j].z = fmaf(cd, prev[j].z, st.z);
      prev[j].w = fmaf(cd, prev[j].w, st.w);
    }
  }
}

// ---------------- fused Y = Ydiag + Yoff + D*x  via MFMA, per (h, bc) block
__global__ __launch_bounds__(256) void yfused(const unsigned short* __restrict__ xT16,
                                              const unsigned short* __restrict__ x16,
                                              const unsigned short* __restrict__ C16,
                                              const float* __restrict__ CBT,
                                              const float* __restrict__ states,
                                              const float* __restrict__ dt_f,
                                              const float* __restrict__ cum_f,
                                              const float* __restrict__ Dp,
                                              float* __restrict__ Ysum) {
  int h = blockIdx.x, bc = blockIdx.y;
  int t0 = bc * 256, tid = threadIdx.x;
  __shared__ unsigned short Sb[256 * 40];
  __shared__ unsigned short Xb[64 * 264];
  __shared__ float cum_s[256], dt_s[256];
  int i = tid;
  cum_s[i] = cum_f[(long)(t0 + i) * 64 + h];
  dt_s[i] = dt_f[(long)(t0 + i) * 64 + h];
  {
    int p = tid >> 2, tq = tid & 3;
    const unsigned short* g = &xT16[((long)(h * 64 + p)) * 4096 + t0 + tq * 64];
    unsigned short* l = &Xb[p * 264 + tq * 64];
#pragma unroll
    for (int c = 0; c < 8; c++)
      *(uint4*)(l + c * 8) = *(const uint4*)(g + c * 8);
  }
  __syncthreads();
  float cum_i = cum_s[i];
  const float* cbrow = CBT + (long)bc * 65536 + (long)i * 256;
  int wv = tid >> 6, lane = tid & 63;
  int mr = lane & 15, koff = (lane >> 4) * 8;
  f32x4 acc[4][4];
#pragma unroll
  for (int mi = 0; mi < 4; mi++)
#pragma unroll
    for (int ni = 0; ni < 4; ni++) acc[mi][ni] = f32x4{0.f, 0.f, 0.f, 0.f};
  for (int kt = 0; kt < 8; kt++) {
    int k0 = kt * 32;
#pragma unroll
    for (int c = 0; c < 8; c++) {
      float4 cb = *(const float4*)&cbrow[k0 + c * 4];
      ushort4 o;
      {
        int j = k0 + c * 4 + 0;
        float s = (j <= i) ? cb.x * expf(cum_i - cum_s[j]) * dt_s[j] : 0.f;
        o.x = f2h(s);
      }
      {
        int j = k0 + c * 4 + 1;
        float s = (j <= i) ? cb.y * expf(cum_i - cum_s[j]) * dt_s[j] : 0.f;
        o.y = f2h(s);
      }
      {
        int j = k0 + c * 4 + 2;
        float s = (j <= i) ? cb.z * expf(cum_i - cum_s[j]) * dt_s[j] : 0.f;
        o.z = f2h(s);
      }
      {
        int j = k0 + c * 4 + 3;
        float s = (j <= i) ? cb.w * expf(cum_i - cum_s[j]) * dt_s[j] : 0.f;
        o.w = f2h(s);
      }
      *(ushort4*)&Sb[i * 40 + c * 4] = o;
    }
    __syncthreads();
    if (kt <= 2 * wv + 1) {
      f16x8 af[4], bf[4];
#pragma unroll
      for (int mi = 0; mi < 4; mi++)
        af[mi] = *(const f16x8*)&Sb[(64 * wv + mi * 16 + mr) * 40 + koff];
#pragma unroll
      for (int ni = 0; ni < 4; ni++)
        bf[ni] = *(const f16x8*)&Xb[(ni * 16 + mr) * 264 + k0 + koff];
#pragma unroll
      for (int mi = 0; mi < 4; mi++)
#pragma unroll
        for (int ni = 0; ni < 4; ni++)
          acc[mi][ni] = __builtin_amdgcn_mfma_f32_16x16x32_f16(af[mi], bf[ni],
                                                               acc[mi][ni], 0, 0, 0);
    }
    __syncthreads();
  }
  {
    int p = tid >> 2, nq = tid & 3;
    const float* g = &states[((long)(bc * 64 + h)) * 8192 + p * 128 + nq * 32];
    unsigned short* l = &Xb[p * 136 + nq * 32];
#pragma unroll
    for (int c = 0; c < 8; c++) {
      float4 v = *(const float4*)(g + c * 4);
      ushort4 u;
      u.x = f2h(v.x); u.y = f2h(v.y); u.z = f2h(v.z); u.w = f2h(v.w);
      *(ushort4*)(l + c * 4) = u;
    }
  }
  float fac_i = expf(cum_i);
  for (int kn = 0; kn < 4; kn++) {
    {
      const unsigned short* g = &C16[((long)(t0 + i)) * 128 + kn * 32];
#pragma unroll
      for (int c = 0; c < 8; c++) {
        ushort4 u = *(const ushort4*)(g + c * 4);
        ushort4 o;
        o.x = f2h(h2f(u.x) * fac_i); o.y = f2h(h2f(u.y) * fac_i);
        o.z = f2h(h2f(u.z) * fac_i); o.w = f2h(h2f(u.w) * fac_i);
        *(ushort4*)&Sb[i * 40 + c * 4] = o;
      }
    }
    __syncthreads();
    f16x8 af[4], bf[4];
#pragma unroll
    for (int mi = 0; mi < 4; mi++)
      af[mi] = *(const f16x8*)&Sb[(64 * wv + mi * 16 + mr) * 40 + koff];
#pragma unroll
    for (int ni = 0; ni < 4; ni++)
      bf[ni] = *(const f16x8*)&Xb[(ni * 16 + mr) * 136 + kn * 32 + koff];
#pragma unroll
    for (int mi = 0; mi < 4; mi++)
#pragma unroll
      for (int ni = 0; ni < 4; ni++)
        acc[mi][ni] = __builtin_amdgcn_mfma_f32_16x16x32_f16(af[mi], bf[ni],
                                                             acc[mi][ni], 0, 0, 0);
    __syncthreads();
  }
  float Dh = Dp[h];
  int cl = lane & 15, rq = (lane >> 4) * 4;
#pragma unroll
  for (int mi = 0; mi < 4; mi++)
#pragma unroll
    for (int r = 0; r < 4; r++) {
      long row = t0 + 64 * wv + mi * 16 + rq + r;
      float* yr = &Ysum[row * 4096 + h * 64];
      const unsigned short* xr = &x16[row * 4096 + h * 64];
#pragma unroll
      for (int ni = 0; ni < 4; ni++) {
        int p = ni * 16 + cl;
        yr[p] = acc[mi][ni][r] + Dh * h2f(xr[p]);
      }
    }
}

// ------------------------------------------------- gate*SiLU + RMSNorm -> fp16
__global__ __launch_bounds__(256) void norm_kernel(const float* __restrict__ Ysum,
                                                   const _Float16* __restrict__ gate,
                                                   const float* __restrict__ nw,
                                                   _Float16* __restrict__ hid) {
  int t = blockIdx.x;
  int tid = threadIdx.x;
  float hv[16];
  float ss = 0.f;
#pragma unroll
  for (int k = 0; k < 4; k++) {
    int d = tid * 4 + k * 1024;
    float4 y = *reinterpret_cast<const float4*>(&Ysum[(long)t * 4096 + d]);
    ushort4 gu = *reinterpret_cast<const ushort4*>(gate + (long)t * 4096 + d);
    float h0 = y.x * siluf(h2f(gu.x)), h1 = y.y * siluf(h2f(gu.y));
    float h2 = y.z * siluf(h2f(gu.z)), h3 = y.w * siluf(h2f(gu.w));
    hv[k * 4 + 0] = h0; hv[k * 4 + 1] = h1; hv[k * 4 + 2] = h2; hv[k * 4 + 3] = h3;
    ss += h0 * h0 + h1 * h1 + h2 * h2 + h3 * h3;
  }
#pragma unroll
  for (int o = 32; o > 0; o >>= 1) ss += __shfl_down(ss, o, 64);
  __shared__ float ws4[4];
  if ((tid & 63) == 0) ws4[tid >> 6] = ss;
  __syncthreads();
  float var = (ws4[0] + ws4[1] + ws4[2] + ws4[3]) * (1.f / 4096.f);
  float scale = rsqrtf(var + 1e-5f);
#pragma unroll
  for (int k = 0; k < 4; k++) {
    int d = tid * 4 + k * 1024;
    ushort4 u;
#pragma unroll
    for (int c = 0; c < 4; c++)
      ((unsigned short*)&u)[c] = f2h(hv[k * 4 + c] * scale * nw[d + c]);
    *reinterpret_cast<ushort4*>(hid + (long)t * 4096 + d) = u;
  }
}

// ===================== out_proj GEMM: 256^2 tile, split-K (z=2), 8-phase =====
__global__ __launch_bounds__(512, 2) void gemm_out8(const _Float16* __restrict__ A,
                                                    const _Float16* __restrict__ Bt,
                                                    float* __restrict__ Cp) {
  __shared__ __attribute__((aligned(128))) char ldsB[131072];
  const int tid = threadIdx.x;
  const int lane = tid & 63;
  const int wv = tid >> 6;
  const int wr = wv >> 2, wc = wv & 3;
  const int wg = blockIdx.x;
  const int z = wg >> 7;
  const int r7 = wg & 127;
  const int sw = (r7 & 7) * 16 + (r7 >> 3);
  const int by = sw >> 3, bx = sw & 7;

  const int srow = tid >> 3;
  const int scolg = (tid & 7) ^ (srow & 7);
  const _Float16* Ab = A + (long)by * 256 * 4096 + (long)z * 2048 +
                       (long)srow * 4096 + scolg * 8;
  const _Float16* Bb = Bt + (long)bx * 256 * 4096 + (long)z * 2048 +
                       (long)srow * 4096 + scolg * 8;
  const int ldst = tid << 4;

#define STAGE_A(tau, h) do {                                              \
    const _Float16* g_ = Ab + (long)(h) * 524288 + (tau) * 64;            \
    char* l_ = ldsB + ((((tau) & 1) << 2) + (h)) * 16384 + ldst;          \
    GLD16(g_, l_); GLD16(g_ + 262144, l_ + 8192); } while (0)
#define STAGE_B(tau, h) do {                                              \
    const _Float16* g_ = Bb + (long)(h) * 524288 + (tau) * 64;            \
    char* l_ = ldsB + ((((tau) & 1) << 2) + 2 + (h)) * 16384 + ldst;      \
    GLD16(g_, l_); GLD16(g_ + 262144, l_ + 8192); } while (0)

  const int fr = lane & 15;
  const int c16 = (lane >> 4) ^ (fr & 7);
  const int aOff = wr * 16384 + fr * 128 + c16 * 16;
  const int bOff = (2 + (wc >> 1)) * 16384 + ((wc & 1) * 64 + fr) * 128 + c16 * 16;
#define RD_A(b, mi, k32) (*(const f16x8*)(ldsB + ((aOff + (b) * 65536 + (mi) * 2048) ^ ((k32) * 64))))
#define RD_B(b, ni, k32) (*(const f16x8*)(ldsB + ((bOff + (b) * 65536 + (ni) * 2048) ^ ((k32) * 64))))

  f32x4 acc[8][4];
#pragma unroll
  for (int mi = 0; mi < 8; ++mi)
#pragma unroll
    for (int ni = 0; ni < 4; ++ni) acc[mi][ni] = f32x4{0.f, 0.f, 0.f, 0.f};

  STAGE_A(0, 0); STAGE_A(0, 1); STAGE_B(0, 0); STAGE_B(0, 1);
  STAGE_B(1, 0); STAGE_B(1, 1);
  WVM4(); BAR();

  for (int u = 0; u < 16; ++u) {
    const int t1 = 2 * u + 1;
    const int t2 = (2 * u + 2) & 31;
    const int t3 = (2 * u + 3) & 31;
    f16x8 PB0[4][2];
#pragma unroll
    for (int ni = 0; ni < 4; ++ni) { PB0[ni][0] = RD_B(0, ni, 0); PB0[ni][1] = RD_B(0, ni, 1); }
    {
      f16x8 x0 = RD_A(0, 0, 0), x1 = RD_A(0, 0, 1), x2 = RD_A(0, 1, 0), x3 = RD_A(0, 1, 1);
      STAGE_A(t1, 0); WLG8(); BAR(); WLG0();
      MFMA_Q(0, 1, x0, x1, x2, x3, PB0) BAR();
    }
    {
      f16x8 x0 = RD_A(0, 2, 0), x1 = RD_A(0, 2, 1), x2 = RD_A(0, 3, 0), x3 = RD_A(0, 3, 1);
      STAGE_A(t1, 1); BAR(); WLG0();
      MFMA_Q(2, 3, x0, x1, x2, x3, PB0) BAR();
    }
    {
      f16x8 x0 = RD_A(0, 4, 0), x1 = RD_A(0, 4, 1), x2 = RD_A(0, 5, 0), x3 = RD_A(0, 5, 1);
      STAGE_B(t2, 0); BAR(); WLG0();
      MFMA_Q(4, 5, x0, x1, x2, x3, PB0) BAR();
    }
    {
      f16x8 x0 = RD_A(0, 6, 0), x1 = RD_A(0, 6, 1), x2 = RD_A(0, 7, 0), x3 = RD_A(0, 7, 1);
      STAGE_B(t2, 1); BAR(); WLG0();
      MFMA_Q(6, 7, x0, x1, x2, x3, PB0) WVM4(); BAR();
    }
    f16x8 PB1[4][2];
#pragma unroll
    for (int ni = 0; ni < 4; ++ni) { PB1[ni][0] = RD_B(1, ni, 0); PB1[ni][1] = RD_B(1, ni, 1); }
    {
      f16x8 x0 = RD_A(1, 0, 0), x1 = RD_A(1, 0, 1), x2 = RD_A(1, 1, 0), x3 = RD_A(1, 1, 1);
      STAGE_A(t2, 0); WLG8(); BAR(); WLG0();
      MFMA_Q(0, 1, x0, x1, x2, x3, PB1) BAR();
    }
    {
      f16x8 x0 = RD_A(1, 2, 0), x1 = RD_A(1, 2, 1), x2 = RD_A(1, 3, 0), x3 = RD_A(1, 3, 1);
      STAGE_A(t2, 1); BAR(); WLG0();
      MFMA_Q(2, 3, x0, x1, x2, x3, PB1) BAR();
    }
    {
      f16x8 x0 = RD_A(1, 4, 0), x1 = RD_A(1, 4, 1), x2 = RD_A(1, 5, 0), x3 = RD_A(1, 5, 1);
      STAGE_B(t3, 0); BAR(); WLG0();
      MFMA_Q(4, 5, x0, x1, x2, x3, PB1) BAR();
    }
    {
      f16x8 x0 = RD_A(1, 6, 0), x1 = RD_A(1, 6, 1), x2 = RD_A(1, 7, 0), x3 = RD_A(1, 7, 1);
      STAGE_B(t3, 1); BAR(); WLG0();
      MFMA_Q(6, 7, x0, x1, x2, x3, PB1) WVM4(); BAR();
    }
  }
  const int m0 = by * 256 + wr * 128;
  const int n0 = bx * 256 + wc * 64;
  const int cl = lane & 15, rq = (lane >> 4) * 4;
  float* Cb = Cp + (long)z * 8388608;
#pragma unroll
  for (int mi = 0; mi < 8; ++mi)
#pragma unroll
    for (int r = 0; r < 4; ++r) {
      long rowoff = (long)(m0 + mi * 16 + rq + r) * 2048 + n0 + cl;
#pragma unroll
      for (int ni = 0; ni < 4; ++ni) Cb[rowoff + ni * 16] = acc[mi][ni][r];
    }
#undef STAGE_A
#undef STAGE_B
#undef RD_A
#undef RD_B
#undef BAR
#undef WLG0
#undef WLG8
#undef WVM4
#undef MFMA_Q
}

// -------------------------------------------- sum the two split-K partials
__global__ __launch_bounds__(256) void add_out(const float* __restrict__ p,
                                               float* __restrict__ o) {
  long i = ((long)blockIdx.x * 256 + threadIdx.x) * 4;
  float4 a = *reinterpret_cast<const float4*>(p + i);
  float4 b = *reinterpret_cast<const float4*>(p + 8388608 + i);
  float4 r;
  r.x = a.x + b.x; r.y = a.y + b.y; r.z = a.z + b.z; r.w = a.w + b.w;
  *reinterpret_cast<float4*>(o + i) = r;
}

// =============================================================== launch
extern "C" void kernel_launch(void* const* d_in, const int* in_sizes, int n_in,
                              void* d_out, int out_size, void* d_ws, size_t ws_size,
                              hipStream_t stream) {
  (void)in_sizes; (void)n_in; (void)out_size; (void)ws_size;
  const float* hs    = (const float*)d_in[0];
  const float* Win   = (const float*)d_in[1];
  const float* convw = (const float*)d_in[2];
  const float* convb = (const float*)d_in[3];
  const float* dtb   = (const float*)d_in[4];
  const float* Alog  = (const float*)d_in[5];
  const float* Dp    = (const float*)d_in[6];
  const float* nw    = (const float*)d_in[7];
  const float* Wout  = (const float*)d_in[8];
  float* out = (float*)d_out;

  char* base = (char*)d_ws;
  size_t off = 0;
  auto take = [&](size_t n) { char* r = base + off; off += (n + 255) & ~(size_t)255; return r; };
  float*    hbcf  = (float*)take(4096UL * 4352 * 4);    // gemm_in -> conv; then Ysum; then out-partials
  _Float16* gateh = (_Float16*)take(4096UL * 4096 * 2); // gemm_in -> norm
  _Float16* Ah    = (_Float16*)take(4096UL * 2048 * 2); // cast -> gemm_in; then WoutT
  _Float16* WtH   = (_Float16*)take(8448UL * 2048 * 2); // trans -> gemm_in; then x16
  _Float16* xT16  = (_Float16*)take(4096UL * 4096 * 2); // convx -> states/yfused
  _Float16* B16   = (_Float16*)take(4096UL * 128 * 2);
  _Float16* C16   = (_Float16*)take(4096UL * 128 * 2);
  float*    zf    = (float*)take(4096UL * 64 * 4);
  float*    dt_f  = (float*)take(4096UL * 64 * 4);
  float*    cum_f = (float*)take(4096UL * 64 * 4);
  float*    cuml  = (float*)take(16UL * 64 * 4);
  float*    CBT   = (float*)take(16UL * 256 * 256 * 4);
  float*    states= (float*)take(1024UL * 8192 * 4);    // rparts scratch; -> states -> prevs; then hid
  // overlays:
  float*    Ysum  = hbcf;               // live yfused..norm
  float*    oparts= hbcf;               // live gemm_out8..add_out
  float*    rparts= states;             // live gemm_in8..fuse2 (8 x 4MB = 32MB)
  _Float16* WoutT = Ah;                 // written by fuse2 (after gemm_in8)
  _Float16* x16   = WtH;                // written by convx (after gemm_in8)
  _Float16* hid   = (_Float16*)states;  // live norm..out_proj

  // 1. prep: dtz || cast || transpose_win (one launch)
  prep<<<26112, 256, 0, stream>>>(hs, Win, Ah, WtH, zf);
  // 2. fp16 in_proj GEMM (256^2 8-phase; 512 full + 128 K-split remainder)
  gemm_in8<<<dim3(640), 512, 0, stream>>>(Ah, WtH, gateh, hbcf, rparts);
  // 3. fuse2: dt_cum || add_rem || transpose_wout (one launch)
  fuse2<<<9232, 256, 0, stream>>>(zf, dtb, Alog, dt_f, cum_f, cuml,
                                  rparts, hbcf, Wout, WoutT);
  // 4. convx: rolling-tap conv+SiLU fused with x->xT transpose
  convx<<<dim3(68, 64), 256, 0, stream>>>(hbcf, convw, convb, x16, B16, C16,
                                          (unsigned short*)xT16);
  // 5. fuse3: states_mfma || CBT gemm (one launch)
  fuse3<<<1088, 256, 0, stream>>>((const unsigned short*)xT16, B16, C16,
                                  dt_f, cum_f, cuml, states, CBT);
  // 6. inter-chunk recurrence (in-place, fp32)
  recur_kernel<<<128, 256, 0, stream>>>(states, cuml);
  // 7. fused Ydiag + Yoff + D*x -> Ysum (overlays dead hbcf)
  yfused<<<dim3(64, 16), 256, 0, stream>>>((const unsigned short*)xT16,
                                           (const unsigned short*)x16,
                                           (const unsigned short*)C16,
                                           CBT, states, dt_f, cum_f, Dp, Ysum);
  // 8. gate + RMSNorm -> hid fp16 (overlays dead states)
  norm_kernel<<<4096, 256, 0, stream>>>(Ysum, gateh, nw, hid);
  // 9. out_proj GEMM (256^2 8-phase, split-K z=2) -> partials in dead hbcf
  gemm_out8<<<dim3(256), 512, 0, stream>>>(hid, WoutT, oparts);
  // 10. sum partials -> d_out fp32
  add_out<<<8192, 256, 0, stream>>>(oparts, out);
}

// Round 6
// 695.222 us; speedup vs baseline: 1.2970x; 1.0272x over previous
//
#include <hip/hip_runtime.h>
#include <hip/hip_bf16.h>

// Mamba2 mixer forward, MI355X. B=2, L=2048, D_MODEL=2048, H=64, P=64, N=128,
// G=1, K=4, CHUNK=256. T = 4096 tokens, 16 chunks.
// Round 6: square per-XCD tile regions in gemm_in8/gemm_out8 (L2 locality:
// per-XCD fetch 34MB strip -> 16MB square), recur parallelized 128->1024 blocks.
// Everything else unchanged from round 5.

typedef __attribute__((ext_vector_type(8))) _Float16 f16x8;
typedef __attribute__((ext_vector_type(4))) float f32x4;

#define GLD16(gp, lp) __builtin_amdgcn_global_load_lds( \
    (__attribute__((address_space(1))) void*)(gp),      \
    (__attribute__((address_space(3))) void*)(lp), 16, 0, 0)

__device__ __forceinline__ unsigned short f2h(float v) {
  _Float16 h = (_Float16)v;
  return *reinterpret_cast<unsigned short*>(&h);
}
__device__ __forceinline__ float h2f(unsigned short u) {
  _Float16 h = *reinterpret_cast<_Float16*>(&u);
  return (float)h;
}
__device__ __forceinline__ float siluf(float x) { return x / (1.f + expf(-x)); }

// ===================== prep: dtz (1024) || cast_f16 (8192) || twin (16896) ===
__global__ __launch_bounds__(256) void prep(const float* __restrict__ hs,
                                            const float* __restrict__ Win,
                                            _Float16* __restrict__ Ah,
                                            _Float16* __restrict__ WtH,
                                            float* __restrict__ zf) {
  __shared__ __attribute__((aligned(16))) char smemP[32768];
  const int bid = blockIdx.x;
  const int tid = threadIdx.x;
  if (bid < 1024) {
    // ---- dtz: fp32 dt pre-activation (exact slice)
    float (*Xs)[2048] = reinterpret_cast<float (*)[2048]>(smemP);
    int t0 = bid * 4;
#pragma unroll
    for (int i = 0; i < 8; i++) {
      int e = tid * 4 + i * 1024;
      int tok = e >> 11, k = e & 2047;
      *reinterpret_cast<float4*>(&Xs[tok][k]) =
          *reinterpret_cast<const float4*>(&hs[(long)(t0 + tok) * 2048 + k]);
    }
    __syncthreads();
    int h = tid & 63, tg = tid >> 6;
    float a0 = 0.f, a1 = 0.f, a2 = 0.f, a3 = 0.f;
    const float* wcol = Win + 8448 + h;
    for (int k = 0; k < 2048; k += 4) {
      a0 = fmaf(Xs[tg][k + 0], wcol[(long)(k + 0) * 8512], a0);
      a1 = fmaf(Xs[tg][k + 1], wcol[(long)(k + 1) * 8512], a1);
      a2 = fmaf(Xs[tg][k + 2], wcol[(long)(k + 2) * 8512], a2);
      a3 = fmaf(Xs[tg][k + 3], wcol[(long)(k + 3) * 8512], a3);
    }
    zf[(long)(t0 + tg) * 64 + h] = (a0 + a1) + (a2 + a3);
  } else if (bid < 9216) {
    // ---- cast X -> fp16
    long i = ((long)(bid - 1024) * 256 + tid) * 4;
    float4 v = *reinterpret_cast<const float4*>(hs + i);
    ushort4 u;
    u.x = f2h(v.x); u.y = f2h(v.y); u.z = f2h(v.z); u.w = f2h(v.w);
    *reinterpret_cast<ushort4*>((unsigned short*)Ah + i) = u;
  } else {
    // ---- transpose Win cols [0,8448) -> fp16 [n][k]
    float (*tile)[33] = reinterpret_cast<float (*)[33]>(smemP);
    int i = bid - 9216;
    int c0 = (i % 264) * 32, r0 = (i / 264) * 32;
    int tx = tid & 31, ty = tid >> 5;
#pragma unroll
    for (int j = 0; j < 4; j++)
      tile[ty + j * 8][tx] = Win[(long)(r0 + ty + j * 8) * 8512 + c0 + tx];
    __syncthreads();
#pragma unroll
    for (int j = 0; j < 4; j++) {
      int c = c0 + ty + j * 8, r = r0 + tx;
      WtH[(long)c * 2048 + r] = (_Float16)tile[tx][ty + j * 8];
    }
  }
}

// ===================== in_proj GEMM: 256^2 tile, BK=64, 8-wave 8-phase =======
// Grid 640: wg [0,512) full tiles with SQUARE per-XCD regions (XCD = wg&7 owns
// an 8x8 (by,bxn) block -> per-XCD fetch ~16MB instead of ~35MB strip);
// wg [512,640): remainder strip N-cols [8192,8448), 16 M x 8 K-slices.
__global__ __launch_bounds__(512, 2) void gemm_in8(const _Float16* __restrict__ A,
                                                   const _Float16* __restrict__ Bt,
                                                   _Float16* __restrict__ gate,
                                                   float* __restrict__ hbcf,
                                                   float* __restrict__ rparts) {
  __shared__ __attribute__((aligned(128))) char ldsB[131072];
  const int tid = threadIdx.x;
  const int lane = tid & 63;
  const int wv = tid >> 6;
  const int wr = wv >> 2, wc = wv & 3;  // 2 (M) x 4 (N) waves; wave C = 128x64
  const int wg = blockIdx.x;
  const bool rem = wg >= 512;
  int by, bxn, kbase, zz;
  if (!rem) {  // square per-XCD mapping: XCD (wg&7) owns 8(by) x 8(bxn)
    const int xcd = wg & 7, j = wg >> 3;
    by = (xcd >> 2) * 8 + (j >> 3);
    bxn = (xcd & 3) * 8 + (j & 7);
    kbase = 0; zz = 0;
  } else {
    const int idx = wg - 512;
    by = idx & 15; zz = idx >> 4; bxn = 32; kbase = zz * 256;
  }

  const int srow = tid >> 3;
  const int scolg = (tid & 7) ^ (srow & 7);  // inverse-swizzled source col16
  const _Float16* Ab = A + (long)by * 524288 + (long)srow * 2048 + scolg * 8 + kbase;
  const _Float16* Bb = Bt + (long)bxn * 524288 + (long)srow * 2048 + scolg * 8 + kbase;
  const int ldst = tid << 4;

#define STAGE_A(tau, h) do {                                              \
    const _Float16* g_ = Ab + (long)(h) * 262144 + (tau) * 64;            \
    char* l_ = ldsB + ((((tau) & 1) << 2) + (h)) * 16384 + ldst;          \
    GLD16(g_, l_); GLD16(g_ + 131072, l_ + 8192); } while (0)
#define STAGE_B(tau, h) do {                                              \
    const _Float16* g_ = Bb + (long)(h) * 262144 + (tau) * 64;            \
    char* l_ = ldsB + ((((tau) & 1) << 2) + 2 + (h)) * 16384 + ldst;      \
    GLD16(g_, l_); GLD16(g_ + 131072, l_ + 8192); } while (0)

  const int fr = lane & 15;
  const int c16 = (lane >> 4) ^ (fr & 7);
  const int aOff = wr * 16384 + fr * 128 + c16 * 16;
  const int bOff = (2 + (wc >> 1)) * 16384 + ((wc & 1) * 64 + fr) * 128 + c16 * 16;
#define RD_A(b, mi, k32) (*(const f16x8*)(ldsB + ((aOff + (b) * 65536 + (mi) * 2048) ^ ((k32) * 64))))
#define RD_B(b, ni, k32) (*(const f16x8*)(ldsB + ((bOff + (b) * 65536 + (ni) * 2048) ^ ((k32) * 64))))

#define BAR() __builtin_amdgcn_s_barrier()
#define WLG0() asm volatile("s_waitcnt lgkmcnt(0)" ::: "memory")
#define WLG8() asm volatile("s_waitcnt lgkmcnt(8)" ::: "memory")
#define WVM4() asm volatile("s_waitcnt vmcnt(4)" ::: "memory")

  f32x4 acc[8][4];
#pragma unroll
  for (int mi = 0; mi < 8; ++mi)
#pragma unroll
    for (int ni = 0; ni < 4; ++ni) acc[mi][ni] = f32x4{0.f, 0.f, 0.f, 0.f};

  STAGE_A(0, 0); STAGE_A(0, 1); STAGE_B(0, 0); STAGE_B(0, 1);
  STAGE_B(1, 0); STAGE_B(1, 1);
  WVM4(); BAR();

#define MFMA_Q(MI0, MI1, x0, x1, x2, x3, PB)                                        \
  __builtin_amdgcn_s_setprio(1);                                                    \
  _Pragma("unroll") for (int ni = 0; ni < 4; ++ni) {                                \
    acc[MI0][ni] = __builtin_amdgcn_mfma_f32_16x16x32_f16(x0, PB[ni][0], acc[MI0][ni], 0, 0, 0); \
    acc[MI0][ni] = __builtin_amdgcn_mfma_f32_16x16x32_f16(x1, PB[ni][1], acc[MI0][ni], 0, 0, 0); \
    acc[MI1][ni] = __builtin_amdgcn_mfma_f32_16x16x32_f16(x2, PB[ni][0], acc[MI1][ni], 0, 0, 0); \
    acc[MI1][ni] = __builtin_amdgcn_mfma_f32_16x16x32_f16(x3, PB[ni][1], acc[MI1][ni], 0, 0, 0); \
  }                                                                                 \
  __builtin_amdgcn_s_setprio(0);

#define ITER8(u, msk) do {                                                          \
    const int t1 = (2 * (u) + 1) & (msk);                                           \
    const int t2 = (2 * (u) + 2) & (msk);                                           \
    const int t3 = (2 * (u) + 3) & (msk);                                           \
    f16x8 PB0[4][2];                                                                \
    _Pragma("unroll") for (int ni = 0; ni < 4; ++ni) {                              \
      PB0[ni][0] = RD_B(0, ni, 0); PB0[ni][1] = RD_B(0, ni, 1); }                   \
    {                                                                               \
      f16x8 x0 = RD_A(0, 0, 0), x1 = RD_A(0, 0, 1), x2 = RD_A(0, 1, 0), x3 = RD_A(0, 1, 1); \
      STAGE_A(t1, 0); WLG8(); BAR(); WLG0();                                        \
      MFMA_Q(0, 1, x0, x1, x2, x3, PB0) BAR();                                      \
    }                                                                               \
    {                                                                               \
      f16x8 x0 = RD_A(0, 2, 0), x1 = RD_A(0, 2, 1), x2 = RD_A(0, 3, 0), x3 = RD_A(0, 3, 1); \
      STAGE_A(t1, 1); BAR(); WLG0();                                                \
      MFMA_Q(2, 3, x0, x1, x2, x3, PB0) BAR();                                      \
    }                                                                               \
    {                                                                               \
      f16x8 x0 = RD_A(0, 4, 0), x1 = RD_A(0, 4, 1), x2 = RD_A(0, 5, 0), x3 = RD_A(0, 5, 1); \
      STAGE_B(t2, 0); BAR(); WLG0();                                                \
      MFMA_Q(4, 5, x0, x1, x2, x3, PB0) BAR();                                      \
    }                                                                               \
    {                                                                               \
      f16x8 x0 = RD_A(0, 6, 0), x1 = RD_A(0, 6, 1), x2 = RD_A(0, 7, 0), x3 = RD_A(0, 7, 1); \
      STAGE_B(t2, 1); BAR(); WLG0();                                                \
      MFMA_Q(6, 7, x0, x1, x2, x3, PB0) WVM4(); BAR();                              \
    }                                                                               \
    f16x8 PB1[4][2];                                                                \
    _Pragma("unroll") for (int ni = 0; ni < 4; ++ni) {                              \
      PB1[ni][0] = RD_B(1, ni, 0); PB1[ni][1] = RD_B(1, ni, 1); }                   \
    {                                                                               \
      f16x8 x0 = RD_A(1, 0, 0), x1 = RD_A(1, 0, 1), x2 = RD_A(1, 1, 0), x3 = RD_A(1, 1, 1); \
      STAGE_A(t2, 0); WLG8(); BAR(); WLG0();                                        \
      MFMA_Q(0, 1, x0, x1, x2, x3, PB1) BAR();                                      \
    }                                                                               \
    {                                                                               \
      f16x8 x0 = RD_A(1, 2, 0), x1 = RD_A(1, 2, 1), x2 = RD_A(1, 3, 0), x3 = RD_A(1, 3, 1); \
      STAGE_A(t2, 1); BAR(); WLG0();                                                \
      MFMA_Q(2, 3, x0, x1, x2, x3, PB1) BAR();                                      \
    }                                                                               \
    {                                                                               \
      f16x8 x0 = RD_A(1, 4, 0), x1 = RD_A(1, 4, 1), x2 = RD_A(1, 5, 0), x3 = RD_A(1, 5, 1); \
      STAGE_B(t3, 0); BAR(); WLG0();                                                \
      MFMA_Q(4, 5, x0, x1, x2, x3, PB1) BAR();                                      \
    }                                                                               \
    {                                                                               \
      f16x8 x0 = RD_A(1, 6, 0), x1 = RD_A(1, 6, 1), x2 = RD_A(1, 7, 0), x3 = RD_A(1, 7, 1); \
      STAGE_B(t3, 1); BAR(); WLG0();                                                \
      MFMA_Q(6, 7, x0, x1, x2, x3, PB1) WVM4(); BAR();                              \
    }                                                                               \
  } while (0)

  if (!rem) {
    for (int u = 0; u < 16; ++u) ITER8(u, 31);
  } else {
    for (int u = 0; u < 2; ++u) ITER8(u, 3);
  }

  const int m0 = by * 256 + wr * 128;
  const int cl = lane & 15, rq = (lane >> 4) * 4;
  if (!rem) {
    const int n0 = bxn * 256 + wc * 64;
    if (bxn < 16) {
#pragma unroll
      for (int mi = 0; mi < 8; ++mi)
#pragma unroll
        for (int r = 0; r < 4; ++r) {
          long rowoff = (long)(m0 + mi * 16 + rq + r) * 4096 + n0 + cl;
#pragma unroll
          for (int ni = 0; ni < 4; ++ni) gate[rowoff + ni * 16] = (_Float16)acc[mi][ni][r];
        }
    } else {
#pragma unroll
      for (int mi = 0; mi < 8; ++mi)
#pragma unroll
        for (int r = 0; r < 4; ++r) {
          long rowoff = (long)(m0 + mi * 16 + rq + r) * 4352 + (n0 - 4096) + cl;
#pragma unroll
          for (int ni = 0; ni < 4; ++ni) hbcf[rowoff + ni * 16] = acc[mi][ni][r];
        }
    }
  } else {
    float* rp = rparts + (long)zz * 1048576;
    const int ncol = wc * 64;
#pragma unroll
    for (int mi = 0; mi < 8; ++mi)
#pragma unroll
      for (int r = 0; r < 4; ++r) {
        long rowoff = (long)(m0 + mi * 16 + rq + r) * 256 + ncol + cl;
#pragma unroll
        for (int ni = 0; ni < 4; ++ni) rp[rowoff + ni * 16] = acc[mi][ni][r];
      }
  }
#undef STAGE_A
#undef STAGE_B
#undef RD_A
#undef RD_B
#undef ITER8
}

// ============ fuse2: dt_cum (16) || add_rem (1024) || transpose_wout (8192) ==
__global__ __launch_bounds__(256) void fuse2(const float* __restrict__ zf,
                                             const float* __restrict__ dtb,
                                             const float* __restrict__ Alog,
                                             float* __restrict__ dt_f,
                                             float* __restrict__ cum_f,
                                             float* __restrict__ cuml,
                                             const float* __restrict__ rp,
                                             float* __restrict__ hbcf,
                                             const float* __restrict__ Wout,
                                             _Float16* __restrict__ WoutT) {
  __shared__ __attribute__((aligned(16))) char smem2[4352];
  const int bid = blockIdx.x;
  const int tid = threadIdx.x;
  if (bid < 16) {
    // ---- dt softplus + chunk cumsum
    float (*segsum)[64] = reinterpret_cast<float (*)[64]>(smem2);
    int bc = bid;
    int h = tid & 63, seg = tid >> 6;
    int t0 = bc * 256;
    float Ah = -expf(Alog[h]);
    float bias = dtb[h];
    float s = 0.f;
    for (int j = 0; j < 64; j++) {
      int t = t0 + seg * 64 + j;
      float z = zf[(long)t * 64 + h] + bias;
      float v = (z > 20.f) ? z : log1pf(expf(z));
      dt_f[(long)t * 64 + h] = v;
      s += v * Ah;
    }
    segsum[seg][h] = s;
    __syncthreads();
    float run = 0.f;
    for (int k = 0; k < seg; k++) run += segsum[k][h];
    for (int j = 0; j < 64; j++) {
      int t = t0 + seg * 64 + j;
      run += dt_f[(long)t * 64 + h] * Ah;
      cum_f[(long)t * 64 + h] = run;
    }
    if (seg == 3) cuml[bc * 64 + h] = run;
  } else if (bid < 1040) {
    // ---- reduce 8 remainder K-partials into hbcf cols [4096,4352)
    long e = ((long)(bid - 16) * 256 + tid) * 4;
    float4 s = *reinterpret_cast<const float4*>(rp + e);
#pragma unroll
    for (int z = 1; z < 8; ++z) {
      float4 v = *reinterpret_cast<const float4*>(rp + (long)z * 1048576 + e);
      s.x += v.x; s.y += v.y; s.z += v.z; s.w += v.w;
    }
    long row = e >> 8, col = e & 255;
    *reinterpret_cast<float4*>(hbcf + row * 4352 + 4096 + col) = s;
  } else {
    // ---- transpose+cast Wout [4096,2048] fp32 -> WoutT [2048][4096] fp16
    float (*tile)[33] = reinterpret_cast<float (*)[33]>(smem2);
    int i = bid - 1040;
    int c0 = (i & 63) * 32, r0 = (i >> 6) * 32;
    int tx = tid & 31, ty = tid >> 5;
#pragma unroll
    for (int j = 0; j < 4; j++)
      tile[ty + j * 8][tx] = Wout[(long)(r0 + ty + j * 8) * 2048 + c0 + tx];
    __syncthreads();
#pragma unroll
    for (int j = 0; j < 4; j++) {
      int c = c0 + ty + j * 8, r = r0 + tx;
      WoutT[(long)c * 4096 + r] = (_Float16)tile[tx][ty + j * 8];
    }
  }
}

// ======= convx: conv(K=4)+SiLU (rolling taps) fused with x -> xT transpose ===
__global__ __launch_bounds__(256) void convx(const float* __restrict__ hbcf,
                                             const float* __restrict__ convw,
                                             const float* __restrict__ convb,
                                             _Float16* __restrict__ x16,
                                             _Float16* __restrict__ B16,
                                             _Float16* __restrict__ C16,
                                             unsigned short* __restrict__ xT16) {
  __shared__ unsigned short tile[64][66];
  const int bx = blockIdx.x, t0 = blockIdx.y * 64;
  const int tid = threadIdx.x;
  const int tq = tid & 63, tg = tid >> 6;
  const int q0 = (bx < 64) ? bx * 64 : 4096 + (bx - 64) * 64;
  const int q = q0 + tq;
  const int ts = t0 + tg * 16;
  const int bstart = ts & ~2047;  // batch start
  const float* colq = hbcf + q;
  float4 wq = *reinterpret_cast<const float4*>(convw + q * 4);
  float bconv = convb[q];
  float v3 = (ts - 3 >= bstart) ? colq[(long)(ts - 3) * 4352] : 0.f;
  float v2 = (ts - 2 >= bstart) ? colq[(long)(ts - 2) * 4352] : 0.f;
  float v1 = (ts - 1 >= bstart) ? colq[(long)(ts - 1) * 4352] : 0.f;
  if (bx < 64) {
#pragma unroll
    for (int j = 0; j < 16; ++j) {
      int t = ts + j;
      float v0 = colq[(long)t * 4352];
      float a = bconv + v3 * wq.x + v2 * wq.y + v1 * wq.z + v0 * wq.w;
      unsigned short o = f2h(siluf(a));
      ((unsigned short*)x16)[(long)t * 4096 + q] = o;
      tile[tg * 16 + j][tq] = o;
      v3 = v2; v2 = v1; v1 = v0;
    }
    __syncthreads();
    int tx = tid & 15, ty = tid >> 4;
#pragma unroll
    for (int i = 0; i < 4; ++i) {
      int c = ty + i * 16;
      ushort4 v;
      v.x = tile[4 * tx + 0][c]; v.y = tile[4 * tx + 1][c];
      v.z = tile[4 * tx + 2][c]; v.w = tile[4 * tx + 3][c];
      *(ushort4*)&xT16[(long)(q0 + c) * 4096 + t0 + 4 * tx] = v;
    }
  } else {
#pragma unroll
    for (int j = 0; j < 16; ++j) {
      int t = ts + j;
      float v0 = colq[(long)t * 4352];
      float a = bconv + v3 * wq.x + v2 * wq.y + v1 * wq.z + v0 * wq.w;
      _Float16 o = (_Float16)siluf(a);
      if (q < 4224) B16[(long)t * 128 + (q - 4096)] = o;
      else C16[(long)t * 128 + (q - 4224)] = o;
      v3 = v2; v2 = v1; v1 = v0;
    }
  }
}

// ================== fuse3: states_mfma (1024) || CBT gemm (64) ==============
__global__ __launch_bounds__(256) void fuse3(const unsigned short* __restrict__ xT16,
                                             const _Float16* __restrict__ B16,
                                             const _Float16* __restrict__ C16,
                                             const float* __restrict__ dt_f,
                                             const float* __restrict__ cum_f,
                                             const float* __restrict__ cuml,
                                             float* __restrict__ states,
                                             float* __restrict__ CBT) {
  __shared__ __attribute__((aligned(16))) char smem3[16384];
  const int bid = blockIdx.x;
  const int tid = threadIdx.x;
  const int wv = tid >> 6, lane = tid & 63;
  const int mr = lane & 15, koff = (lane >> 4) * 8;
  if (bid < 1024) {
    float* w_s = (float*)smem3;
    unsigned short* Aw = (unsigned short*)(smem3 + 1024);
    unsigned short* BT = (unsigned short*)(smem3 + 6144);
    int h = bid & 63, bc = bid >> 6;
    int t0 = bc * 256;
    {
      int t = t0 + tid;
      w_s[tid] = expf(cuml[bc * 64 + h] - cum_f[(long)t * 64 + h]) * dt_f[(long)t * 64 + h];
    }
    __syncthreads();
    f32x4 acc[4][2];
#pragma unroll
    for (int mi = 0; mi < 4; mi++)
#pragma unroll
      for (int nj = 0; nj < 2; nj++) acc[mi][nj] = f32x4{0.f, 0.f, 0.f, 0.f};
    for (int kt = 0; kt < 8; kt++) {
      {
        int p = tid >> 2, tq2 = tid & 3;
        const unsigned short* g = &xT16[((long)(h * 64 + p)) * 4096 + t0 + kt * 32 + tq2 * 8];
        ushort4 u0 = *(const ushort4*)g, u1 = *(const ushort4*)(g + 4);
        const float* wp = &w_s[kt * 32 + tq2 * 8];
        ushort4 o0, o1;
        o0.x = f2h(h2f(u0.x) * wp[0]); o0.y = f2h(h2f(u0.y) * wp[1]);
        o0.z = f2h(h2f(u0.z) * wp[2]); o0.w = f2h(h2f(u0.w) * wp[3]);
        o1.x = f2h(h2f(u1.x) * wp[4]); o1.y = f2h(h2f(u1.y) * wp[5]);
        o1.z = f2h(h2f(u1.z) * wp[6]); o1.w = f2h(h2f(u1.w) * wp[7]);
        *(ushort4*)&Aw[p * 40 + tq2 * 8] = o0;
        *(ushort4*)&Aw[p * 40 + tq2 * 8 + 4] = o1;
      }
      {
        int tl = tid >> 3, ng = tid & 7;
        const unsigned short* g = (const unsigned short*)B16 +
                                  ((long)(t0 + kt * 32 + tl)) * 128 + ng * 16;
#pragma unroll
        for (int j = 0; j < 16; j++) BT[(ng * 16 + j) * 40 + tl] = g[j];
      }
      __syncthreads();
      f16x8 af[4], bf[2];
#pragma unroll
      for (int mi = 0; mi < 4; mi++)
        af[mi] = *(const f16x8*)&Aw[(mi * 16 + mr) * 40 + koff];
#pragma unroll
      for (int nj = 0; nj < 2; nj++)
        bf[nj] = *(const f16x8*)&BT[((wv * 2 + nj) * 16 + mr) * 40 + koff];
#pragma unroll
      for (int mi = 0; mi < 4; mi++)
#pragma unroll
        for (int nj = 0; nj < 2; nj++)
          acc[mi][nj] = __builtin_amdgcn_mfma_f32_16x16x32_f16(af[mi], bf[nj],
                                                               acc[mi][nj], 0, 0, 0);
      __syncthreads();
    }
    int cl = lane & 15, rq = (lane >> 4) * 4;
    long base = ((long)(bc * 64 + h)) * 8192;
#pragma unroll
    for (int mi = 0; mi < 4; mi++)
#pragma unroll
      for (int r = 0; r < 4; r++) {
        int p = mi * 16 + rq + r;
#pragma unroll
        for (int nj = 0; nj < 2; nj++) {
          int n = (wv * 2 + nj) * 16 + cl;
          states[base + p * 128 + n] = acc[mi][nj][r];
        }
      }
  } else {
    _Float16* As = (_Float16*)smem3;
    _Float16* Bs = (_Float16*)(smem3 + 8192);
    int i = bid - 1024;
    int bx = i & 1, by = (i >> 1) & 1, bz = i >> 2;
    const _Float16* Ab = C16 + (long)bz * 32768 + (long)by * 128 * 128;
    const _Float16* Bb = B16 + (long)bz * 32768 + (long)bx * 128 * 128;
    const int c0 = wv * 128 + lane;
    const int c1 = c0 + 64;
    const long ra0 = (long)(c0 >> 2) * 128 + (c0 & 3) * 8;
    const long ra1 = (long)(c1 >> 2) * 128 + (c1 & 3) * 8;
    f32x4 acc[4][4];
#pragma unroll
    for (int mi = 0; mi < 4; mi++)
#pragma unroll
      for (int ni = 0; ni < 4; ni++) acc[mi][ni] = f32x4{0.f, 0.f, 0.f, 0.f};
    const int mrow = (wv & 1) * 64 + (lane & 15);
    const int nrow = (wv >> 1) * 64 + (lane & 15);
    for (int k0 = 0; k0 < 128; k0 += 32) {
      GLD16(Ab + ra0 + k0, (char*)As + c0 * 16);
      GLD16(Ab + ra1 + k0, (char*)As + c1 * 16);
      GLD16(Bb + ra0 + k0, (char*)Bs + c0 * 16);
      GLD16(Bb + ra1 + k0, (char*)Bs + c1 * 16);
      __syncthreads();
      f16x8 af[4], bfr[4];
#pragma unroll
      for (int mi = 0; mi < 4; mi++)
        af[mi] = *(const f16x8*)(As + (mrow + mi * 16) * 32 + koff);
#pragma unroll
      for (int ni = 0; ni < 4; ni++)
        bfr[ni] = *(const f16x8*)(Bs + (nrow + ni * 16) * 32 + koff);
#pragma unroll
      for (int mi = 0; mi < 4; mi++)
#pragma unroll
        for (int ni = 0; ni < 4; ni++)
          acc[mi][ni] = __builtin_amdgcn_mfma_f32_16x16x32_f16(af[mi], bfr[ni],
                                                               acc[mi][ni], 0, 0, 0);
      __syncthreads();
    }
    const int m0 = by * 128 + (wv & 1) * 64;
    const int n0 = bx * 128 + (wv >> 1) * 64;
    const int cl = lane & 15, rq = (lane >> 4) * 4;
    const long zc = (long)bz * 65536;
#pragma unroll
    for (int mi = 0; mi < 4; mi++)
#pragma unroll
      for (int r = 0; r < 4; r++) {
        long rowoff = zc + (long)(m0 + mi * 16 + rq + r) * 256 + n0 + cl;
#pragma unroll
        for (int ni = 0; ni < 4; ni++) CBT[rowoff + ni * 16] = acc[mi][ni][r];
      }
  }
}

// ------------- inter-chunk recurrence (1024 blocks: 128 bh x 8 j-slices) -----
__global__ __launch_bounds__(256) void recur_kernel(float* __restrict__ states,
                                                    const float* __restrict__ cuml) {
  int g = blockIdx.x;
  int bh = g >> 3, js = g & 7;
  int b = bh >> 6, h = bh & 63;
  int tid = threadIdx.x;
  float4 prev = make_float4(0.f, 0.f, 0.f, 0.f);
  for (int c = 0; c < 8; c++) {
    int bc = b * 8 + c;
    float cd = expf(cuml[bc * 64 + h]);
    long o = (long)(bc * 64 + h) * 8192 + js * 1024 + tid * 4;
    float4 st = *reinterpret_cast<const float4*>(&states[o]);
    *reinterpret_cast<float4*>(&states[o]) = prev;
    prev.x = fmaf(cd, prev.x, st.x);
    prev.y = fmaf(cd, prev.y, st.y);
    prev.z = fmaf(cd, prev.z, st.z);
    prev.w = fmaf(cd, prev.w, st.w);
  }
}

// ---------------- fused Y = Ydiag + Yoff + D*x  via MFMA, per (h, bc) block
__global__ __launch_bounds__(256) void yfused(const unsigned short* __restrict__ xT16,
                                              const unsigned short* __restrict__ x16,
                                              const unsigned short* __restrict__ C16,
                                              const float* __restrict__ CBT,
                                              const float* __restrict__ states,
                                              const float* __restrict__ dt_f,
                                              const float* __restrict__ cum_f,
                                              const float* __restrict__ Dp,
                                              float* __restrict__ Ysum) {
  int h = blockIdx.x, bc = blockIdx.y;
  int t0 = bc * 256, tid = threadIdx.x;
  __shared__ unsigned short Sb[256 * 40];
  __shared__ unsigned short Xb[64 * 264];
  __shared__ float cum_s[256], dt_s[256];
  int i = tid;
  cum_s[i] = cum_f[(long)(t0 + i) * 64 + h];
  dt_s[i] = dt_f[(long)(t0 + i) * 64 + h];
  {
    int p = tid >> 2, tq = tid & 3;
    const unsigned short* g = &xT16[((long)(h * 64 + p)) * 4096 + t0 + tq * 64];
    unsigned short* l = &Xb[p * 264 + tq * 64];
#pragma unroll
    for (int c = 0; c < 8; c++)
      *(uint4*)(l + c * 8) = *(const uint4*)(g + c * 8);
  }
  __syncthreads();
  float cum_i = cum_s[i];
  const float* cbrow = CBT + (long)bc * 65536 + (long)i * 256;
  int wv = tid >> 6, lane = tid & 63;
  int mr = lane & 15, koff = (lane >> 4) * 8;
  f32x4 acc[4][4];
#pragma unroll
  for (int mi = 0; mi < 4; mi++)
#pragma unroll
    for (int ni = 0; ni < 4; ni++) acc[mi][ni] = f32x4{0.f, 0.f, 0.f, 0.f};
  for (int kt = 0; kt < 8; kt++) {
    int k0 = kt * 32;
#pragma unroll
    for (int c = 0; c < 8; c++) {
      float4 cb = *(const float4*)&cbrow[k0 + c * 4];
      ushort4 o;
      {
        int j = k0 + c * 4 + 0;
        float s = (j <= i) ? cb.x * expf(cum_i - cum_s[j]) * dt_s[j] : 0.f;
        o.x = f2h(s);
      }
      {
        int j = k0 + c * 4 + 1;
        float s = (j <= i) ? cb.y * expf(cum_i - cum_s[j]) * dt_s[j] : 0.f;
        o.y = f2h(s);
      }
      {
        int j = k0 + c * 4 + 2;
        float s = (j <= i) ? cb.z * expf(cum_i - cum_s[j]) * dt_s[j] : 0.f;
        o.z = f2h(s);
      }
      {
        int j = k0 + c * 4 + 3;
        float s = (j <= i) ? cb.w * expf(cum_i - cum_s[j]) * dt_s[j] : 0.f;
        o.w = f2h(s);
      }
      *(ushort4*)&Sb[i * 40 + c * 4] = o;
    }
    __syncthreads();
    if (kt <= 2 * wv + 1) {
      f16x8 af[4], bf[4];
#pragma unroll
      for (int mi = 0; mi < 4; mi++)
        af[mi] = *(const f16x8*)&Sb[(64 * wv + mi * 16 + mr) * 40 + koff];
#pragma unroll
      for (int ni = 0; ni < 4; ni++)
        bf[ni] = *(const f16x8*)&Xb[(ni * 16 + mr) * 264 + k0 + koff];
#pragma unroll
      for (int mi = 0; mi < 4; mi++)
#pragma unroll
        for (int ni = 0; ni < 4; ni++)
          acc[mi][ni] = __builtin_amdgcn_mfma_f32_16x16x32_f16(af[mi], bf[ni],
                                                               acc[mi][ni], 0, 0, 0);
    }
    __syncthreads();
  }
  {
    int p = tid >> 2, nq = tid & 3;
    const float* g = &states[((long)(bc * 64 + h)) * 8192 + p * 128 + nq * 32];
    unsigned short* l = &Xb[p * 136 + nq * 32];
#pragma unroll
    for (int c = 0; c < 8; c++) {
      float4 v = *(const float4*)(g + c * 4);
      ushort4 u;
      u.x = f2h(v.x); u.y = f2h(v.y); u.z = f2h(v.z); u.w = f2h(v.w);
      *(ushort4*)(l + c * 4) = u;
    }
  }
  float fac_i = expf(cum_i);
  for (int kn = 0; kn < 4; kn++) {
    {
      const unsigned short* g = &C16[((long)(t0 + i)) * 128 + kn * 32];
#pragma unroll
      for (int c = 0; c < 8; c++) {
        ushort4 u = *(const ushort4*)(g + c * 4);
        ushort4 o;
        o.x = f2h(h2f(u.x) * fac_i); o.y = f2h(h2f(u.y) * fac_i);
        o.z = f2h(h2f(u.z) * fac_i); o.w = f2h(h2f(u.w) * fac_i);
        *(ushort4*)&Sb[i * 40 + c * 4] = o;
      }
    }
    __syncthreads();
    f16x8 af[4], bf[4];
#pragma unroll
    for (int mi = 0; mi < 4; mi++)
      af[mi] = *(const f16x8*)&Sb[(64 * wv + mi * 16 + mr) * 40 + koff];
#pragma unroll
    for (int ni = 0; ni < 4; ni++)
      bf[ni] = *(const f16x8*)&Xb[(ni * 16 + mr) * 136 + kn * 32 + koff];
#pragma unroll
    for (int mi = 0; mi < 4; mi++)
#pragma unroll
      for (int ni = 0; ni < 4; ni++)
        acc[mi][ni] = __builtin_amdgcn_mfma_f32_16x16x32_f16(af[mi], bf[ni],
                                                             acc[mi][ni], 0, 0, 0);
    __syncthreads();
  }
  float Dh = Dp[h];
  int cl = lane & 15, rq = (lane >> 4) * 4;
#pragma unroll
  for (int mi = 0; mi < 4; mi++)
#pragma unroll
    for (int r = 0; r < 4; r++) {
      long row = t0 + 64 * wv + mi * 16 + rq + r;
      float* yr = &Ysum[row * 4096 + h * 64];
      const unsigned short* xr = &x16[row * 4096 + h * 64];
#pragma unroll
      for (int ni = 0; ni < 4; ni++) {
        int p = ni * 16 + cl;
        yr[p] = acc[mi][ni][r] + Dh * h2f(xr[p]);
      }
    }
}

// ------------------------------------------------- gate*SiLU + RMSNorm -> fp16
__global__ __launch_bounds__(256) void norm_kernel(const float* __restrict__ Ysum,
                                                   const _Float16* __restrict__ gate,
                                                   const float* __restrict__ nw,
                                                   _Float16* __restrict__ hid) {
  int t = blockIdx.x;
  int tid = threadIdx.x;
  float hv[16];
  float ss = 0.f;
#pragma unroll
  for (int k = 0; k < 4; k++) {
    int d = tid * 4 + k * 1024;
    float4 y = *reinterpret_cast<const float4*>(&Ysum[(long)t * 4096 + d]);
    ushort4 gu = *reinterpret_cast<const ushort4*>(gate + (long)t * 4096 + d);
    float h0 = y.x * siluf(h2f(gu.x)), h1 = y.y * siluf(h2f(gu.y));
    float h2 = y.z * siluf(h2f(gu.z)), h3 = y.w * siluf(h2f(gu.w));
    hv[k * 4 + 0] = h0; hv[k * 4 + 1] = h1; hv[k * 4 + 2] = h2; hv[k * 4 + 3] = h3;
    ss += h0 * h0 + h1 * h1 + h2 * h2 + h3 * h3;
  }
#pragma unroll
  for (int o = 32; o > 0; o >>= 1) ss += __shfl_down(ss, o, 64);
  __shared__ float ws4[4];
  if ((tid & 63) == 0) ws4[tid >> 6] = ss;
  __syncthreads();
  float var = (ws4[0] + ws4[1] + ws4[2] + ws4[3]) * (1.f / 4096.f);
  float scale = rsqrtf(var + 1e-5f);
#pragma unroll
  for (int k = 0; k < 4; k++) {
    int d = tid * 4 + k * 1024;
    ushort4 u;
#pragma unroll
    for (int c = 0; c < 4; c++)
      ((unsigned short*)&u)[c] = f2h(hv[k * 4 + c] * scale * nw[d + c]);
    *reinterpret_cast<ushort4*>(hid + (long)t * 4096 + d) = u;
  }
}

// ===================== out_proj GEMM: 256^2 tile, split-K (z=2), 8-phase =====
// Square per-XCD regions: XCD (wg&7) owns 4(by) x 4(bx) x 2(z).
__global__ __launch_bounds__(512, 2) void gemm_out8(const _Float16* __restrict__ A,
                                                    const _Float16* __restrict__ Bt,
                                                    float* __restrict__ Cp) {
  __shared__ __attribute__((aligned(128))) char ldsB[131072];
  const int tid = threadIdx.x;
  const int lane = tid & 63;
  const int wv = tid >> 6;
  const int wr = wv >> 2, wc = wv & 3;
  const int wg = blockIdx.x;
  const int xcd = wg & 7, j = wg >> 3;   // j in [0,32)
  const int z = j >> 4, t = j & 15;
  const int by = (xcd >> 1) * 4 + (t >> 2);
  const int bx = (xcd & 1) * 4 + (t & 3);

  const int srow = tid >> 3;
  const int scolg = (tid & 7) ^ (srow & 7);
  const _Float16* Ab = A + (long)by * 256 * 4096 + (long)z * 2048 +
                       (long)srow * 4096 + scolg * 8;
  const _Float16* Bb = Bt + (long)bx * 256 * 4096 + (long)z * 2048 +
                       (long)srow * 4096 + scolg * 8;
  const int ldst = tid << 4;

#define STAGE_A(tau, h) do {                                              \
    const _Float16* g_ = Ab + (long)(h) * 524288 + (tau) * 64;            \
    char* l_ = ldsB + ((((tau) & 1) << 2) + (h)) * 16384 + ldst;          \
    GLD16(g_, l_); GLD16(g_ + 262144, l_ + 8192); } while (0)
#define STAGE_B(tau, h) do {                                              \
    const _Float16* g_ = Bb + (long)(h) * 524288 + (tau) * 64;            \
    char* l_ = ldsB + ((((tau) & 1) << 2) + 2 + (h)) * 16384 + ldst;      \
    GLD16(g_, l_); GLD16(g_ + 262144, l_ + 8192); } while (0)

  const int fr = lane & 15;
  const int c16 = (lane >> 4) ^ (fr & 7);
  const int aOff = wr * 16384 + fr * 128 + c16 * 16;
  const int bOff = (2 + (wc >> 1)) * 16384 + ((wc & 1) * 64 + fr) * 128 + c16 * 16;
#define RD_A(b, mi, k32) (*(const f16x8*)(ldsB + ((aOff + (b) * 65536 + (mi) * 2048) ^ ((k32) * 64))))
#define RD_B(b, ni, k32) (*(const f16x8*)(ldsB + ((bOff + (b) * 65536 + (ni) * 2048) ^ ((k32) * 64))))

  f32x4 acc[8][4];
#pragma unroll
  for (int mi = 0; mi < 8; ++mi)
#pragma unroll
    for (int ni = 0; ni < 4; ++ni) acc[mi][ni] = f32x4{0.f, 0.f, 0.f, 0.f};

  STAGE_A(0, 0); STAGE_A(0, 1); STAGE_B(0, 0); STAGE_B(0, 1);
  STAGE_B(1, 0); STAGE_B(1, 1);
  WVM4(); BAR();

  for (int u = 0; u < 16; ++u) {
    const int t1 = 2 * u + 1;
    const int t2 = (2 * u + 2) & 31;
    const int t3 = (2 * u + 3) & 31;
    f16x8 PB0[4][2];
#pragma unroll
    for (int ni = 0; ni < 4; ++ni) { PB0[ni][0] = RD_B(0, ni, 0); PB0[ni][1] = RD_B(0, ni, 1); }
    {
      f16x8 x0 = RD_A(0, 0, 0), x1 = RD_A(0, 0, 1), x2 = RD_A(0, 1, 0), x3 = RD_A(0, 1, 1);
      STAGE_A(t1, 0); WLG8(); BAR(); WLG0();
      MFMA_Q(0, 1, x0, x1, x2, x3, PB0) BAR();
    }
    {
      f16x8 x0 = RD_A(0, 2, 0), x1 = RD_A(0, 2, 1), x2 = RD_A(0, 3, 0), x3 = RD_A(0, 3, 1);
      STAGE_A(t1, 1); BAR(); WLG0();
      MFMA_Q(2, 3, x0, x1, x2, x3, PB0) BAR();
    }
    {
      f16x8 x0 = RD_A(0, 4, 0), x1 = RD_A(0, 4, 1), x2 = RD_A(0, 5, 0), x3 = RD_A(0, 5, 1);
      STAGE_B(t2, 0); BAR(); WLG0();
      MFMA_Q(4, 5, x0, x1, x2, x3, PB0) BAR();
    }
    {
      f16x8 x0 = RD_A(0, 6, 0), x1 = RD_A(0, 6, 1), x2 = RD_A(0, 7, 0), x3 = RD_A(0, 7, 1);
      STAGE_B(t2, 1); BAR(); WLG0();
      MFMA_Q(6, 7, x0, x1, x2, x3, PB0) WVM4(); BAR();
    }
    f16x8 PB1[4][2];
#pragma unroll
    for (int ni = 0; ni < 4; ++ni) { PB1[ni][0] = RD_B(1, ni, 0); PB1[ni][1] = RD_B(1, ni, 1); }
    {
      f16x8 x0 = RD_A(1, 0, 0), x1 = RD_A(1, 0, 1), x2 = RD_A(1, 1, 0), x3 = RD_A(1, 1, 1);
      STAGE_A(t2, 0); WLG8(); BAR(); WLG0();
      MFMA_Q(0, 1, x0, x1, x2, x3, PB1) BAR();
    }
    {
      f16x8 x0 = RD_A(1, 2, 0), x1 = RD_A(1, 2, 1), x2 = RD_A(1, 3, 0), x3 = RD_A(1, 3, 1);
      STAGE_A(t2, 1); BAR(); WLG0();
      MFMA_Q(2, 3, x0, x1, x2, x3, PB1) BAR();
    }
    {
      f16x8 x0 = RD_A(1, 4, 0), x1 = RD_A(1, 4, 1), x2 = RD_A(1, 5, 0), x3 = RD_A(1, 5, 1);
      STAGE_B(t3, 0); BAR(); WLG0();
      MFMA_Q(4, 5, x0, x1, x2, x3, PB1) BAR();
    }
    {
      f16x8 x0 = RD_A(1, 6, 0), x1 = RD_A(1, 6, 1), x2 = RD_A(1, 7, 0), x3 = RD_A(1, 7, 1);
      STAGE_B(t3, 1); BAR(); WLG0();
      MFMA_Q(6, 7, x0, x1, x2, x3, PB1) WVM4(); BAR();
    }
  }
  const int m0 = by * 256 + wr * 128;
  const int n0 = bx * 256 + wc * 64;
  const int cl = lane & 15, rq = (lane >> 4) * 4;
  float* Cb = Cp + (long)z * 8388608;
#pragma unroll
  for (int mi = 0; mi < 8; ++mi)
#pragma unroll
    for (int r = 0; r < 4; ++r) {
      long rowoff = (long)(m0 + mi * 16 + rq + r) * 2048 + n0 + cl;
#pragma unroll
      for (int ni = 0; ni < 4; ++ni) Cb[rowoff + ni * 16] = acc[mi][ni][r];
    }
#undef STAGE_A
#undef STAGE_B
#undef RD_A
#undef RD_B
#undef BAR
#undef WLG0
#undef WLG8
#undef WVM4
#undef MFMA_Q
}

// -------------------------------------------- sum the two split-K partials
__global__ __launch_bounds__(256) void add_out(const float* __restrict__ p,
                                               float* __restrict__ o) {
  long i = ((long)blockIdx.x * 256 + threadIdx.x) * 4;
  float4 a = *reinterpret_cast<const float4*>(p + i);
  float4 b = *reinterpret_cast<const float4*>(p + 8388608 + i);
  float4 r;
  r.x = a.x + b.x; r.y = a.y + b.y; r.z = a.z + b.z; r.w = a.w + b.w;
  *reinterpret_cast<float4*>(o + i) = r;
}

// =============================================================== launch
extern "C" void kernel_launch(void* const* d_in, const int* in_sizes, int n_in,
                              void* d_out, int out_size, void* d_ws, size_t ws_size,
                              hipStream_t stream) {
  (void)in_sizes; (void)n_in; (void)out_size; (void)ws_size;
  const float* hs    = (const float*)d_in[0];
  const float* Win   = (const float*)d_in[1];
  const float* convw = (const float*)d_in[2];
  const float* convb = (const float*)d_in[3];
  const float* dtb   = (const float*)d_in[4];
  const float* Alog  = (const float*)d_in[5];
  const float* Dp    = (const float*)d_in[6];
  const float* nw    = (const float*)d_in[7];
  const float* Wout  = (const float*)d_in[8];
  float* out = (float*)d_out;

  char* base = (char*)d_ws;
  size_t off = 0;
  auto take = [&](size_t n) { char* r = base + off; off += (n + 255) & ~(size_t)255; return r; };
  float*    hbcf  = (float*)take(4096UL * 4352 * 4);    // gemm_in -> conv; then Ysum; then out-partials
  _Float16* gateh = (_Float16*)take(4096UL * 4096 * 2); // gemm_in -> norm
  _Float16* Ah    = (_Float16*)take(4096UL * 2048 * 2); // cast -> gemm_in; then WoutT
  _Float16* WtH   = (_Float16*)take(8448UL * 2048 * 2); // trans -> gemm_in; then x16
  _Float16* xT16  = (_Float16*)take(4096UL * 4096 * 2); // convx -> states/yfused
  _Float16* B16   = (_Float16*)take(4096UL * 128 * 2);
  _Float16* C16   = (_Float16*)take(4096UL * 128 * 2);
  float*    zf    = (float*)take(4096UL * 64 * 4);
  float*    dt_f  = (float*)take(4096UL * 64 * 4);
  float*    cum_f = (float*)take(4096UL * 64 * 4);
  float*    cuml  = (float*)take(16UL * 64 * 4);
  float*    CBT   = (float*)take(16UL * 256 * 256 * 4);
  float*    states= (float*)take(1024UL * 8192 * 4);    // rparts scratch; -> states -> prevs; then hid
  // overlays:
  float*    Ysum  = hbcf;               // live yfused..norm
  float*    oparts= hbcf;               // live gemm_out8..add_out
  float*    rparts= states;             // live gemm_in8..fuse2 (8 x 4MB = 32MB)
  _Float16* WoutT = Ah;                 // written by fuse2 (after gemm_in8)
  _Float16* x16   = WtH;                // written by convx (after gemm_in8)
  _Float16* hid   = (_Float16*)states;  // live norm..out_proj

  // 1. prep: dtz || cast || transpose_win (one launch)
  prep<<<26112, 256, 0, stream>>>(hs, Win, Ah, WtH, zf);
  // 2. fp16 in_proj GEMM (256^2 8-phase; square per-XCD regions + remainder)
  gemm_in8<<<dim3(640), 512, 0, stream>>>(Ah, WtH, gateh, hbcf, rparts);
  // 3. fuse2: dt_cum || add_rem || transpose_wout (one launch)
  fuse2<<<9232, 256, 0, stream>>>(zf, dtb, Alog, dt_f, cum_f, cuml,
                                  rparts, hbcf, Wout, WoutT);
  // 4. convx: rolling-tap conv+SiLU fused with x->xT transpose
  convx<<<dim3(68, 64), 256, 0, stream>>>(hbcf, convw, convb, x16, B16, C16,
                                          (unsigned short*)xT16);
  // 5. fuse3: states_mfma || CBT gemm (one launch)
  fuse3<<<1088, 256, 0, stream>>>((const unsigned short*)xT16, B16, C16,
                                  dt_f, cum_f, cuml, states, CBT);
  // 6. inter-chunk recurrence (1024 blocks)
  recur_kernel<<<1024, 256, 0, stream>>>(states, cuml);
  // 7. fused Ydiag + Yoff + D*x -> Ysum (overlays dead hbcf)
  yfused<<<dim3(64, 16), 256, 0, stream>>>((const unsigned short*)xT16,
                                           (const unsigned short*)x16,
                                           (const unsigned short*)C16,
                                           CBT, states, dt_f, cum_f, Dp, Ysum);
  // 8. gate + RMSNorm -> hid fp16 (overlays dead states)
  norm_kernel<<<4096, 256, 0, stream>>>(Ysum, gateh, nw, hid);
  // 9. out_proj GEMM (256^2 8-phase, split-K z=2) -> partials in dead hbcf
  gemm_out8<<<dim3(256), 512, 0, stream>>>(hid, WoutT, oparts);
  // 10. sum partials -> d_out fp32
  add_out<<<8192, 256, 0, stream>>>(oparts, out);
}